// Round 13
// baseline (2080.750 us; speedup 1.0000x reference)
//
#include <hip/hip_runtime.h>
#include <math.h>

#define GRIDN 160
#define N3 (160*160*160)
#define SX (160*160)
#define SY 160
#define DIST_C 0.005f
#define W0K 104   // sW0 row stride (ushorts), K=96 used
#define W1K 136   // sW1/sW2/sH row stride (ushorts), K=128 used
#define TPB 16    // groups (of 256 points) per MLP block -> grid = 256 = 1 block/CU
#define NBUCKET 125

__device__ __forceinline__ float sigm_(float x) { return 1.f / (1.f + expf(-x)); }
__device__ __forceinline__ unsigned short f2bf(float x) {
  unsigned u = __builtin_bit_cast(unsigned, x);
  u = (u + 0x7fffu + ((u >> 16) & 1u)) >> 16;
  return (unsigned short)u;
}
__device__ __forceinline__ unsigned pk_bf16(float a, float b) {
  return (unsigned)f2bf(a) | ((unsigned)f2bf(b) << 16);
}
__device__ __forceinline__ float bf_lo(unsigned u) { return __builtin_bit_cast(float, u << 16); }
__device__ __forceinline__ float bf_hi(unsigned u) { return __builtin_bit_cast(float, u & 0xffff0000u); }
__device__ __forceinline__ unsigned short f2h(float x) {
  _Float16 h = (_Float16)x; return __builtin_bit_cast(unsigned short, h);
}
__device__ __forceinline__ float h_lo(unsigned u) {
  return (float)__builtin_bit_cast(_Float16, (unsigned short)(u & 0xffffu));
}
__device__ __forceinline__ float h_hi(unsigned u) {
  return (float)__builtin_bit_cast(_Float16, (unsigned short)(u >> 16));
}
__device__ __forceinline__ int voxel_ix(float p) {
  const float SC = 0.5f * 159.f;
  float u = fminf(fmaxf((p + 1.f) * SC, 0.f), 159.f);
  return min((int)u, 158);
}
__device__ __forceinline__ int bucket_key(float px, float py, float pz) {
  return ((voxel_ix(px) >> 5) * 5 + (voxel_ix(py) >> 5)) * 5 + (voxel_ix(pz) >> 5);
}

typedef __attribute__((ext_vector_type(8))) short bf16x8;
typedef __attribute__((ext_vector_type(4))) float f32x4;
typedef __attribute__((ext_vector_type(4))) unsigned u32x4;

// ==== fused repack -> 32B voxel record: [sdf,gx,gy,gz](f16) + k0 ch0..11 (bf16) ====
__global__ __launch_bounds__(256) void vox_repack_all(
    const float* __restrict__ V, const float* __restrict__ k0,
    unsigned short* __restrict__ VR) {
  int idx = blockIdx.x * 256 + threadIdx.x;
  if (idx >= N3) return;
  int z = idx % GRIDN; int t = idx / GRIDN; int y = t % GRIDN; int x = t / GRIDN;
  float v = V[idx];
  float xp = (x < 159) ? V[idx + SX] : v, xm = (x > 0) ? V[idx - SX] : v;
  float yp = (y < 159) ? V[idx + SY] : v, ym = (y > 0) ? V[idx - SY] : v;
  float zp = (z < 159) ? V[idx + 1]  : v, zm = (z > 0) ? V[idx - 1]  : v;
  float cx = (x > 0 && x < 159) ? (159.f / 4.f) : (159.f / 2.f);
  float cy = (y > 0 && y < 159) ? (159.f / 4.f) : (159.f / 2.f);
  float cz = (z > 0 && z < 159) ? (159.f / 4.f) : (159.f / 2.f);
  unsigned f0 = (unsigned)f2h(v) | ((unsigned)f2h((xp - xm) * cx) << 16);
  unsigned f1 = (unsigned)f2h((yp - ym) * cy) | ((unsigned)f2h((zp - zm) * cz) << 16);
  unsigned w[6];
#pragma unroll
  for (int j = 0; j < 6; j++) {
    float a = __builtin_nontemporal_load(k0 + (size_t)(2 * j) * N3 + idx);
    float b = __builtin_nontemporal_load(k0 + (size_t)(2 * j + 1) * N3 + idx);
    w[j] = pk_bf16(a, b);
  }
  u32x4* r = (u32x4*)(VR + (size_t)idx * 16);
  r[0] = (u32x4){f0, f1, w[0], w[1]};
  r[1] = (u32x4){w[2], w[3], w[4], w[5]};
}

// ============ repack weights -> transposed bf16 with padded strides ============
__global__ __launch_bounds__(256) void vox_repack_w(
    const float* __restrict__ w0, const float* __restrict__ w1, const float* __restrict__ w2,
    unsigned short* __restrict__ W0B, unsigned short* __restrict__ W1B,
    unsigned short* __restrict__ W2B) {
  int i = blockIdx.x * 256 + threadIdx.x;
  if (i < 128 * W0K) {                    // W0B[c][k] = w0[k][c], k<75
    int c = i / W0K, k = i - c * W0K;
    W0B[i] = (k < 75) ? f2bf(w0[k * 128 + c]) : (unsigned short)0;
  }
  if (i < 128 * W1K) {                    // W1B[c][k] = w1[k][c], k<128
    int c = i / W1K, k = i - c * W1K;
    W1B[i] = (k < 128) ? f2bf(w1[k * 128 + c]) : (unsigned short)0;
  }
  if (i < 16 * W1K) {                     // W2B[c][k] = w2[k][c], c<3, k<128
    int c = i / W1K, k = i - c * W1K;
    W2B[i] = (k < 128 && c < 3) ? f2bf(w2[k * 3 + c]) : (unsigned short)0;
  }
}

// ============ counting sort by 125 macro-cells ============
__global__ void vox_sort_zero(unsigned* __restrict__ hist, unsigned* __restrict__ cursor) {
  if (threadIdx.x < NBUCKET) { hist[threadIdx.x] = 0; cursor[threadIdx.x] = 0; }
}
__global__ __launch_bounds__(256) void vox_sort_hist(
    const float* __restrict__ pts, unsigned* __restrict__ hist, int M) {
  int i = blockIdx.x * 256 + threadIdx.x;
  if (i >= M) return;
  int key = bucket_key(pts[3 * i], pts[3 * i + 1], pts[3 * i + 2]);
  atomicAdd(&hist[key], 1u);
}
__global__ void vox_sort_scan(const unsigned* __restrict__ hist, unsigned* __restrict__ cursor) {
  __shared__ unsigned s[128];
  int t = threadIdx.x;
  unsigned own = (t < NBUCKET) ? hist[t] : 0;
  s[t] = own; __syncthreads();
  for (int off = 1; off < 128; off <<= 1) {
    unsigned v = (t >= off) ? s[t - off] : 0;
    __syncthreads(); s[t] += v; __syncthreads();
  }
  if (t < NBUCKET) cursor[t] = s[t] - own;   // exclusive prefix
}
__global__ __launch_bounds__(256) void vox_sort_scatter(
    const float* __restrict__ pts, unsigned* __restrict__ cursor,
    unsigned* __restrict__ sortedIdx, int M) {
  int i = blockIdx.x * 256 + threadIdx.x;
  if (i >= M) return;
  int key = bucket_key(pts[3 * i], pts[3 * i + 1], pts[3 * i + 2]);
  unsigned pos = atomicAdd(&cursor[key], 1u);
  sortedIdx[pos] = (unsigned)i;
}

// ============ gather (sorted order): trilerps + alpha + feat[96] bf16 ============
__global__ __launch_bounds__(256) void vox_gather_kernel(
    const float* __restrict__ ray_pts, const float* __restrict__ rays_d,
    const unsigned short* __restrict__ VR,
    const float* __restrict__ s_val, const int* __restrict__ ray_id,
    const unsigned* __restrict__ sortedIdx,
    float* __restrict__ alpha_out, unsigned short* __restrict__ featB, int M) {
  // XCD-contiguous swizzle: each XCD gets a contiguous sorted range (T1, bijective
  // since gridDim % 8 == 0 is guaranteed by the launcher).
  int nb = (int)gridDim.x;
  int swz = ((int)blockIdx.x % 8) * (nb / 8) + (int)blockIdx.x / 8;
  int j = swz * 256 + (int)threadIdx.x;
  if (j >= M) return;
  int i = (int)sortedIdx[j];

  float px = ray_pts[3 * i + 0], py = ray_pts[3 * i + 1], pz = ray_pts[3 * i + 2];
  const float SC = 0.5f * 159.f;
  float ux = fminf(fmaxf((px + 1.f) * SC, 0.f), 159.f);
  float uy = fminf(fmaxf((py + 1.f) * SC, 0.f), 159.f);
  float uz = fminf(fmaxf((pz + 1.f) * SC, 0.f), 159.f);
  int ix = min((int)ux, 158), iy = min((int)uy, 158), iz = min((int)uz, 158);
  float fx = ux - (float)ix, fy = uy - (float)iy, fz = uz - (float)iz;
  float wx0 = 1.f - fx, wy0 = 1.f - fy, wz0 = 1.f - fz;
  float wxy[4];
  wxy[0] = wx0 * wy0; wxy[1] = wx0 * fy; wxy[2] = fx * wy0; wxy[3] = fx * fy;
  const int pairoff[4] = {0, SY, SX, SX + SY};
  int base = (ix * GRIDN + iy) * GRIDN + iz;

  // ---- 4 z-pair taps, 64B contiguous each (2 voxel records) ----
  u32x4 q[4][4];
#pragma unroll
  for (int t = 0; t < 4; t++) {
    const u32x4* p = (const u32x4*)(VR + (size_t)(base + pairoff[t]) * 16);
    q[t][0] = p[0]; q[t][1] = p[1]; q[t][2] = p[2]; q[t][3] = p[3];
  }

  float sdf = 0.f, gx = 0.f, gy = 0.f, gz = 0.f;
  float k[12];
#pragma unroll
  for (int j2 = 0; j2 < 12; j2++) k[j2] = 0.f;
#pragma unroll
  for (int t = 0; t < 4; t++) {
    float w0z = wxy[t] * wz0, w1z = wxy[t] * fz;
    sdf = fmaf(w0z, h_lo(q[t][0].x), sdf);
    gx  = fmaf(w0z, h_hi(q[t][0].x), gx);
    gy  = fmaf(w0z, h_lo(q[t][0].y), gy);
    gz  = fmaf(w0z, h_hi(q[t][0].y), gz);
    k[0]  = fmaf(w0z, bf_lo(q[t][0].z), k[0]);
    k[1]  = fmaf(w0z, bf_hi(q[t][0].z), k[1]);
    k[2]  = fmaf(w0z, bf_lo(q[t][0].w), k[2]);
    k[3]  = fmaf(w0z, bf_hi(q[t][0].w), k[3]);
    k[4]  = fmaf(w0z, bf_lo(q[t][1].x), k[4]);
    k[5]  = fmaf(w0z, bf_hi(q[t][1].x), k[5]);
    k[6]  = fmaf(w0z, bf_lo(q[t][1].y), k[6]);
    k[7]  = fmaf(w0z, bf_hi(q[t][1].y), k[7]);
    k[8]  = fmaf(w0z, bf_lo(q[t][1].z), k[8]);
    k[9]  = fmaf(w0z, bf_hi(q[t][1].z), k[9]);
    k[10] = fmaf(w0z, bf_lo(q[t][1].w), k[10]);
    k[11] = fmaf(w0z, bf_hi(q[t][1].w), k[11]);
    sdf = fmaf(w1z, h_lo(q[t][2].x), sdf);
    gx  = fmaf(w1z, h_hi(q[t][2].x), gx);
    gy  = fmaf(w1z, h_lo(q[t][2].y), gy);
    gz  = fmaf(w1z, h_hi(q[t][2].y), gz);
    k[0]  = fmaf(w1z, bf_lo(q[t][2].z), k[0]);
    k[1]  = fmaf(w1z, bf_hi(q[t][2].z), k[1]);
    k[2]  = fmaf(w1z, bf_lo(q[t][2].w), k[2]);
    k[3]  = fmaf(w1z, bf_hi(q[t][2].w), k[3]);
    k[4]  = fmaf(w1z, bf_lo(q[t][3].x), k[4]);
    k[5]  = fmaf(w1z, bf_hi(q[t][3].x), k[5]);
    k[6]  = fmaf(w1z, bf_lo(q[t][3].y), k[6]);
    k[7]  = fmaf(w1z, bf_hi(q[t][3].y), k[7]);
    k[8]  = fmaf(w1z, bf_lo(q[t][3].z), k[8]);
    k[9]  = fmaf(w1z, bf_hi(q[t][3].z), k[9]);
    k[10] = fmaf(w1z, bf_lo(q[t][3].w), k[10]);
    k[11] = fmaf(w1z, bf_hi(q[t][3].w), k[11]);
  }
  float ginv = 1.f / (sqrtf(gx * gx + gy * gy + gz * gz) + 1e-8f);
  float gnx = gx * ginv, gny = gy * ginv, gnz = gz * ginv;

  int rid = ray_id[i];
  float ddx = rays_d[3 * rid + 0], ddy = rays_d[3 * rid + 1], ddz = rays_d[3 * rid + 2];

  float true_cos = ddx * gnx + ddy * gny + ddz * gnz;
  float iter_cos = fminf(true_cos, 0.f);
  float inv_s = 1.f / s_val[0];
  float e = iter_cos * (DIST_C * 0.5f);
  float prev_cdf = sigm_((sdf - e) * inv_s);
  float next_cdf = sigm_((sdf + e) * inv_s);
  float alpha = (prev_cdf - next_cdf + 1e-5f) / (prev_cdf + 1e-5f);
  alpha_out[i] = fminf(fmaxf(alpha, 0.f), 1.f);   // scattered 4B write (original order)

  float feat[75];
#pragma unroll
  for (int j2 = 0; j2 < 12; j2++) feat[j2] = k[j2];

  float x01 = (px + 1.f) * 0.5f, y01 = (py + 1.f) * 0.5f, z01 = (pz + 1.f) * 0.5f;
  feat[12] = x01; feat[13] = y01; feat[14] = z01;
#pragma unroll
  for (int l = 0; l < 5; l++) {
    float f = (float)(1 << l), s, c;
    sincosf(x01 * f, &s, &c); feat[15 + l] = s; feat[30 + l] = c;
    sincosf(y01 * f, &s, &c); feat[20 + l] = s; feat[35 + l] = c;
    sincosf(z01 * f, &s, &c); feat[25 + l] = s; feat[40 + l] = c;
  }
  feat[45] = ddx; feat[46] = ddy; feat[47] = ddz;
#pragma unroll
  for (int l = 0; l < 4; l++) {
    float f = (float)(1 << l), s, c;
    sincosf(ddx * f, &s, &c); feat[48 + l] = s; feat[60 + l] = c;
    sincosf(ddy * f, &s, &c); feat[52 + l] = s; feat[64 + l] = c;
    sincosf(ddz * f, &s, &c); feat[56 + l] = s; feat[68 + l] = c;
  }
  feat[72] = gnx; feat[73] = gny; feat[74] = gnz;

  // pack 96 bf16 -> featB in SORTED order (coalesced streaming write)
  unsigned pw[48];
#pragma unroll
  for (int wv = 0; wv < 37; wv++) pw[wv] = pk_bf16(feat[2 * wv], feat[2 * wv + 1]);
  pw[37] = pk_bf16(feat[74], 0.f);
#pragma unroll
  for (int wv = 38; wv < 48; wv++) pw[wv] = 0u;
  u32x4* fb = (u32x4*)(featB + (size_t)j * 96);
#pragma unroll
  for (int q2 = 0; q2 < 12; q2++)
    fb[q2] = (u32x4){pw[4 * q2], pw[4 * q2 + 1], pw[4 * q2 + 2], pw[4 * q2 + 3]};
}

// ======== MFMA MLP: 1024 thr = 16 waves share one weight staging ========
__global__ __launch_bounds__(1024, 1) void vox_mlp_kernel(
    const unsigned short* __restrict__ featB,
    const unsigned short* __restrict__ W0B, const unsigned short* __restrict__ W1B,
    const unsigned short* __restrict__ W2B,
    const float* __restrict__ b0, const float* __restrict__ b1,
    const float* __restrict__ b2, const unsigned* __restrict__ sortedIdx,
    float* __restrict__ rgb, int ngroups) {
  __shared__ __align__(16) unsigned short sW0[128 * W0K];
  __shared__ __align__(16) unsigned short sW1[128 * W1K];
  __shared__ __align__(16) unsigned short sW2[16 * W1K];
  __shared__ __align__(16) unsigned short sH[16 * 16 * W1K];
  __shared__ __align__(16) float sB0[128], sB1[128], sB2[16];

  {
    const uint4* s0 = (const uint4*)W0B; uint4* d0 = (uint4*)sW0;
    for (int i = threadIdx.x; i < 128 * W0K / 8; i += 1024) d0[i] = s0[i];
    const uint4* s1 = (const uint4*)W1B; uint4* d1 = (uint4*)sW1;
    for (int i = threadIdx.x; i < 128 * W1K / 8; i += 1024) d1[i] = s1[i];
    const uint4* s2 = (const uint4*)W2B; uint4* d2 = (uint4*)sW2;
    for (int i = threadIdx.x; i < 16 * W1K / 8; i += 1024) d2[i] = s2[i];
    if (threadIdx.x < 128) { sB0[threadIdx.x] = b0[threadIdx.x]; sB1[threadIdx.x] = b1[threadIdx.x]; }
    if (threadIdx.x < 16) sB2[threadIdx.x] = (threadIdx.x < 3) ? b2[threadIdx.x] : 0.f;
  }
  __syncthreads();

  const int wid = (int)(threadIdx.x >> 6), lane = (int)(threadIdx.x & 63);
  const int l15 = lane & 15, g = lane >> 4;
  unsigned short* myH = sH + wid * (16 * W1K);

#pragma unroll 1
  for (int t = 0; t < TPB; ++t) {
    int grp = blockIdx.x * TPB + t;
    if (grp >= ngroups) break;
    const int pt0 = grp * 256 + wid * 16;

    const unsigned short* fr = featB + (size_t)(pt0 + l15) * 96 + g * 8;
    bf16x8 cb0 = __builtin_nontemporal_load((const bf16x8*)(fr));
    bf16x8 cb1 = __builtin_nontemporal_load((const bf16x8*)(fr + 32));
    bf16x8 cb2 = __builtin_nontemporal_load((const bf16x8*)(fr + 64));

    // ---- GEMM1: D1[hid][pt] = W0^T x feat^T, K=96 ----
    f32x4 acc1[8];
#pragma unroll
    for (int m = 0; m < 8; m++) acc1[m] = (f32x4){0.f, 0.f, 0.f, 0.f};
#pragma unroll
    for (int m = 0; m < 8; m++) {
      bf16x8 a0 = *(const bf16x8*)(sW0 + (m * 16 + l15) * W0K + g * 8);
      acc1[m] = __builtin_amdgcn_mfma_f32_16x16x32_bf16(a0, cb0, acc1[m], 0, 0, 0);
      bf16x8 a1 = *(const bf16x8*)(sW0 + (m * 16 + l15) * W0K + 32 + g * 8);
      acc1[m] = __builtin_amdgcn_mfma_f32_16x16x32_bf16(a1, cb1, acc1[m], 0, 0, 0);
      bf16x8 a2 = *(const bf16x8*)(sW0 + (m * 16 + l15) * W0K + 64 + g * 8);
      acc1[m] = __builtin_amdgcn_mfma_f32_16x16x32_bf16(a2, cb2, acc1[m], 0, 0, 0);
    }
#pragma unroll
    for (int m = 0; m < 8; m++) {
      f32x4 bias = *(const f32x4*)(sB0 + m * 16 + g * 4);
      float h0 = fmaxf(acc1[m][0] + bias[0], 0.f);
      float h1 = fmaxf(acc1[m][1] + bias[1], 0.f);
      float h2 = fmaxf(acc1[m][2] + bias[2], 0.f);
      float h3 = fmaxf(acc1[m][3] + bias[3], 0.f);
      *(uint2*)(myH + l15 * W1K + m * 16 + g * 4) = make_uint2(pk_bf16(h0, h1), pk_bf16(h2, h3));
    }

    // ---- GEMM2: K=128 ----
    f32x4 acc2[8];
#pragma unroll
    for (int m = 0; m < 8; m++) acc2[m] = (f32x4){0.f, 0.f, 0.f, 0.f};
    const unsigned short* hb = myH + l15 * W1K + g * 8;
#pragma unroll
    for (int ks = 0; ks < 4; ks++) {
      bf16x8 bfrag = *(const bf16x8*)(hb + ks * 32);
#pragma unroll
      for (int m = 0; m < 8; m++) {
        bf16x8 afrag = *(const bf16x8*)(sW1 + (m * 16 + l15) * W1K + ks * 32 + g * 8);
        acc2[m] = __builtin_amdgcn_mfma_f32_16x16x32_bf16(afrag, bfrag, acc2[m], 0, 0, 0);
      }
    }
#pragma unroll
    for (int m = 0; m < 8; m++) {
      f32x4 bias = *(const f32x4*)(sB1 + m * 16 + g * 4);
      float h0 = fmaxf(acc2[m][0] + bias[0], 0.f);
      float h1 = fmaxf(acc2[m][1] + bias[1], 0.f);
      float h2 = fmaxf(acc2[m][2] + bias[2], 0.f);
      float h3 = fmaxf(acc2[m][3] + bias[3], 0.f);
      *(uint2*)(myH + l15 * W1K + m * 16 + g * 4) = make_uint2(pk_bf16(h0, h1), pk_bf16(h2, h3));
    }

    // ---- GEMM3: K=128, 1 tile ----
    f32x4 acc3 = (f32x4){0.f, 0.f, 0.f, 0.f};
#pragma unroll
    for (int ks = 0; ks < 4; ks++) {
      bf16x8 bfrag = *(const bf16x8*)(hb + ks * 32);
      bf16x8 afrag = *(const bf16x8*)(sW2 + l15 * W1K + ks * 32 + g * 8);
      acc3 = __builtin_amdgcn_mfma_f32_16x16x32_bf16(afrag, bfrag, acc3, 0, 0, 0);
    }
    if (g == 0) {   // rows 0..3 = channels; only 0..2 valid
      int orig = (int)sortedIdx[pt0 + l15];
      rgb[orig * 3 + 0] = sigm_(acc3[0] + sB2[0]);
      rgb[orig * 3 + 1] = sigm_(acc3[1] + sB2[1]);
      rgb[orig * 3 + 2] = sigm_(acc3[2] + sB2[2]);
    }
  }
}

// ============ per-ray scan + composite (1 wave / ray) ============
__global__ __launch_bounds__(256) void vox_scan_kernel(
    const float* __restrict__ alpha, const float* __restrict__ rgb,
    const int* __restrict__ ray_id, float* __restrict__ out, int M, int NR) {
  int wave = (int)((blockIdx.x * blockDim.x + threadIdx.x) >> 6);
  int lane = threadIdx.x & 63;
  if (wave >= NR) return;
  int r = wave;
  int lo = 0, hi = M;
  while (lo < hi) { int mid = (lo + hi) >> 1; if (ray_id[mid] < r) lo = mid + 1; else hi = mid; }
  int start = lo; hi = M;
  while (lo < hi) { int mid = (lo + hi) >> 1; if (ray_id[mid] < r + 1) lo = mid + 1; else hi = mid; }
  int end = lo;

  float carry = 0.f, cr = 0.f, cg = 0.f, cb = 0.f;
  for (int s = start; s < end; s += 64) {
    int idx = s + lane;
    bool valid = idx < end;
    float a = valid ? alpha[idx] : 0.f;
    float l = valid ? log1pf(-fminf(a, 1.f - 1e-7f)) : 0.f;
    float sc = l;
#pragma unroll
    for (int off = 1; off < 64; off <<= 1) {
      float t = __shfl_up(sc, (unsigned)off);
      if (lane >= off) sc += t;
    }
    if (valid) {
      float T = expf(carry + (sc - l));
      float w = a * T;
      cr = fmaf(w, rgb[3 * idx + 0], cr);
      cg = fmaf(w, rgb[3 * idx + 1], cg);
      cb = fmaf(w, rgb[3 * idx + 2], cb);
    }
    carry += __shfl(sc, 63);
  }
#pragma unroll
  for (int off = 32; off > 0; off >>= 1) {
    cr += __shfl_down(cr, (unsigned)off);
    cg += __shfl_down(cg, (unsigned)off);
    cb += __shfl_down(cb, (unsigned)off);
  }
  if (lane == 0) {
    float ail = expf(carry);
    out[3 * r + 0] = cr + ail;
    out[3 * r + 1] = cg + ail;
    out[3 * r + 2] = cb + ail;
  }
}

// ============ fallback (round-1 monolithic path, used if ws too small) ============
__global__ __launch_bounds__(256) void vox_transpose_w0(
    const float* __restrict__ w0, float* __restrict__ w0t) {
  for (int idx = threadIdx.x; idx < 128 * 80; idx += 256) {
    int j = idx / 80, k = idx - j * 80;
    w0t[idx] = (k < 75) ? w0[k * 128 + j] : 0.f;
  }
}

__global__ __launch_bounds__(256) void vox_point_kernel(
    const float* __restrict__ ray_pts, const float* __restrict__ rays_d,
    const float* __restrict__ sdf_vol, const float* __restrict__ k0_vol,
    const float* __restrict__ w0t, const float* __restrict__ b0,
    const float* __restrict__ w1, const float* __restrict__ b1,
    const float* __restrict__ w2, const float* __restrict__ b2,
    const float* __restrict__ s_val, const int* __restrict__ ray_id,
    float* __restrict__ alpha_out, float* __restrict__ rgb_out, int M) {
  int i = blockIdx.x * 256 + threadIdx.x;
  if (i >= M) return;
  float px = ray_pts[3 * i + 0], py = ray_pts[3 * i + 1], pz = ray_pts[3 * i + 2];
  const float SC = 0.5f * 159.f;
  float ux = fminf(fmaxf((px + 1.f) * SC, 0.f), 159.f);
  float uy = fminf(fmaxf((py + 1.f) * SC, 0.f), 159.f);
  float uz = fminf(fmaxf((pz + 1.f) * SC, 0.f), 159.f);
  int ix = min((int)ux, 158), iy = min((int)uy, 158), iz = min((int)uz, 158);
  float fx = ux - (float)ix, fy = uy - (float)iy, fz = uz - (float)iz;
  float wx0 = 1.f - fx, wy0 = 1.f - fy, wz0 = 1.f - fz;
  float w000 = wx0 * wy0 * wz0, w001 = wx0 * wy0 * fz;
  float w010 = wx0 * fy * wz0,  w011 = wx0 * fy * fz;
  float w100 = fx * wy0 * wz0,  w101 = fx * wy0 * fz;
  float w110 = fx * fy * wz0,   w111 = fx * fy * fz;
  int base = (ix * GRIDN + iy) * GRIDN + iz;
  const float* V = sdf_vol;
  float c000 = V[base],          c001 = V[base + 1];
  float c010 = V[base + SY],     c011 = V[base + SY + 1];
  float c100 = V[base + SX],     c101 = V[base + SX + 1];
  float c110 = V[base + SX + SY], c111 = V[base + SX + SY + 1];
  float xm00 = V[base - SX],          xm01 = V[base - SX + 1];
  float xm10 = V[base - SX + SY],     xm11 = V[base - SX + SY + 1];
  float xp00 = V[base + 2 * SX],      xp01 = V[base + 2 * SX + 1];
  float xp10 = V[base + 2 * SX + SY], xp11 = V[base + 2 * SX + SY + 1];
  float ym00 = V[base - SY],          ym01 = V[base - SY + 1];
  float ym10 = V[base + SX - SY],     ym11 = V[base + SX - SY + 1];
  float yp00 = V[base + 2 * SY],      yp01 = V[base + 2 * SY + 1];
  float yp10 = V[base + SX + 2 * SY], yp11 = V[base + SX + 2 * SY + 1];
  float zm00 = V[base - 1],           zm01 = V[base + SY - 1];
  float zm10 = V[base + SX - 1],      zm11 = V[base + SX + SY - 1];
  float zp00 = V[base + 2],           zp01 = V[base + SY + 2];
  float zp10 = V[base + SX + 2],      zp11 = V[base + SX + SY + 2];
  float sdf = w000 * c000 + w001 * c001 + w010 * c010 + w011 * c011 +
              w100 * c100 + w101 * c101 + w110 * c110 + w111 * c111;
  const float INV2H = 159.f / 4.f;
  float gx = (w000 * (c100 - xm00) + w001 * (c101 - xm01) +
              w010 * (c110 - xm10) + w011 * (c111 - xm11) +
              w100 * (xp00 - c000) + w101 * (xp01 - c001) +
              w110 * (xp10 - c010) + w111 * (xp11 - c011)) * INV2H;
  float gy = (w000 * (c010 - ym00) + w001 * (c011 - ym01) +
              w100 * (c110 - ym10) + w101 * (c111 - ym11) +
              w010 * (yp00 - c000) + w011 * (yp01 - c001) +
              w110 * (yp10 - c100) + w111 * (yp11 - c101)) * INV2H;
  float gz = (w000 * (c001 - zm00) + w010 * (c011 - zm01) +
              w100 * (c101 - zm10) + w110 * (c111 - zm11) +
              w001 * (zp00 - c000) + w011 * (zp01 - c010) +
              w101 * (zp10 - c100) + w111 * (zp11 - c110)) * INV2H;
  float ginv = 1.f / (sqrtf(gx * gx + gy * gy + gz * gz) + 1e-8f);
  float gnx = gx * ginv, gny = gy * ginv, gnz = gz * ginv;
  int rid = ray_id[i];
  float ddx = rays_d[3 * rid + 0], ddy = rays_d[3 * rid + 1], ddz = rays_d[3 * rid + 2];
  float true_cos = ddx * gnx + ddy * gny + ddz * gnz;
  float iter_cos = fminf(true_cos, 0.f);
  float inv_s = 1.f / s_val[0];
  float e = iter_cos * (DIST_C * 0.5f);
  float prev_cdf = sigm_((sdf - e) * inv_s);
  float next_cdf = sigm_((sdf + e) * inv_s);
  float alpha = fminf(fmaxf((prev_cdf - next_cdf + 1e-5f) / (prev_cdf + 1e-5f), 0.f), 1.f);
  alpha_out[i] = alpha;
  float feat[75];
  {
    const int offs[8] = {0, 1, SY, SY + 1, SX, SX + 1, SX + SY, SX + SY + 1};
    const float wts[8] = {w000, w001, w010, w011, w100, w101, w110, w111};
#pragma unroll
    for (int c = 0; c < 12; c++) {
      const float* kc = k0_vol + c * N3 + base;
      float acc = 0.f;
#pragma unroll
      for (int t = 0; t < 8; t++) acc = fmaf(wts[t], kc[offs[t]], acc);
      feat[c] = acc;
    }
  }
  float x01 = (px + 1.f) * 0.5f, y01 = (py + 1.f) * 0.5f, z01 = (pz + 1.f) * 0.5f;
  feat[12] = x01; feat[13] = y01; feat[14] = z01;
#pragma unroll
  for (int l = 0; l < 5; l++) {
    float f = (float)(1 << l), s, c;
    sincosf(x01 * f, &s, &c); feat[15 + l] = s; feat[30 + l] = c;
    sincosf(y01 * f, &s, &c); feat[20 + l] = s; feat[35 + l] = c;
    sincosf(z01 * f, &s, &c); feat[25 + l] = s; feat[40 + l] = c;
  }
  feat[45] = ddx; feat[46] = ddy; feat[47] = ddz;
#pragma unroll
  for (int l = 0; l < 4; l++) {
    float f = (float)(1 << l), s, c;
    sincosf(ddx * f, &s, &c); feat[48 + l] = s; feat[60 + l] = c;
    sincosf(ddy * f, &s, &c); feat[52 + l] = s; feat[64 + l] = c;
    sincosf(ddz * f, &s, &c); feat[56 + l] = s; feat[68 + l] = c;
  }
  feat[72] = gnx; feat[73] = gny; feat[74] = gnz;
  float rr = 0.f, rg = 0.f, rb = 0.f;
#pragma unroll 1
  for (int half = 0; half < 2; ++half) {
    float acc[64];
#pragma unroll
    for (int t = 0; t < 64; t++) acc[t] = b1[half * 64 + t];
#pragma unroll 1
    for (int j = 0; j < 128; ++j) {
      float h = b0[j];
      const float* wr = w0t + j * 80;
#pragma unroll
      for (int k = 0; k < 75; k++) h = fmaf(feat[k], wr[k], h);
      h = fmaxf(h, 0.f);
      const float* w1r = w1 + j * 128 + half * 64;
#pragma unroll
      for (int t = 0; t < 64; t++) acc[t] = fmaf(h, w1r[t], acc[t]);
    }
#pragma unroll
    for (int t = 0; t < 64; t++) {
      float h2 = fmaxf(acc[t], 0.f);
      int j2 = half * 64 + t;
      rr = fmaf(h2, w2[3 * j2 + 0], rr);
      rg = fmaf(h2, w2[3 * j2 + 1], rg);
      rb = fmaf(h2, w2[3 * j2 + 2], rb);
    }
  }
  rgb_out[3 * i + 0] = sigm_(rr + b2[0]);
  rgb_out[3 * i + 1] = sigm_(rg + b2[1]);
  rgb_out[3 * i + 2] = sigm_(rb + b2[2]);
}

extern "C" void kernel_launch(void* const* d_in, const int* in_sizes, int n_in,
                              void* d_out, int out_size, void* d_ws, size_t ws_size,
                              hipStream_t stream) {
  const float* ray_pts = (const float*)d_in[0];
  const float* rays_d  = (const float*)d_in[1];
  const float* sdf_vol = (const float*)d_in[2];
  const float* k0_vol  = (const float*)d_in[3];
  const float* w0      = (const float*)d_in[4];
  const float* b0      = (const float*)d_in[5];
  const float* w1      = (const float*)d_in[6];
  const float* b1      = (const float*)d_in[7];
  const float* w2      = (const float*)d_in[8];
  const float* b2      = (const float*)d_in[9];
  const float* s_val   = (const float*)d_in[10];
  const int*   ray_id  = (const int*)d_in[11];
  float* out = (float*)d_out;

  int M  = in_sizes[0] / 3;   // 1048576
  int NR = in_sizes[1] / 3;   // 8192

  char* ws = (char*)d_ws;
  size_t offVR   = 0;                                  // N3*32 combined records
  size_t offFeat = offVR + (size_t)N3 * 32;
  size_t offA    = offFeat + (size_t)M * 96 * 2;
  size_t offRgb  = offA + (size_t)M * 4;
  size_t offW0   = offRgb + (size_t)M * 12;
  size_t offW1   = offW0 + (size_t)128 * W0K * 2;
  size_t offW2   = offW1 + (size_t)128 * W1K * 2;
  size_t offSI   = offW2 + (size_t)16 * W1K * 2;
  size_t offHist = offSI + (size_t)M * 4;
  size_t offCur  = offHist + 512;
  size_t need    = offCur + 512;

  int nblocks = (M + 255) / 256;
  bool can_sort = (M % 256) == 0 && (nblocks % 8) == 0;

  if (ws_size >= need && can_sort) {
    unsigned short* VR = (unsigned short*)(ws + offVR);
    unsigned short* featB = (unsigned short*)(ws + offFeat);
    float* alpha_ws = (float*)(ws + offA);
    float* rgb_ws = (float*)(ws + offRgb);
    unsigned short* W0B = (unsigned short*)(ws + offW0);
    unsigned short* W1B = (unsigned short*)(ws + offW1);
    unsigned short* W2B = (unsigned short*)(ws + offW2);
    unsigned* sortedIdx = (unsigned*)(ws + offSI);
    unsigned* hist = (unsigned*)(ws + offHist);
    unsigned* cursor = (unsigned*)(ws + offCur);

    int ngroups = M / 256;
    vox_sort_zero<<<1, 128, 0, stream>>>(hist, cursor);
    vox_sort_hist<<<nblocks, 256, 0, stream>>>(ray_pts, hist, M);
    vox_sort_scan<<<1, 128, 0, stream>>>(hist, cursor);
    vox_sort_scatter<<<nblocks, 256, 0, stream>>>(ray_pts, cursor, sortedIdx, M);
    vox_repack_all<<<(N3 + 255) / 256, 256, 0, stream>>>(sdf_vol, k0_vol, VR);
    vox_repack_w<<<(128 * W1K + 255) / 256, 256, 0, stream>>>(w0, w1, w2, W0B, W1B, W2B);
    vox_gather_kernel<<<nblocks, 256, 0, stream>>>(
        ray_pts, rays_d, VR, s_val, ray_id, sortedIdx, alpha_ws, featB, M);
    vox_mlp_kernel<<<(ngroups + TPB - 1) / TPB, 1024, 0, stream>>>(
        featB, W0B, W1B, W2B, b0, b1, b2, sortedIdx, rgb_ws, ngroups);
    vox_scan_kernel<<<(NR * 64 + 255) / 256, 256, 0, stream>>>(
        alpha_ws, rgb_ws, ray_id, out, M, NR);
  } else {
    float* alpha_ws = (float*)ws;
    float* rgb_ws   = (float*)(ws + (size_t)M * 4);
    float* w0t_ws   = (float*)(ws + (size_t)M * 16);
    vox_transpose_w0<<<1, 256, 0, stream>>>(w0, w0t_ws);
    vox_point_kernel<<<(M + 255) / 256, 256, 0, stream>>>(
        ray_pts, rays_d, sdf_vol, k0_vol, w0t_ws, b0, w1, b1, w2, b2,
        s_val, ray_id, alpha_ws, rgb_ws, M);
    vox_scan_kernel<<<(NR * 64 + 255) / 256, 256, 0, stream>>>(
        alpha_ws, rgb_ws, ray_id, out, M, NR);
  }
}

// Round 14
// 491.378 us; speedup vs baseline: 4.2345x; 4.2345x over previous
//
#include <hip/hip_runtime.h>
#include <math.h>

#define GRIDN 160
#define N3 (160*160*160)
#define SX (160*160)
#define SY 160
#define DIST_C 0.005f
#define W0K 104   // sW0 row stride (ushorts), K=96 used
#define W1K 136   // sW1/sW2/sH row stride (ushorts), K=128 used
#define TPB 16    // groups (of 256 points) per MLP block -> grid = 256 = 1 block/CU
#define NBUCKET 125
#define CPAD 16   // u32 per bucket slot (64B line) to kill same-line atomic serialization

__device__ __forceinline__ float sigm_(float x) { return 1.f / (1.f + expf(-x)); }
__device__ __forceinline__ unsigned short f2bf(float x) {
  unsigned u = __builtin_bit_cast(unsigned, x);
  u = (u + 0x7fffu + ((u >> 16) & 1u)) >> 16;
  return (unsigned short)u;
}
__device__ __forceinline__ unsigned pk_bf16(float a, float b) {
  return (unsigned)f2bf(a) | ((unsigned)f2bf(b) << 16);
}
__device__ __forceinline__ float bf_lo(unsigned u) { return __builtin_bit_cast(float, u << 16); }
__device__ __forceinline__ float bf_hi(unsigned u) { return __builtin_bit_cast(float, u & 0xffff0000u); }
__device__ __forceinline__ unsigned short f2h(float x) {
  _Float16 h = (_Float16)x; return __builtin_bit_cast(unsigned short, h);
}
__device__ __forceinline__ float h_lo(unsigned u) {
  return (float)__builtin_bit_cast(_Float16, (unsigned short)(u & 0xffffu));
}
__device__ __forceinline__ float h_hi(unsigned u) {
  return (float)__builtin_bit_cast(_Float16, (unsigned short)(u >> 16));
}
__device__ __forceinline__ int voxel_ix(float p) {
  const float SC = 0.5f * 159.f;
  float u = fminf(fmaxf((p + 1.f) * SC, 0.f), 159.f);
  return min((int)u, 158);
}
__device__ __forceinline__ int bucket_key(float px, float py, float pz) {
  return ((voxel_ix(px) >> 5) * 5 + (voxel_ix(py) >> 5)) * 5 + (voxel_ix(pz) >> 5);
}

typedef __attribute__((ext_vector_type(8))) short bf16x8;
typedef __attribute__((ext_vector_type(4))) float f32x4;
typedef __attribute__((ext_vector_type(4))) unsigned u32x4;

// ==== fused repack -> 32B voxel record: [sdf,gx,gy,gz](f16) + k0 ch0..11 (bf16) ====
__global__ __launch_bounds__(256) void vox_repack_all(
    const float* __restrict__ V, const float* __restrict__ k0,
    unsigned short* __restrict__ VR) {
  int idx = blockIdx.x * 256 + threadIdx.x;
  if (idx >= N3) return;
  int z = idx % GRIDN; int t = idx / GRIDN; int y = t % GRIDN; int x = t / GRIDN;
  float v = V[idx];
  float xp = (x < 159) ? V[idx + SX] : v, xm = (x > 0) ? V[idx - SX] : v;
  float yp = (y < 159) ? V[idx + SY] : v, ym = (y > 0) ? V[idx - SY] : v;
  float zp = (z < 159) ? V[idx + 1]  : v, zm = (z > 0) ? V[idx - 1]  : v;
  float cx = (x > 0 && x < 159) ? (159.f / 4.f) : (159.f / 2.f);
  float cy = (y > 0 && y < 159) ? (159.f / 4.f) : (159.f / 2.f);
  float cz = (z > 0 && z < 159) ? (159.f / 4.f) : (159.f / 2.f);
  unsigned f0 = (unsigned)f2h(v) | ((unsigned)f2h((xp - xm) * cx) << 16);
  unsigned f1 = (unsigned)f2h((yp - ym) * cy) | ((unsigned)f2h((zp - zm) * cz) << 16);
  unsigned w[6];
#pragma unroll
  for (int j = 0; j < 6; j++) {
    float a = __builtin_nontemporal_load(k0 + (size_t)(2 * j) * N3 + idx);
    float b = __builtin_nontemporal_load(k0 + (size_t)(2 * j + 1) * N3 + idx);
    w[j] = pk_bf16(a, b);
  }
  u32x4* r = (u32x4*)(VR + (size_t)idx * 16);
  r[0] = (u32x4){f0, f1, w[0], w[1]};
  r[1] = (u32x4){w[2], w[3], w[4], w[5]};
}

// ============ repack weights -> transposed bf16 with padded strides ============
__global__ __launch_bounds__(256) void vox_repack_w(
    const float* __restrict__ w0, const float* __restrict__ w1, const float* __restrict__ w2,
    unsigned short* __restrict__ W0B, unsigned short* __restrict__ W1B,
    unsigned short* __restrict__ W2B) {
  int i = blockIdx.x * 256 + threadIdx.x;
  if (i < 128 * W0K) {                    // W0B[c][k] = w0[k][c], k<75
    int c = i / W0K, k = i - c * W0K;
    W0B[i] = (k < 75) ? f2bf(w0[k * 128 + c]) : (unsigned short)0;
  }
  if (i < 128 * W1K) {                    // W1B[c][k] = w1[k][c], k<128
    int c = i / W1K, k = i - c * W1K;
    W1B[i] = (k < 128) ? f2bf(w1[k * 128 + c]) : (unsigned short)0;
  }
  if (i < 16 * W1K) {                     // W2B[c][k] = w2[k][c], c<3, k<128
    int c = i / W1K, k = i - c * W1K;
    W2B[i] = (k < 128 && c < 3) ? f2bf(w2[k * 3 + c]) : (unsigned short)0;
  }
}

// ============ counting sort by 125 macro-cells (LDS-aggregated, padded cursors) ====
__global__ void vox_sort_zero(unsigned* __restrict__ hist, unsigned* __restrict__ cursor) {
  for (int i = threadIdx.x; i < NBUCKET * CPAD; i += 256) { hist[i] = 0; cursor[i] = 0; }
}
__global__ __launch_bounds__(256) void vox_sort_hist(
    const float* __restrict__ pts, unsigned* __restrict__ hist, int M) {
  __shared__ unsigned lh[NBUCKET];
  for (int b = threadIdx.x; b < NBUCKET; b += 256) lh[b] = 0;
  __syncthreads();
  int i = blockIdx.x * 256 + threadIdx.x;
  if (i < M) {
    int key = bucket_key(pts[3 * i], pts[3 * i + 1], pts[3 * i + 2]);
    atomicAdd(&lh[key], 1u);
  }
  __syncthreads();
  for (int b = threadIdx.x; b < NBUCKET; b += 256)
    if (lh[b]) atomicAdd(&hist[b * CPAD], lh[b]);
}
__global__ void vox_sort_scan(const unsigned* __restrict__ hist, unsigned* __restrict__ cursor) {
  __shared__ unsigned s[128];
  int t = threadIdx.x;
  unsigned own = (t < NBUCKET) ? hist[t * CPAD] : 0;
  s[t] = own; __syncthreads();
  for (int off = 1; off < 128; off <<= 1) {
    unsigned v = (t >= off) ? s[t - off] : 0;
    __syncthreads(); s[t] += v; __syncthreads();
  }
  if (t < NBUCKET) cursor[t * CPAD] = s[t] - own;   // exclusive prefix
}
__global__ __launch_bounds__(256) void vox_sort_scatter(
    const float* __restrict__ pts, unsigned* __restrict__ cursor,
    unsigned* __restrict__ sortedIdx, int M) {
  __shared__ unsigned lh[NBUCKET];
  __shared__ unsigned lbase[NBUCKET];
  for (int b = threadIdx.x; b < NBUCKET; b += 256) lh[b] = 0;
  __syncthreads();
  int i = blockIdx.x * 256 + threadIdx.x;
  int key = 0; unsigned lrank = 0;
  if (i < M) {
    key = bucket_key(pts[3 * i], pts[3 * i + 1], pts[3 * i + 2]);
    lrank = atomicAdd(&lh[key], 1u);          // LDS atomic: local rank
  }
  __syncthreads();
  for (int b = threadIdx.x; b < NBUCKET; b += 256)
    lbase[b] = lh[b] ? atomicAdd(&cursor[b * CPAD], lh[b]) : 0;  // 1 global atomic/bucket/block
  __syncthreads();
  if (i < M) sortedIdx[lbase[key] + lrank] = (unsigned)i;
}

// ============ gather (sorted order): trilerps + alpha + feat[96] bf16 ============
__global__ __launch_bounds__(256) void vox_gather_kernel(
    const float* __restrict__ ray_pts, const float* __restrict__ rays_d,
    const unsigned short* __restrict__ VR,
    const float* __restrict__ s_val, const int* __restrict__ ray_id,
    const unsigned* __restrict__ sortedIdx,
    float* __restrict__ alpha_out, unsigned short* __restrict__ featB, int M) {
  // XCD-contiguous swizzle: each XCD gets a contiguous sorted range (bijective;
  // launcher guarantees gridDim % 8 == 0).
  int nb = (int)gridDim.x;
  int swz = ((int)blockIdx.x % 8) * (nb / 8) + (int)blockIdx.x / 8;
  int j = swz * 256 + (int)threadIdx.x;
  if (j >= M) return;
  int i = (int)sortedIdx[j];

  float px = ray_pts[3 * i + 0], py = ray_pts[3 * i + 1], pz = ray_pts[3 * i + 2];
  const float SC = 0.5f * 159.f;
  float ux = fminf(fmaxf((px + 1.f) * SC, 0.f), 159.f);
  float uy = fminf(fmaxf((py + 1.f) * SC, 0.f), 159.f);
  float uz = fminf(fmaxf((pz + 1.f) * SC, 0.f), 159.f);
  int ix = min((int)ux, 158), iy = min((int)uy, 158), iz = min((int)uz, 158);
  float fx = ux - (float)ix, fy = uy - (float)iy, fz = uz - (float)iz;
  float wx0 = 1.f - fx, wy0 = 1.f - fy, wz0 = 1.f - fz;
  float wxy[4];
  wxy[0] = wx0 * wy0; wxy[1] = wx0 * fy; wxy[2] = fx * wy0; wxy[3] = fx * fy;
  const int pairoff[4] = {0, SY, SX, SX + SY};
  int base = (ix * GRIDN + iy) * GRIDN + iz;

  u32x4 q[4][4];
#pragma unroll
  for (int t = 0; t < 4; t++) {
    const u32x4* p = (const u32x4*)(VR + (size_t)(base + pairoff[t]) * 16);
    q[t][0] = p[0]; q[t][1] = p[1]; q[t][2] = p[2]; q[t][3] = p[3];
  }

  float sdf = 0.f, gx = 0.f, gy = 0.f, gz = 0.f;
  float k[12];
#pragma unroll
  for (int j2 = 0; j2 < 12; j2++) k[j2] = 0.f;
#pragma unroll
  for (int t = 0; t < 4; t++) {
    float w0z = wxy[t] * wz0, w1z = wxy[t] * fz;
    sdf = fmaf(w0z, h_lo(q[t][0].x), sdf);
    gx  = fmaf(w0z, h_hi(q[t][0].x), gx);
    gy  = fmaf(w0z, h_lo(q[t][0].y), gy);
    gz  = fmaf(w0z, h_hi(q[t][0].y), gz);
    k[0]  = fmaf(w0z, bf_lo(q[t][0].z), k[0]);
    k[1]  = fmaf(w0z, bf_hi(q[t][0].z), k[1]);
    k[2]  = fmaf(w0z, bf_lo(q[t][0].w), k[2]);
    k[3]  = fmaf(w0z, bf_hi(q[t][0].w), k[3]);
    k[4]  = fmaf(w0z, bf_lo(q[t][1].x), k[4]);
    k[5]  = fmaf(w0z, bf_hi(q[t][1].x), k[5]);
    k[6]  = fmaf(w0z, bf_lo(q[t][1].y), k[6]);
    k[7]  = fmaf(w0z, bf_hi(q[t][1].y), k[7]);
    k[8]  = fmaf(w0z, bf_lo(q[t][1].z), k[8]);
    k[9]  = fmaf(w0z, bf_hi(q[t][1].z), k[9]);
    k[10] = fmaf(w0z, bf_lo(q[t][1].w), k[10]);
    k[11] = fmaf(w0z, bf_hi(q[t][1].w), k[11]);
    sdf = fmaf(w1z, h_lo(q[t][2].x), sdf);
    gx  = fmaf(w1z, h_hi(q[t][2].x), gx);
    gy  = fmaf(w1z, h_lo(q[t][2].y), gy);
    gz  = fmaf(w1z, h_hi(q[t][2].y), gz);
    k[0]  = fmaf(w1z, bf_lo(q[t][2].z), k[0]);
    k[1]  = fmaf(w1z, bf_hi(q[t][2].z), k[1]);
    k[2]  = fmaf(w1z, bf_lo(q[t][2].w), k[2]);
    k[3]  = fmaf(w1z, bf_hi(q[t][2].w), k[3]);
    k[4]  = fmaf(w1z, bf_lo(q[t][3].x), k[4]);
    k[5]  = fmaf(w1z, bf_hi(q[t][3].x), k[5]);
    k[6]  = fmaf(w1z, bf_lo(q[t][3].y), k[6]);
    k[7]  = fmaf(w1z, bf_hi(q[t][3].y), k[7]);
    k[8]  = fmaf(w1z, bf_lo(q[t][3].z), k[8]);
    k[9]  = fmaf(w1z, bf_hi(q[t][3].z), k[9]);
    k[10] = fmaf(w1z, bf_lo(q[t][3].w), k[10]);
    k[11] = fmaf(w1z, bf_hi(q[t][3].w), k[11]);
  }
  float ginv = 1.f / (sqrtf(gx * gx + gy * gy + gz * gz) + 1e-8f);
  float gnx = gx * ginv, gny = gy * ginv, gnz = gz * ginv;

  int rid = ray_id[i];
  float ddx = rays_d[3 * rid + 0], ddy = rays_d[3 * rid + 1], ddz = rays_d[3 * rid + 2];

  float true_cos = ddx * gnx + ddy * gny + ddz * gnz;
  float iter_cos = fminf(true_cos, 0.f);
  float inv_s = 1.f / s_val[0];
  float e = iter_cos * (DIST_C * 0.5f);
  float prev_cdf = sigm_((sdf - e) * inv_s);
  float next_cdf = sigm_((sdf + e) * inv_s);
  float alpha = (prev_cdf - next_cdf + 1e-5f) / (prev_cdf + 1e-5f);
  alpha_out[i] = fminf(fmaxf(alpha, 0.f), 1.f);

  float feat[75];
#pragma unroll
  for (int j2 = 0; j2 < 12; j2++) feat[j2] = k[j2];

  float x01 = (px + 1.f) * 0.5f, y01 = (py + 1.f) * 0.5f, z01 = (pz + 1.f) * 0.5f;
  feat[12] = x01; feat[13] = y01; feat[14] = z01;
#pragma unroll
  for (int l = 0; l < 5; l++) {
    float f = (float)(1 << l), s, c;
    sincosf(x01 * f, &s, &c); feat[15 + l] = s; feat[30 + l] = c;
    sincosf(y01 * f, &s, &c); feat[20 + l] = s; feat[35 + l] = c;
    sincosf(z01 * f, &s, &c); feat[25 + l] = s; feat[40 + l] = c;
  }
  feat[45] = ddx; feat[46] = ddy; feat[47] = ddz;
#pragma unroll
  for (int l = 0; l < 4; l++) {
    float f = (float)(1 << l), s, c;
    sincosf(ddx * f, &s, &c); feat[48 + l] = s; feat[60 + l] = c;
    sincosf(ddy * f, &s, &c); feat[52 + l] = s; feat[64 + l] = c;
    sincosf(ddz * f, &s, &c); feat[56 + l] = s; feat[68 + l] = c;
  }
  feat[72] = gnx; feat[73] = gny; feat[74] = gnz;

  unsigned pw[48];
#pragma unroll
  for (int wv = 0; wv < 37; wv++) pw[wv] = pk_bf16(feat[2 * wv], feat[2 * wv + 1]);
  pw[37] = pk_bf16(feat[74], 0.f);
#pragma unroll
  for (int wv = 38; wv < 48; wv++) pw[wv] = 0u;
  u32x4* fb = (u32x4*)(featB + (size_t)j * 96);
#pragma unroll
  for (int q2 = 0; q2 < 12; q2++)
    fb[q2] = (u32x4){pw[4 * q2], pw[4 * q2 + 1], pw[4 * q2 + 2], pw[4 * q2 + 3]};
}

// ======== MFMA MLP: 1024 thr = 16 waves share one weight staging ========
__global__ __launch_bounds__(1024, 1) void vox_mlp_kernel(
    const unsigned short* __restrict__ featB,
    const unsigned short* __restrict__ W0B, const unsigned short* __restrict__ W1B,
    const unsigned short* __restrict__ W2B,
    const float* __restrict__ b0, const float* __restrict__ b1,
    const float* __restrict__ b2, const unsigned* __restrict__ sortedIdx,
    float* __restrict__ rgb, int ngroups) {
  __shared__ __align__(16) unsigned short sW0[128 * W0K];
  __shared__ __align__(16) unsigned short sW1[128 * W1K];
  __shared__ __align__(16) unsigned short sW2[16 * W1K];
  __shared__ __align__(16) unsigned short sH[16 * 16 * W1K];
  __shared__ __align__(16) float sB0[128], sB1[128], sB2[16];

  {
    const uint4* s0 = (const uint4*)W0B; uint4* d0 = (uint4*)sW0;
    for (int i = threadIdx.x; i < 128 * W0K / 8; i += 1024) d0[i] = s0[i];
    const uint4* s1 = (const uint4*)W1B; uint4* d1 = (uint4*)sW1;
    for (int i = threadIdx.x; i < 128 * W1K / 8; i += 1024) d1[i] = s1[i];
    const uint4* s2 = (const uint4*)W2B; uint4* d2 = (uint4*)sW2;
    for (int i = threadIdx.x; i < 16 * W1K / 8; i += 1024) d2[i] = s2[i];
    if (threadIdx.x < 128) { sB0[threadIdx.x] = b0[threadIdx.x]; sB1[threadIdx.x] = b1[threadIdx.x]; }
    if (threadIdx.x < 16) sB2[threadIdx.x] = (threadIdx.x < 3) ? b2[threadIdx.x] : 0.f;
  }
  __syncthreads();

  const int wid = (int)(threadIdx.x >> 6), lane = (int)(threadIdx.x & 63);
  const int l15 = lane & 15, g = lane >> 4;
  unsigned short* myH = sH + wid * (16 * W1K);

#pragma unroll 1
  for (int t = 0; t < TPB; ++t) {
    int grp = blockIdx.x * TPB + t;
    if (grp >= ngroups) break;
    const int pt0 = grp * 256 + wid * 16;

    const unsigned short* fr = featB + (size_t)(pt0 + l15) * 96 + g * 8;
    bf16x8 cb0 = __builtin_nontemporal_load((const bf16x8*)(fr));
    bf16x8 cb1 = __builtin_nontemporal_load((const bf16x8*)(fr + 32));
    bf16x8 cb2 = __builtin_nontemporal_load((const bf16x8*)(fr + 64));

    // ---- GEMM1: K=96 ----
    f32x4 acc1[8];
#pragma unroll
    for (int m = 0; m < 8; m++) acc1[m] = (f32x4){0.f, 0.f, 0.f, 0.f};
#pragma unroll
    for (int m = 0; m < 8; m++) {
      bf16x8 a0 = *(const bf16x8*)(sW0 + (m * 16 + l15) * W0K + g * 8);
      acc1[m] = __builtin_amdgcn_mfma_f32_16x16x32_bf16(a0, cb0, acc1[m], 0, 0, 0);
      bf16x8 a1 = *(const bf16x8*)(sW0 + (m * 16 + l15) * W0K + 32 + g * 8);
      acc1[m] = __builtin_amdgcn_mfma_f32_16x16x32_bf16(a1, cb1, acc1[m], 0, 0, 0);
      bf16x8 a2 = *(const bf16x8*)(sW0 + (m * 16 + l15) * W0K + 64 + g * 8);
      acc1[m] = __builtin_amdgcn_mfma_f32_16x16x32_bf16(a2, cb2, acc1[m], 0, 0, 0);
    }
#pragma unroll
    for (int m = 0; m < 8; m++) {
      f32x4 bias = *(const f32x4*)(sB0 + m * 16 + g * 4);
      float h0 = fmaxf(acc1[m][0] + bias[0], 0.f);
      float h1 = fmaxf(acc1[m][1] + bias[1], 0.f);
      float h2 = fmaxf(acc1[m][2] + bias[2], 0.f);
      float h3 = fmaxf(acc1[m][3] + bias[3], 0.f);
      *(uint2*)(myH + l15 * W1K + m * 16 + g * 4) = make_uint2(pk_bf16(h0, h1), pk_bf16(h2, h3));
    }

    // ---- GEMM2: K=128 ----
    f32x4 acc2[8];
#pragma unroll
    for (int m = 0; m < 8; m++) acc2[m] = (f32x4){0.f, 0.f, 0.f, 0.f};
    const unsigned short* hb = myH + l15 * W1K + g * 8;
#pragma unroll
    for (int ks = 0; ks < 4; ks++) {
      bf16x8 bfrag = *(const bf16x8*)(hb + ks * 32);
#pragma unroll
      for (int m = 0; m < 8; m++) {
        bf16x8 afrag = *(const bf16x8*)(sW1 + (m * 16 + l15) * W1K + ks * 32 + g * 8);
        acc2[m] = __builtin_amdgcn_mfma_f32_16x16x32_bf16(afrag, bfrag, acc2[m], 0, 0, 0);
      }
    }
#pragma unroll
    for (int m = 0; m < 8; m++) {
      f32x4 bias = *(const f32x4*)(sB1 + m * 16 + g * 4);
      float h0 = fmaxf(acc2[m][0] + bias[0], 0.f);
      float h1 = fmaxf(acc2[m][1] + bias[1], 0.f);
      float h2 = fmaxf(acc2[m][2] + bias[2], 0.f);
      float h3 = fmaxf(acc2[m][3] + bias[3], 0.f);
      *(uint2*)(myH + l15 * W1K + m * 16 + g * 4) = make_uint2(pk_bf16(h0, h1), pk_bf16(h2, h3));
    }

    // ---- GEMM3: K=128, 1 tile ----
    f32x4 acc3 = (f32x4){0.f, 0.f, 0.f, 0.f};
#pragma unroll
    for (int ks = 0; ks < 4; ks++) {
      bf16x8 bfrag = *(const bf16x8*)(hb + ks * 32);
      bf16x8 afrag = *(const bf16x8*)(sW2 + l15 * W1K + ks * 32 + g * 8);
      acc3 = __builtin_amdgcn_mfma_f32_16x16x32_bf16(afrag, bfrag, acc3, 0, 0, 0);
    }
    if (g == 0) {
      int orig = (int)sortedIdx[pt0 + l15];
      rgb[orig * 3 + 0] = sigm_(acc3[0] + sB2[0]);
      rgb[orig * 3 + 1] = sigm_(acc3[1] + sB2[1]);
      rgb[orig * 3 + 2] = sigm_(acc3[2] + sB2[2]);
    }
  }
}

// ============ per-ray scan + composite (1 wave / ray) ============
__global__ __launch_bounds__(256) void vox_scan_kernel(
    const float* __restrict__ alpha, const float* __restrict__ rgb,
    const int* __restrict__ ray_id, float* __restrict__ out, int M, int NR) {
  int wave = (int)((blockIdx.x * blockDim.x + threadIdx.x) >> 6);
  int lane = threadIdx.x & 63;
  if (wave >= NR) return;
  int r = wave;
  int lo = 0, hi = M;
  while (lo < hi) { int mid = (lo + hi) >> 1; if (ray_id[mid] < r) lo = mid + 1; else hi = mid; }
  int start = lo; hi = M;
  while (lo < hi) { int mid = (lo + hi) >> 1; if (ray_id[mid] < r + 1) lo = mid + 1; else hi = mid; }
  int end = lo;

  float carry = 0.f, cr = 0.f, cg = 0.f, cb = 0.f;
  for (int s = start; s < end; s += 64) {
    int idx = s + lane;
    bool valid = idx < end;
    float a = valid ? alpha[idx] : 0.f;
    float l = valid ? log1pf(-fminf(a, 1.f - 1e-7f)) : 0.f;
    float sc = l;
#pragma unroll
    for (int off = 1; off < 64; off <<= 1) {
      float t = __shfl_up(sc, (unsigned)off);
      if (lane >= off) sc += t;
    }
    if (valid) {
      float T = expf(carry + (sc - l));
      float w = a * T;
      cr = fmaf(w, rgb[3 * idx + 0], cr);
      cg = fmaf(w, rgb[3 * idx + 1], cg);
      cb = fmaf(w, rgb[3 * idx + 2], cb);
    }
    carry += __shfl(sc, 63);
  }
#pragma unroll
  for (int off = 32; off > 0; off >>= 1) {
    cr += __shfl_down(cr, (unsigned)off);
    cg += __shfl_down(cg, (unsigned)off);
    cb += __shfl_down(cb, (unsigned)off);
  }
  if (lane == 0) {
    float ail = expf(carry);
    out[3 * r + 0] = cr + ail;
    out[3 * r + 1] = cg + ail;
    out[3 * r + 2] = cb + ail;
  }
}

// ============ fallback (round-1 monolithic path, used if ws too small) ============
__global__ __launch_bounds__(256) void vox_transpose_w0(
    const float* __restrict__ w0, float* __restrict__ w0t) {
  for (int idx = threadIdx.x; idx < 128 * 80; idx += 256) {
    int j = idx / 80, k = idx - j * 80;
    w0t[idx] = (k < 75) ? w0[k * 128 + j] : 0.f;
  }
}

__global__ __launch_bounds__(256) void vox_point_kernel(
    const float* __restrict__ ray_pts, const float* __restrict__ rays_d,
    const float* __restrict__ sdf_vol, const float* __restrict__ k0_vol,
    const float* __restrict__ w0t, const float* __restrict__ b0,
    const float* __restrict__ w1, const float* __restrict__ b1,
    const float* __restrict__ w2, const float* __restrict__ b2,
    const float* __restrict__ s_val, const int* __restrict__ ray_id,
    float* __restrict__ alpha_out, float* __restrict__ rgb_out, int M) {
  int i = blockIdx.x * 256 + threadIdx.x;
  if (i >= M) return;
  float px = ray_pts[3 * i + 0], py = ray_pts[3 * i + 1], pz = ray_pts[3 * i + 2];
  const float SC = 0.5f * 159.f;
  float ux = fminf(fmaxf((px + 1.f) * SC, 0.f), 159.f);
  float uy = fminf(fmaxf((py + 1.f) * SC, 0.f), 159.f);
  float uz = fminf(fmaxf((pz + 1.f) * SC, 0.f), 159.f);
  int ix = min((int)ux, 158), iy = min((int)uy, 158), iz = min((int)uz, 158);
  float fx = ux - (float)ix, fy = uy - (float)iy, fz = uz - (float)iz;
  float wx0 = 1.f - fx, wy0 = 1.f - fy, wz0 = 1.f - fz;
  float w000 = wx0 * wy0 * wz0, w001 = wx0 * wy0 * fz;
  float w010 = wx0 * fy * wz0,  w011 = wx0 * fy * fz;
  float w100 = fx * wy0 * wz0,  w101 = fx * wy0 * fz;
  float w110 = fx * fy * wz0,   w111 = fx * fy * fz;
  int base = (ix * GRIDN + iy) * GRIDN + iz;
  const float* V = sdf_vol;
  float c000 = V[base],          c001 = V[base + 1];
  float c010 = V[base + SY],     c011 = V[base + SY + 1];
  float c100 = V[base + SX],     c101 = V[base + SX + 1];
  float c110 = V[base + SX + SY], c111 = V[base + SX + SY + 1];
  float xm00 = V[base - SX],          xm01 = V[base - SX + 1];
  float xm10 = V[base - SX + SY],     xm11 = V[base - SX + SY + 1];
  float xp00 = V[base + 2 * SX],      xp01 = V[base + 2 * SX + 1];
  float xp10 = V[base + 2 * SX + SY], xp11 = V[base + 2 * SX + SY + 1];
  float ym00 = V[base - SY],          ym01 = V[base - SY + 1];
  float ym10 = V[base + SX - SY],     ym11 = V[base + SX - SY + 1];
  float yp00 = V[base + 2 * SY],      yp01 = V[base + 2 * SY + 1];
  float yp10 = V[base + SX + 2 * SY], yp11 = V[base + SX + 2 * SY + 1];
  float zm00 = V[base - 1],           zm01 = V[base + SY - 1];
  float zm10 = V[base + SX - 1],      zm11 = V[base + SX + SY - 1];
  float zp00 = V[base + 2],           zp01 = V[base + SY + 2];
  float zp10 = V[base + SX + 2],      zp11 = V[base + SX + SY + 2];
  float sdf = w000 * c000 + w001 * c001 + w010 * c010 + w011 * c011 +
              w100 * c100 + w101 * c101 + w110 * c110 + w111 * c111;
  const float INV2H = 159.f / 4.f;
  float gx = (w000 * (c100 - xm00) + w001 * (c101 - xm01) +
              w010 * (c110 - xm10) + w011 * (c111 - xm11) +
              w100 * (xp00 - c000) + w101 * (xp01 - c001) +
              w110 * (xp10 - c010) + w111 * (xp11 - c011)) * INV2H;
  float gy = (w000 * (c010 - ym00) + w001 * (c011 - ym01) +
              w100 * (c110 - ym10) + w101 * (c111 - ym11) +
              w010 * (yp00 - c000) + w011 * (yp01 - c001) +
              w110 * (yp10 - c100) + w111 * (yp11 - c101)) * INV2H;
  float gz = (w000 * (c001 - zm00) + w010 * (c011 - zm01) +
              w100 * (c101 - zm10) + w110 * (c111 - zm11) +
              w001 * (zp00 - c000) + w011 * (zp01 - c010) +
              w101 * (zp10 - c100) + w111 * (zp11 - c110)) * INV2H;
  float ginv = 1.f / (sqrtf(gx * gx + gy * gy + gz * gz) + 1e-8f);
  float gnx = gx * ginv, gny = gy * ginv, gnz = gz * ginv;
  int rid = ray_id[i];
  float ddx = rays_d[3 * rid + 0], ddy = rays_d[3 * rid + 1], ddz = rays_d[3 * rid + 2];
  float true_cos = ddx * gnx + ddy * gny + ddz * gnz;
  float iter_cos = fminf(true_cos, 0.f);
  float inv_s = 1.f / s_val[0];
  float e = iter_cos * (DIST_C * 0.5f);
  float prev_cdf = sigm_((sdf - e) * inv_s);
  float next_cdf = sigm_((sdf + e) * inv_s);
  float alpha = fminf(fmaxf((prev_cdf - next_cdf + 1e-5f) / (prev_cdf + 1e-5f), 0.f), 1.f);
  alpha_out[i] = alpha;
  float feat[75];
  {
    const int offs[8] = {0, 1, SY, SY + 1, SX, SX + 1, SX + SY, SX + SY + 1};
    const float wts[8] = {w000, w001, w010, w011, w100, w101, w110, w111};
#pragma unroll
    for (int c = 0; c < 12; c++) {
      const float* kc = k0_vol + c * N3 + base;
      float acc = 0.f;
#pragma unroll
      for (int t = 0; t < 8; t++) acc = fmaf(wts[t], kc[offs[t]], acc);
      feat[c] = acc;
    }
  }
  float x01 = (px + 1.f) * 0.5f, y01 = (py + 1.f) * 0.5f, z01 = (pz + 1.f) * 0.5f;
  feat[12] = x01; feat[13] = y01; feat[14] = z01;
#pragma unroll
  for (int l = 0; l < 5; l++) {
    float f = (float)(1 << l), s, c;
    sincosf(x01 * f, &s, &c); feat[15 + l] = s; feat[30 + l] = c;
    sincosf(y01 * f, &s, &c); feat[20 + l] = s; feat[35 + l] = c;
    sincosf(z01 * f, &s, &c); feat[25 + l] = s; feat[40 + l] = c;
  }
  feat[45] = ddx; feat[46] = ddy; feat[47] = ddz;
#pragma unroll
  for (int l = 0; l < 4; l++) {
    float f = (float)(1 << l), s, c;
    sincosf(ddx * f, &s, &c); feat[48 + l] = s; feat[60 + l] = c;
    sincosf(ddy * f, &s, &c); feat[52 + l] = s; feat[64 + l] = c;
    sincosf(ddz * f, &s, &c); feat[56 + l] = s; feat[68 + l] = c;
  }
  feat[72] = gnx; feat[73] = gny; feat[74] = gnz;
  float rr = 0.f, rg = 0.f, rb = 0.f;
#pragma unroll 1
  for (int half = 0; half < 2; ++half) {
    float acc[64];
#pragma unroll
    for (int t = 0; t < 64; t++) acc[t] = b1[half * 64 + t];
#pragma unroll 1
    for (int j = 0; j < 128; ++j) {
      float h = b0[j];
      const float* wr = w0t + j * 80;
#pragma unroll
      for (int k = 0; k < 75; k++) h = fmaf(feat[k], wr[k], h);
      h = fmaxf(h, 0.f);
      const float* w1r = w1 + j * 128 + half * 64;
#pragma unroll
      for (int t = 0; t < 64; t++) acc[t] = fmaf(h, w1r[t], acc[t]);
    }
#pragma unroll
    for (int t = 0; t < 64; t++) {
      float h2 = fmaxf(acc[t], 0.f);
      int j2 = half * 64 + t;
      rr = fmaf(h2, w2[3 * j2 + 0], rr);
      rg = fmaf(h2, w2[3 * j2 + 1], rg);
      rb = fmaf(h2, w2[3 * j2 + 2], rb);
    }
  }
  rgb_out[3 * i + 0] = sigm_(rr + b2[0]);
  rgb_out[3 * i + 1] = sigm_(rg + b2[1]);
  rgb_out[3 * i + 2] = sigm_(rb + b2[2]);
}

extern "C" void kernel_launch(void* const* d_in, const int* in_sizes, int n_in,
                              void* d_out, int out_size, void* d_ws, size_t ws_size,
                              hipStream_t stream) {
  const float* ray_pts = (const float*)d_in[0];
  const float* rays_d  = (const float*)d_in[1];
  const float* sdf_vol = (const float*)d_in[2];
  const float* k0_vol  = (const float*)d_in[3];
  const float* w0      = (const float*)d_in[4];
  const float* b0      = (const float*)d_in[5];
  const float* w1      = (const float*)d_in[6];
  const float* b1      = (const float*)d_in[7];
  const float* w2      = (const float*)d_in[8];
  const float* b2      = (const float*)d_in[9];
  const float* s_val   = (const float*)d_in[10];
  const int*   ray_id  = (const int*)d_in[11];
  float* out = (float*)d_out;

  int M  = in_sizes[0] / 3;   // 1048576
  int NR = in_sizes[1] / 3;   // 8192

  char* ws = (char*)d_ws;
  size_t offVR   = 0;                                  // N3*32 combined records
  size_t offFeat = offVR + (size_t)N3 * 32;
  size_t offA    = offFeat + (size_t)M * 96 * 2;
  size_t offRgb  = offA + (size_t)M * 4;
  size_t offW0   = offRgb + (size_t)M * 12;
  size_t offW1   = offW0 + (size_t)128 * W0K * 2;
  size_t offW2   = offW1 + (size_t)128 * W1K * 2;
  size_t offSI   = offW2 + (size_t)16 * W1K * 2;
  size_t offHist = offSI + (size_t)M * 4;
  size_t offCur  = offHist + (size_t)NBUCKET * CPAD * 4;
  size_t need    = offCur + (size_t)NBUCKET * CPAD * 4;

  int nblocks = (M + 255) / 256;
  bool can_sort = (M % 256) == 0 && (nblocks % 8) == 0;

  if (ws_size >= need && can_sort) {
    unsigned short* VR = (unsigned short*)(ws + offVR);
    unsigned short* featB = (unsigned short*)(ws + offFeat);
    float* alpha_ws = (float*)(ws + offA);
    float* rgb_ws = (float*)(ws + offRgb);
    unsigned short* W0B = (unsigned short*)(ws + offW0);
    unsigned short* W1B = (unsigned short*)(ws + offW1);
    unsigned short* W2B = (unsigned short*)(ws + offW2);
    unsigned* sortedIdx = (unsigned*)(ws + offSI);
    unsigned* hist = (unsigned*)(ws + offHist);
    unsigned* cursor = (unsigned*)(ws + offCur);

    int ngroups = M / 256;
    vox_sort_zero<<<1, 256, 0, stream>>>(hist, cursor);
    vox_sort_hist<<<nblocks, 256, 0, stream>>>(ray_pts, hist, M);
    vox_sort_scan<<<1, 128, 0, stream>>>(hist, cursor);
    vox_sort_scatter<<<nblocks, 256, 0, stream>>>(ray_pts, cursor, sortedIdx, M);
    vox_repack_all<<<(N3 + 255) / 256, 256, 0, stream>>>(sdf_vol, k0_vol, VR);
    vox_repack_w<<<(128 * W1K + 255) / 256, 256, 0, stream>>>(w0, w1, w2, W0B, W1B, W2B);
    vox_gather_kernel<<<nblocks, 256, 0, stream>>>(
        ray_pts, rays_d, VR, s_val, ray_id, sortedIdx, alpha_ws, featB, M);
    vox_mlp_kernel<<<(ngroups + TPB - 1) / TPB, 1024, 0, stream>>>(
        featB, W0B, W1B, W2B, b0, b1, b2, sortedIdx, rgb_ws, ngroups);
    vox_scan_kernel<<<(NR * 64 + 255) / 256, 256, 0, stream>>>(
        alpha_ws, rgb_ws, ray_id, out, M, NR);
  } else {
    float* alpha_ws = (float*)ws;
    float* rgb_ws   = (float*)(ws + (size_t)M * 4);
    float* w0t_ws   = (float*)(ws + (size_t)M * 16);
    vox_transpose_w0<<<1, 256, 0, stream>>>(w0, w0t_ws);
    vox_point_kernel<<<(M + 255) / 256, 256, 0, stream>>>(
        ray_pts, rays_d, sdf_vol, k0_vol, w0t_ws, b0, w1, b1, w2, b2,
        s_val, ray_id, alpha_ws, rgb_ws, M);
    vox_scan_kernel<<<(NR * 64 + 255) / 256, 256, 0, stream>>>(
        alpha_ws, rgb_ws, ray_id, out, M, NR);
  }
}

// Round 15
// 345.515 us; speedup vs baseline: 6.0222x; 1.4222x over previous
//
#include <hip/hip_runtime.h>
#include <math.h>

#define GRIDN 160
#define N3 (160*160*160)
#define SX (160*160)
#define SY 160
#define DIST_C 0.005f
#define W0K 104   // sW0 row stride (ushorts), K=96 used
#define W1K 136   // sW1/sW2/sH row stride (ushorts), K=128 used
#define TPB 16    // groups (of 256 points) per MLP block -> grid = 256 = 1 block/CU

__device__ __forceinline__ float sigm_(float x) { return 1.f / (1.f + expf(-x)); }
__device__ __forceinline__ unsigned short f2bf(float x) {
  unsigned u = __builtin_bit_cast(unsigned, x);
  u = (u + 0x7fffu + ((u >> 16) & 1u)) >> 16;
  return (unsigned short)u;
}
__device__ __forceinline__ unsigned pk_bf16(float a, float b) {
  return (unsigned)f2bf(a) | ((unsigned)f2bf(b) << 16);
}
__device__ __forceinline__ float bf_lo(unsigned u) { return __builtin_bit_cast(float, u << 16); }
__device__ __forceinline__ float bf_hi(unsigned u) { return __builtin_bit_cast(float, u & 0xffff0000u); }
__device__ __forceinline__ unsigned short f2h(float x) {
  _Float16 h = (_Float16)x; return __builtin_bit_cast(unsigned short, h);
}
__device__ __forceinline__ float h_lo(unsigned u) {
  return (float)__builtin_bit_cast(_Float16, (unsigned short)(u & 0xffffu));
}
__device__ __forceinline__ float h_hi(unsigned u) {
  return (float)__builtin_bit_cast(_Float16, (unsigned short)(u >> 16));
}

typedef __attribute__((ext_vector_type(8))) short bf16x8;
typedef __attribute__((ext_vector_type(4))) float f32x4;
typedef __attribute__((ext_vector_type(4))) unsigned u32x4;

// ==== fused repack -> 32B voxel record: [sdf,gx,gy,gz](f16) + k0 ch0..11 (bf16) ====
__global__ __launch_bounds__(256) void vox_repack_all(
    const float* __restrict__ V, const float* __restrict__ k0,
    unsigned short* __restrict__ VR) {
  int idx = blockIdx.x * 256 + threadIdx.x;
  if (idx >= N3) return;
  int z = idx % GRIDN; int t = idx / GRIDN; int y = t % GRIDN; int x = t / GRIDN;
  float v = V[idx];
  float xp = (x < 159) ? V[idx + SX] : v, xm = (x > 0) ? V[idx - SX] : v;
  float yp = (y < 159) ? V[idx + SY] : v, ym = (y > 0) ? V[idx - SY] : v;
  float zp = (z < 159) ? V[idx + 1]  : v, zm = (z > 0) ? V[idx - 1]  : v;
  float cx = (x > 0 && x < 159) ? (159.f / 4.f) : (159.f / 2.f);
  float cy = (y > 0 && y < 159) ? (159.f / 4.f) : (159.f / 2.f);
  float cz = (z > 0 && z < 159) ? (159.f / 4.f) : (159.f / 2.f);
  unsigned f0 = (unsigned)f2h(v) | ((unsigned)f2h((xp - xm) * cx) << 16);
  unsigned f1 = (unsigned)f2h((yp - ym) * cy) | ((unsigned)f2h((zp - zm) * cz) << 16);
  unsigned w[6];
#pragma unroll
  for (int j = 0; j < 6; j++) {
    float a = __builtin_nontemporal_load(k0 + (size_t)(2 * j) * N3 + idx);
    float b = __builtin_nontemporal_load(k0 + (size_t)(2 * j + 1) * N3 + idx);
    w[j] = pk_bf16(a, b);
  }
  u32x4* r = (u32x4*)(VR + (size_t)idx * 16);
  r[0] = (u32x4){f0, f1, w[0], w[1]};
  r[1] = (u32x4){w[2], w[3], w[4], w[5]};
}

// ============ repack weights -> transposed bf16 with padded strides ============
__global__ __launch_bounds__(256) void vox_repack_w(
    const float* __restrict__ w0, const float* __restrict__ w1, const float* __restrict__ w2,
    unsigned short* __restrict__ W0B, unsigned short* __restrict__ W1B,
    unsigned short* __restrict__ W2B) {
  int i = blockIdx.x * 256 + threadIdx.x;
  if (i < 128 * W0K) {                    // W0B[c][k] = w0[k][c], k<75
    int c = i / W0K, k = i - c * W0K;
    W0B[i] = (k < 75) ? f2bf(w0[k * 128 + c]) : (unsigned short)0;
  }
  if (i < 128 * W1K) {                    // W1B[c][k] = w1[k][c], k<128
    int c = i / W1K, k = i - c * W1K;
    W1B[i] = (k < 128) ? f2bf(w1[k * 128 + c]) : (unsigned short)0;
  }
  if (i < 16 * W1K) {                     // W2B[c][k] = w2[k][c], c<3, k<128
    int c = i / W1K, k = i - c * W1K;
    W2B[i] = (k < 128 && c < 3) ? f2bf(w2[k * 3 + c]) : (unsigned short)0;
  }
}

// ============ gather: trilerps + alpha + feat[96] bf16 (fast __sincosf) ============
__global__ __launch_bounds__(256) void vox_gather_kernel(
    const float* __restrict__ ray_pts, const float* __restrict__ rays_d,
    const unsigned short* __restrict__ VR,
    const float* __restrict__ s_val, const int* __restrict__ ray_id,
    float* __restrict__ alpha_out, unsigned short* __restrict__ featB, int M) {
  int i = blockIdx.x * 256 + threadIdx.x;
  if (i >= M) return;

  float px = ray_pts[3 * i + 0], py = ray_pts[3 * i + 1], pz = ray_pts[3 * i + 2];
  const float SC = 0.5f * 159.f;
  float ux = fminf(fmaxf((px + 1.f) * SC, 0.f), 159.f);
  float uy = fminf(fmaxf((py + 1.f) * SC, 0.f), 159.f);
  float uz = fminf(fmaxf((pz + 1.f) * SC, 0.f), 159.f);
  int ix = min((int)ux, 158), iy = min((int)uy, 158), iz = min((int)uz, 158);
  float fx = ux - (float)ix, fy = uy - (float)iy, fz = uz - (float)iz;
  float wx0 = 1.f - fx, wy0 = 1.f - fy, wz0 = 1.f - fz;
  float wxy[4];
  wxy[0] = wx0 * wy0; wxy[1] = wx0 * fy; wxy[2] = fx * wy0; wxy[3] = fx * fy;
  const int pairoff[4] = {0, SY, SX, SX + SY};
  int base = (ix * GRIDN + iy) * GRIDN + iz;

  // ---- 4 z-pair taps, 64B contiguous each (2 voxel records) ----
  u32x4 q[4][4];
#pragma unroll
  for (int t = 0; t < 4; t++) {
    const u32x4* p = (const u32x4*)(VR + (size_t)(base + pairoff[t]) * 16);
    q[t][0] = p[0]; q[t][1] = p[1]; q[t][2] = p[2]; q[t][3] = p[3];
  }

  float sdf = 0.f, gx = 0.f, gy = 0.f, gz = 0.f;
  float k[12];
#pragma unroll
  for (int j = 0; j < 12; j++) k[j] = 0.f;
#pragma unroll
  for (int t = 0; t < 4; t++) {
    float w0z = wxy[t] * wz0, w1z = wxy[t] * fz;
    sdf = fmaf(w0z, h_lo(q[t][0].x), sdf);
    gx  = fmaf(w0z, h_hi(q[t][0].x), gx);
    gy  = fmaf(w0z, h_lo(q[t][0].y), gy);
    gz  = fmaf(w0z, h_hi(q[t][0].y), gz);
    k[0]  = fmaf(w0z, bf_lo(q[t][0].z), k[0]);
    k[1]  = fmaf(w0z, bf_hi(q[t][0].z), k[1]);
    k[2]  = fmaf(w0z, bf_lo(q[t][0].w), k[2]);
    k[3]  = fmaf(w0z, bf_hi(q[t][0].w), k[3]);
    k[4]  = fmaf(w0z, bf_lo(q[t][1].x), k[4]);
    k[5]  = fmaf(w0z, bf_hi(q[t][1].x), k[5]);
    k[6]  = fmaf(w0z, bf_lo(q[t][1].y), k[6]);
    k[7]  = fmaf(w0z, bf_hi(q[t][1].y), k[7]);
    k[8]  = fmaf(w0z, bf_lo(q[t][1].z), k[8]);
    k[9]  = fmaf(w0z, bf_hi(q[t][1].z), k[9]);
    k[10] = fmaf(w0z, bf_lo(q[t][1].w), k[10]);
    k[11] = fmaf(w0z, bf_hi(q[t][1].w), k[11]);
    sdf = fmaf(w1z, h_lo(q[t][2].x), sdf);
    gx  = fmaf(w1z, h_hi(q[t][2].x), gx);
    gy  = fmaf(w1z, h_lo(q[t][2].y), gy);
    gz  = fmaf(w1z, h_hi(q[t][2].y), gz);
    k[0]  = fmaf(w1z, bf_lo(q[t][2].z), k[0]);
    k[1]  = fmaf(w1z, bf_hi(q[t][2].z), k[1]);
    k[2]  = fmaf(w1z, bf_lo(q[t][2].w), k[2]);
    k[3]  = fmaf(w1z, bf_hi(q[t][2].w), k[3]);
    k[4]  = fmaf(w1z, bf_lo(q[t][3].x), k[4]);
    k[5]  = fmaf(w1z, bf_hi(q[t][3].x), k[5]);
    k[6]  = fmaf(w1z, bf_lo(q[t][3].y), k[6]);
    k[7]  = fmaf(w1z, bf_hi(q[t][3].y), k[7]);
    k[8]  = fmaf(w1z, bf_lo(q[t][3].z), k[8]);
    k[9]  = fmaf(w1z, bf_hi(q[t][3].z), k[9]);
    k[10] = fmaf(w1z, bf_lo(q[t][3].w), k[10]);
    k[11] = fmaf(w1z, bf_hi(q[t][3].w), k[11]);
  }
  float ginv = 1.f / (sqrtf(gx * gx + gy * gy + gz * gz) + 1e-8f);
  float gnx = gx * ginv, gny = gy * ginv, gnz = gz * ginv;

  int rid = ray_id[i];
  float ddx = rays_d[3 * rid + 0], ddy = rays_d[3 * rid + 1], ddz = rays_d[3 * rid + 2];

  float true_cos = ddx * gnx + ddy * gny + ddz * gnz;
  float iter_cos = fminf(true_cos, 0.f);
  float inv_s = 1.f / s_val[0];
  float e = iter_cos * (DIST_C * 0.5f);
  float prev_cdf = sigm_((sdf - e) * inv_s);
  float next_cdf = sigm_((sdf + e) * inv_s);
  float alpha = (prev_cdf - next_cdf + 1e-5f) / (prev_cdf + 1e-5f);
  alpha_out[i] = fminf(fmaxf(alpha, 0.f), 1.f);

  float feat[75];
#pragma unroll
  for (int j = 0; j < 12; j++) feat[j] = k[j];

  float x01 = (px + 1.f) * 0.5f, y01 = (py + 1.f) * 0.5f, z01 = (pz + 1.f) * 0.5f;
  feat[12] = x01; feat[13] = y01; feat[14] = z01;
#pragma unroll
  for (int l = 0; l < 5; l++) {
    float f = (float)(1 << l), s, c;
    __sincosf(x01 * f, &s, &c); feat[15 + l] = s; feat[30 + l] = c;
    __sincosf(y01 * f, &s, &c); feat[20 + l] = s; feat[35 + l] = c;
    __sincosf(z01 * f, &s, &c); feat[25 + l] = s; feat[40 + l] = c;
  }
  feat[45] = ddx; feat[46] = ddy; feat[47] = ddz;
#pragma unroll
  for (int l = 0; l < 4; l++) {
    float f = (float)(1 << l), s, c;
    __sincosf(ddx * f, &s, &c); feat[48 + l] = s; feat[60 + l] = c;
    __sincosf(ddy * f, &s, &c); feat[52 + l] = s; feat[64 + l] = c;
    __sincosf(ddz * f, &s, &c); feat[56 + l] = s; feat[68 + l] = c;
  }
  feat[72] = gnx; feat[73] = gny; feat[74] = gnz;

  // pack 96 bf16 (75 real + zero pad) -> 12 normal 16B stores
  unsigned pw[48];
#pragma unroll
  for (int wv = 0; wv < 37; wv++) pw[wv] = pk_bf16(feat[2 * wv], feat[2 * wv + 1]);
  pw[37] = pk_bf16(feat[74], 0.f);
#pragma unroll
  for (int wv = 38; wv < 48; wv++) pw[wv] = 0u;
  u32x4* fb = (u32x4*)(featB + (size_t)i * 96);
#pragma unroll
  for (int q2 = 0; q2 < 12; q2++)
    fb[q2] = (u32x4){pw[4 * q2], pw[4 * q2 + 1], pw[4 * q2 + 2], pw[4 * q2 + 3]};
}

// ======== MFMA MLP: 1024 thr = 16 waves share one weight staging ========
__global__ __launch_bounds__(1024, 1) void vox_mlp_kernel(
    const unsigned short* __restrict__ featB,
    const unsigned short* __restrict__ W0B, const unsigned short* __restrict__ W1B,
    const unsigned short* __restrict__ W2B,
    const float* __restrict__ b0, const float* __restrict__ b1,
    const float* __restrict__ b2, float* __restrict__ rgb, int ngroups) {
  __shared__ __align__(16) unsigned short sW0[128 * W0K];
  __shared__ __align__(16) unsigned short sW1[128 * W1K];
  __shared__ __align__(16) unsigned short sW2[16 * W1K];
  __shared__ __align__(16) unsigned short sH[16 * 16 * W1K];
  __shared__ __align__(16) float sB0[128], sB1[128], sB2[16];

  {
    const uint4* s0 = (const uint4*)W0B; uint4* d0 = (uint4*)sW0;
    for (int i = threadIdx.x; i < 128 * W0K / 8; i += 1024) d0[i] = s0[i];
    const uint4* s1 = (const uint4*)W1B; uint4* d1 = (uint4*)sW1;
    for (int i = threadIdx.x; i < 128 * W1K / 8; i += 1024) d1[i] = s1[i];
    const uint4* s2 = (const uint4*)W2B; uint4* d2 = (uint4*)sW2;
    for (int i = threadIdx.x; i < 16 * W1K / 8; i += 1024) d2[i] = s2[i];
    if (threadIdx.x < 128) { sB0[threadIdx.x] = b0[threadIdx.x]; sB1[threadIdx.x] = b1[threadIdx.x]; }
    if (threadIdx.x < 16) sB2[threadIdx.x] = (threadIdx.x < 3) ? b2[threadIdx.x] : 0.f;
  }
  __syncthreads();

  const int wid = (int)(threadIdx.x >> 6), lane = (int)(threadIdx.x & 63);
  const int l15 = lane & 15, g = lane >> 4;
  unsigned short* myH = sH + wid * (16 * W1K);

#pragma unroll 1
  for (int t = 0; t < TPB; ++t) {
    int grp = blockIdx.x * TPB + t;
    if (grp >= ngroups) break;
    const int pt0 = grp * 256 + wid * 16;

    const unsigned short* fr = featB + (size_t)(pt0 + l15) * 96 + g * 8;
    bf16x8 cb0 = __builtin_nontemporal_load((const bf16x8*)(fr));
    bf16x8 cb1 = __builtin_nontemporal_load((const bf16x8*)(fr + 32));
    bf16x8 cb2 = __builtin_nontemporal_load((const bf16x8*)(fr + 64));

    // ---- GEMM1: D1[hid][pt] = W0^T x feat^T, K=96 ----
    f32x4 acc1[8];
#pragma unroll
    for (int m = 0; m < 8; m++) acc1[m] = (f32x4){0.f, 0.f, 0.f, 0.f};
#pragma unroll
    for (int m = 0; m < 8; m++) {
      bf16x8 a0 = *(const bf16x8*)(sW0 + (m * 16 + l15) * W0K + g * 8);
      acc1[m] = __builtin_amdgcn_mfma_f32_16x16x32_bf16(a0, cb0, acc1[m], 0, 0, 0);
      bf16x8 a1 = *(const bf16x8*)(sW0 + (m * 16 + l15) * W0K + 32 + g * 8);
      acc1[m] = __builtin_amdgcn_mfma_f32_16x16x32_bf16(a1, cb1, acc1[m], 0, 0, 0);
      bf16x8 a2 = *(const bf16x8*)(sW0 + (m * 16 + l15) * W0K + 64 + g * 8);
      acc1[m] = __builtin_amdgcn_mfma_f32_16x16x32_bf16(a2, cb2, acc1[m], 0, 0, 0);
    }
#pragma unroll
    for (int m = 0; m < 8; m++) {
      f32x4 bias = *(const f32x4*)(sB0 + m * 16 + g * 4);
      float h0 = fmaxf(acc1[m][0] + bias[0], 0.f);
      float h1 = fmaxf(acc1[m][1] + bias[1], 0.f);
      float h2 = fmaxf(acc1[m][2] + bias[2], 0.f);
      float h3 = fmaxf(acc1[m][3] + bias[3], 0.f);
      *(uint2*)(myH + l15 * W1K + m * 16 + g * 4) = make_uint2(pk_bf16(h0, h1), pk_bf16(h2, h3));
    }

    // ---- GEMM2: D2[hid2][pt] = W1^T x h1^T, K=128 ----
    f32x4 acc2[8];
#pragma unroll
    for (int m = 0; m < 8; m++) acc2[m] = (f32x4){0.f, 0.f, 0.f, 0.f};
    const unsigned short* hb = myH + l15 * W1K + g * 8;
#pragma unroll
    for (int ks = 0; ks < 4; ks++) {
      bf16x8 bfrag = *(const bf16x8*)(hb + ks * 32);
#pragma unroll
      for (int m = 0; m < 8; m++) {
        bf16x8 afrag = *(const bf16x8*)(sW1 + (m * 16 + l15) * W1K + ks * 32 + g * 8);
        acc2[m] = __builtin_amdgcn_mfma_f32_16x16x32_bf16(afrag, bfrag, acc2[m], 0, 0, 0);
      }
    }
#pragma unroll
    for (int m = 0; m < 8; m++) {
      f32x4 bias = *(const f32x4*)(sB1 + m * 16 + g * 4);
      float h0 = fmaxf(acc2[m][0] + bias[0], 0.f);
      float h1 = fmaxf(acc2[m][1] + bias[1], 0.f);
      float h2 = fmaxf(acc2[m][2] + bias[2], 0.f);
      float h3 = fmaxf(acc2[m][3] + bias[3], 0.f);
      *(uint2*)(myH + l15 * W1K + m * 16 + g * 4) = make_uint2(pk_bf16(h0, h1), pk_bf16(h2, h3));
    }

    // ---- GEMM3: D3[ch][pt] = W2^T x h2^T, K=128, 1 tile ----
    f32x4 acc3 = (f32x4){0.f, 0.f, 0.f, 0.f};
#pragma unroll
    for (int ks = 0; ks < 4; ks++) {
      bf16x8 bfrag = *(const bf16x8*)(hb + ks * 32);
      bf16x8 afrag = *(const bf16x8*)(sW2 + l15 * W1K + ks * 32 + g * 8);
      acc3 = __builtin_amdgcn_mfma_f32_16x16x32_bf16(afrag, bfrag, acc3, 0, 0, 0);
    }
    if (g == 0) {   // rows 0..3 = channels; only 0..2 valid
      int pt = pt0 + l15;
      rgb[pt * 3 + 0] = sigm_(acc3[0] + sB2[0]);
      rgb[pt * 3 + 1] = sigm_(acc3[1] + sB2[1]);
      rgb[pt * 3 + 2] = sigm_(acc3[2] + sB2[2]);
    }
  }
}

// ============ per-ray scan + composite (1 wave / ray) ============
__global__ __launch_bounds__(256) void vox_scan_kernel(
    const float* __restrict__ alpha, const float* __restrict__ rgb,
    const int* __restrict__ ray_id, float* __restrict__ out, int M, int NR) {
  int wave = (int)((blockIdx.x * blockDim.x + threadIdx.x) >> 6);
  int lane = threadIdx.x & 63;
  if (wave >= NR) return;
  int r = wave;
  int lo = 0, hi = M;
  while (lo < hi) { int mid = (lo + hi) >> 1; if (ray_id[mid] < r) lo = mid + 1; else hi = mid; }
  int start = lo; hi = M;
  while (lo < hi) { int mid = (lo + hi) >> 1; if (ray_id[mid] < r + 1) lo = mid + 1; else hi = mid; }
  int end = lo;

  float carry = 0.f, cr = 0.f, cg = 0.f, cb = 0.f;
  for (int s = start; s < end; s += 64) {
    int idx = s + lane;
    bool valid = idx < end;
    float a = valid ? alpha[idx] : 0.f;
    float l = valid ? log1pf(-fminf(a, 1.f - 1e-7f)) : 0.f;
    float sc = l;
#pragma unroll
    for (int off = 1; off < 64; off <<= 1) {
      float t = __shfl_up(sc, (unsigned)off);
      if (lane >= off) sc += t;
    }
    if (valid) {
      float T = expf(carry + (sc - l));
      float w = a * T;
      cr = fmaf(w, rgb[3 * idx + 0], cr);
      cg = fmaf(w, rgb[3 * idx + 1], cg);
      cb = fmaf(w, rgb[3 * idx + 2], cb);
    }
    carry += __shfl(sc, 63);
  }
#pragma unroll
  for (int off = 32; off > 0; off >>= 1) {
    cr += __shfl_down(cr, (unsigned)off);
    cg += __shfl_down(cg, (unsigned)off);
    cb += __shfl_down(cb, (unsigned)off);
  }
  if (lane == 0) {
    float ail = expf(carry);
    out[3 * r + 0] = cr + ail;
    out[3 * r + 1] = cg + ail;
    out[3 * r + 2] = cb + ail;
  }
}

// ============ fallback (round-1 monolithic path, used if ws too small) ============
__global__ __launch_bounds__(256) void vox_transpose_w0(
    const float* __restrict__ w0, float* __restrict__ w0t) {
  for (int idx = threadIdx.x; idx < 128 * 80; idx += 256) {
    int j = idx / 80, k = idx - j * 80;
    w0t[idx] = (k < 75) ? w0[k * 128 + j] : 0.f;
  }
}

__global__ __launch_bounds__(256) void vox_point_kernel(
    const float* __restrict__ ray_pts, const float* __restrict__ rays_d,
    const float* __restrict__ sdf_vol, const float* __restrict__ k0_vol,
    const float* __restrict__ w0t, const float* __restrict__ b0,
    const float* __restrict__ w1, const float* __restrict__ b1,
    const float* __restrict__ w2, const float* __restrict__ b2,
    const float* __restrict__ s_val, const int* __restrict__ ray_id,
    float* __restrict__ alpha_out, float* __restrict__ rgb_out, int M) {
  int i = blockIdx.x * 256 + threadIdx.x;
  if (i >= M) return;
  float px = ray_pts[3 * i + 0], py = ray_pts[3 * i + 1], pz = ray_pts[3 * i + 2];
  const float SC = 0.5f * 159.f;
  float ux = fminf(fmaxf((px + 1.f) * SC, 0.f), 159.f);
  float uy = fminf(fmaxf((py + 1.f) * SC, 0.f), 159.f);
  float uz = fminf(fmaxf((pz + 1.f) * SC, 0.f), 159.f);
  int ix = min((int)ux, 158), iy = min((int)uy, 158), iz = min((int)uz, 158);
  float fx = ux - (float)ix, fy = uy - (float)iy, fz = uz - (float)iz;
  float wx0 = 1.f - fx, wy0 = 1.f - fy, wz0 = 1.f - fz;
  float w000 = wx0 * wy0 * wz0, w001 = wx0 * wy0 * fz;
  float w010 = wx0 * fy * wz0,  w011 = wx0 * fy * fz;
  float w100 = fx * wy0 * wz0,  w101 = fx * wy0 * fz;
  float w110 = fx * fy * wz0,   w111 = fx * fy * fz;
  int base = (ix * GRIDN + iy) * GRIDN + iz;
  const float* V = sdf_vol;
  float c000 = V[base],          c001 = V[base + 1];
  float c010 = V[base + SY],     c011 = V[base + SY + 1];
  float c100 = V[base + SX],     c101 = V[base + SX + 1];
  float c110 = V[base + SX + SY], c111 = V[base + SX + SY + 1];
  float xm00 = V[base - SX],          xm01 = V[base - SX + 1];
  float xm10 = V[base - SX + SY],     xm11 = V[base - SX + SY + 1];
  float xp00 = V[base + 2 * SX],      xp01 = V[base + 2 * SX + 1];
  float xp10 = V[base + 2 * SX + SY], xp11 = V[base + 2 * SX + SY + 1];
  float ym00 = V[base - SY],          ym01 = V[base - SY + 1];
  float ym10 = V[base + SX - SY],     ym11 = V[base + SX - SY + 1];
  float yp00 = V[base + 2 * SY],      yp01 = V[base + 2 * SY + 1];
  float yp10 = V[base + SX + 2 * SY], yp11 = V[base + SX + 2 * SY + 1];
  float zm00 = V[base - 1],           zm01 = V[base + SY - 1];
  float zm10 = V[base + SX - 1],      zm11 = V[base + SX + SY - 1];
  float zp00 = V[base + 2],           zp01 = V[base + SY + 2];
  float zp10 = V[base + SX + 2],      zp11 = V[base + SX + SY + 2];
  float sdf = w000 * c000 + w001 * c001 + w010 * c010 + w011 * c011 +
              w100 * c100 + w101 * c101 + w110 * c110 + w111 * c111;
  const float INV2H = 159.f / 4.f;
  float gx = (w000 * (c100 - xm00) + w001 * (c101 - xm01) +
              w010 * (c110 - xm10) + w011 * (c111 - xm11) +
              w100 * (xp00 - c000) + w101 * (xp01 - c001) +
              w110 * (xp10 - c010) + w111 * (xp11 - c011)) * INV2H;
  float gy = (w000 * (c010 - ym00) + w001 * (c011 - ym01) +
              w100 * (c110 - ym10) + w101 * (c111 - ym11) +
              w010 * (yp00 - c000) + w011 * (yp01 - c001) +
              w110 * (yp10 - c100) + w111 * (yp11 - c101)) * INV2H;
  float gz = (w000 * (c001 - zm00) + w010 * (c011 - zm01) +
              w100 * (c101 - zm10) + w110 * (c111 - zm11) +
              w001 * (zp00 - c000) + w011 * (zp01 - c010) +
              w101 * (zp10 - c100) + w111 * (zp11 - c110)) * INV2H;
  float ginv = 1.f / (sqrtf(gx * gx + gy * gy + gz * gz) + 1e-8f);
  float gnx = gx * ginv, gny = gy * ginv, gnz = gz * ginv;
  int rid = ray_id[i];
  float ddx = rays_d[3 * rid + 0], ddy = rays_d[3 * rid + 1], ddz = rays_d[3 * rid + 2];
  float true_cos = ddx * gnx + ddy * gny + ddz * gnz;
  float iter_cos = fminf(true_cos, 0.f);
  float inv_s = 1.f / s_val[0];
  float e = iter_cos * (DIST_C * 0.5f);
  float prev_cdf = sigm_((sdf - e) * inv_s);
  float next_cdf = sigm_((sdf + e) * inv_s);
  float alpha = fminf(fmaxf((prev_cdf - next_cdf + 1e-5f) / (prev_cdf + 1e-5f), 0.f), 1.f);
  alpha_out[i] = alpha;
  float feat[75];
  {
    const int offs[8] = {0, 1, SY, SY + 1, SX, SX + 1, SX + SY, SX + SY + 1};
    const float wts[8] = {w000, w001, w010, w011, w100, w101, w110, w111};
#pragma unroll
    for (int c = 0; c < 12; c++) {
      const float* kc = k0_vol + c * N3 + base;
      float acc = 0.f;
#pragma unroll
      for (int t = 0; t < 8; t++) acc = fmaf(wts[t], kc[offs[t]], acc);
      feat[c] = acc;
    }
  }
  float x01 = (px + 1.f) * 0.5f, y01 = (py + 1.f) * 0.5f, z01 = (pz + 1.f) * 0.5f;
  feat[12] = x01; feat[13] = y01; feat[14] = z01;
#pragma unroll
  for (int l = 0; l < 5; l++) {
    float f = (float)(1 << l), s, c;
    sincosf(x01 * f, &s, &c); feat[15 + l] = s; feat[30 + l] = c;
    sincosf(y01 * f, &s, &c); feat[20 + l] = s; feat[35 + l] = c;
    sincosf(z01 * f, &s, &c); feat[25 + l] = s; feat[40 + l] = c;
  }
  feat[45] = ddx; feat[46] = ddy; feat[47] = ddz;
#pragma unroll
  for (int l = 0; l < 4; l++) {
    float f = (float)(1 << l), s, c;
    sincosf(ddx * f, &s, &c); feat[48 + l] = s; feat[60 + l] = c;
    sincosf(ddy * f, &s, &c); feat[52 + l] = s; feat[64 + l] = c;
    sincosf(ddz * f, &s, &c); feat[56 + l] = s; feat[68 + l] = c;
  }
  feat[72] = gnx; feat[73] = gny; feat[74] = gnz;
  float rr = 0.f, rg = 0.f, rb = 0.f;
#pragma unroll 1
  for (int half = 0; half < 2; ++half) {
    float acc[64];
#pragma unroll
    for (int t = 0; t < 64; t++) acc[t] = b1[half * 64 + t];
#pragma unroll 1
    for (int j = 0; j < 128; ++j) {
      float h = b0[j];
      const float* wr = w0t + j * 80;
#pragma unroll
      for (int k = 0; k < 75; k++) h = fmaf(feat[k], wr[k], h);
      h = fmaxf(h, 0.f);
      const float* w1r = w1 + j * 128 + half * 64;
#pragma unroll
      for (int t = 0; t < 64; t++) acc[t] = fmaf(h, w1r[t], acc[t]);
    }
#pragma unroll
    for (int t = 0; t < 64; t++) {
      float h2 = fmaxf(acc[t], 0.f);
      int j2 = half * 64 + t;
      rr = fmaf(h2, w2[3 * j2 + 0], rr);
      rg = fmaf(h2, w2[3 * j2 + 1], rg);
      rb = fmaf(h2, w2[3 * j2 + 2], rb);
    }
  }
  rgb_out[3 * i + 0] = sigm_(rr + b2[0]);
  rgb_out[3 * i + 1] = sigm_(rg + b2[1]);
  rgb_out[3 * i + 2] = sigm_(rb + b2[2]);
}

extern "C" void kernel_launch(void* const* d_in, const int* in_sizes, int n_in,
                              void* d_out, int out_size, void* d_ws, size_t ws_size,
                              hipStream_t stream) {
  const float* ray_pts = (const float*)d_in[0];
  const float* rays_d  = (const float*)d_in[1];
  const float* sdf_vol = (const float*)d_in[2];
  const float* k0_vol  = (const float*)d_in[3];
  const float* w0      = (const float*)d_in[4];
  const float* b0      = (const float*)d_in[5];
  const float* w1      = (const float*)d_in[6];
  const float* b1      = (const float*)d_in[7];
  const float* w2      = (const float*)d_in[8];
  const float* b2      = (const float*)d_in[9];
  const float* s_val   = (const float*)d_in[10];
  const int*   ray_id  = (const int*)d_in[11];
  float* out = (float*)d_out;

  int M  = in_sizes[0] / 3;   // 1048576
  int NR = in_sizes[1] / 3;   // 8192

  char* ws = (char*)d_ws;
  size_t offVR   = 0;                                  // N3*32 combined records
  size_t offFeat = offVR + (size_t)N3 * 32;
  size_t offA    = offFeat + (size_t)M * 96 * 2;
  size_t offRgb  = offA + (size_t)M * 4;
  size_t offW0   = offRgb + (size_t)M * 12;
  size_t offW1   = offW0 + (size_t)128 * W0K * 2;
  size_t offW2   = offW1 + (size_t)128 * W1K * 2;
  size_t need    = offW2 + (size_t)16 * W1K * 2;

  if (ws_size >= need && (M % 256) == 0) {
    unsigned short* VR = (unsigned short*)(ws + offVR);
    unsigned short* featB = (unsigned short*)(ws + offFeat);
    float* alpha_ws = (float*)(ws + offA);
    float* rgb_ws = (float*)(ws + offRgb);
    unsigned short* W0B = (unsigned short*)(ws + offW0);
    unsigned short* W1B = (unsigned short*)(ws + offW1);
    unsigned short* W2B = (unsigned short*)(ws + offW2);

    int ngroups = M / 256;
    vox_repack_all<<<(N3 + 255) / 256, 256, 0, stream>>>(sdf_vol, k0_vol, VR);
    vox_repack_w<<<(128 * W1K + 255) / 256, 256, 0, stream>>>(w0, w1, w2, W0B, W1B, W2B);
    vox_gather_kernel<<<(M + 255) / 256, 256, 0, stream>>>(
        ray_pts, rays_d, VR, s_val, ray_id, alpha_ws, featB, M);
    vox_mlp_kernel<<<(ngroups + TPB - 1) / TPB, 1024, 0, stream>>>(
        featB, W0B, W1B, W2B, b0, b1, b2, rgb_ws, ngroups);
    vox_scan_kernel<<<(NR * 64 + 255) / 256, 256, 0, stream>>>(
        alpha_ws, rgb_ws, ray_id, out, M, NR);
  } else {
    float* alpha_ws = (float*)ws;
    float* rgb_ws   = (float*)(ws + (size_t)M * 4);
    float* w0t_ws   = (float*)(ws + (size_t)M * 16);
    vox_transpose_w0<<<1, 256, 0, stream>>>(w0, w0t_ws);
    vox_point_kernel<<<(M + 255) / 256, 256, 0, stream>>>(
        ray_pts, rays_d, sdf_vol, k0_vol, w0t_ws, b0, w1, b1, w2, b2,
        s_val, ray_id, alpha_ws, rgb_ws, M);
    vox_scan_kernel<<<(NR * 64 + 255) / 256, 256, 0, stream>>>(
        alpha_ws, rgb_ws, ray_id, out, M, NR);
  }
}

// Round 16
// 316.628 us; speedup vs baseline: 6.5716x; 1.0912x over previous
//
#include <hip/hip_runtime.h>
#include <math.h>

#define GRIDN 160
#define N3 (160*160*160)
#define SX (160*160)
#define SY 160
#define DIST_C 0.005f
#define W0K 104   // sW0 row stride (ushorts), K=96 used
#define W1K 136   // sW1/sW2/sH row stride (ushorts), K=128 used
#define TPB 16    // groups (of 256 points) per MLP block -> grid = 256 = 1 block/CU

__device__ __forceinline__ float sigm_(float x) { return 1.f / (1.f + expf(-x)); }
__device__ __forceinline__ unsigned short f2bf(float x) {
  unsigned u = __builtin_bit_cast(unsigned, x);
  u = (u + 0x7fffu + ((u >> 16) & 1u)) >> 16;
  return (unsigned short)u;
}
__device__ __forceinline__ unsigned pk_bf16(float a, float b) {
  return (unsigned)f2bf(a) | ((unsigned)f2bf(b) << 16);
}
__device__ __forceinline__ float bf_lo(unsigned u) { return __builtin_bit_cast(float, u << 16); }
__device__ __forceinline__ float bf_hi(unsigned u) { return __builtin_bit_cast(float, u & 0xffff0000u); }
__device__ __forceinline__ unsigned short f2h(float x) {
  _Float16 h = (_Float16)x; return __builtin_bit_cast(unsigned short, h);
}
__device__ __forceinline__ float h_lo(unsigned u) {
  return (float)__builtin_bit_cast(_Float16, (unsigned short)(u & 0xffffu));
}
__device__ __forceinline__ float h_hi(unsigned u) {
  return (float)__builtin_bit_cast(_Float16, (unsigned short)(u >> 16));
}

typedef __attribute__((ext_vector_type(8))) short bf16x8;
typedef __attribute__((ext_vector_type(4))) float f32x4;
typedef __attribute__((ext_vector_type(4))) unsigned u32x4;

// ==== fused repack -> 32B voxel record: [sdf,gx,gy,gz](f16) + k0 ch0..11 (bf16) ====
__global__ __launch_bounds__(256) void vox_repack_all(
    const float* __restrict__ V, const float* __restrict__ k0,
    unsigned short* __restrict__ VR) {
  int idx = blockIdx.x * 256 + threadIdx.x;
  if (idx >= N3) return;
  int z = idx % GRIDN; int t = idx / GRIDN; int y = t % GRIDN; int x = t / GRIDN;
  float v = V[idx];
  float xp = (x < 159) ? V[idx + SX] : v, xm = (x > 0) ? V[idx - SX] : v;
  float yp = (y < 159) ? V[idx + SY] : v, ym = (y > 0) ? V[idx - SY] : v;
  float zp = (z < 159) ? V[idx + 1]  : v, zm = (z > 0) ? V[idx - 1]  : v;
  float cx = (x > 0 && x < 159) ? (159.f / 4.f) : (159.f / 2.f);
  float cy = (y > 0 && y < 159) ? (159.f / 4.f) : (159.f / 2.f);
  float cz = (z > 0 && z < 159) ? (159.f / 4.f) : (159.f / 2.f);
  unsigned f0 = (unsigned)f2h(v) | ((unsigned)f2h((xp - xm) * cx) << 16);
  unsigned f1 = (unsigned)f2h((yp - ym) * cy) | ((unsigned)f2h((zp - zm) * cz) << 16);
  unsigned w[6];
#pragma unroll
  for (int j = 0; j < 6; j++) {
    float a = __builtin_nontemporal_load(k0 + (size_t)(2 * j) * N3 + idx);
    float b = __builtin_nontemporal_load(k0 + (size_t)(2 * j + 1) * N3 + idx);
    w[j] = pk_bf16(a, b);
  }
  u32x4* r = (u32x4*)(VR + (size_t)idx * 16);
  r[0] = (u32x4){f0, f1, w[0], w[1]};
  r[1] = (u32x4){w[2], w[3], w[4], w[5]};
}

// ============ repack weights -> transposed bf16 with padded strides ============
__global__ __launch_bounds__(256) void vox_repack_w(
    const float* __restrict__ w0, const float* __restrict__ w1, const float* __restrict__ w2,
    unsigned short* __restrict__ W0B, unsigned short* __restrict__ W1B,
    unsigned short* __restrict__ W2B) {
  int i = blockIdx.x * 256 + threadIdx.x;
  if (i < 128 * W0K) {                    // W0B[c][k] = w0[k][c], k<75
    int c = i / W0K, k = i - c * W0K;
    W0B[i] = (k < 75) ? f2bf(w0[k * 128 + c]) : (unsigned short)0;
  }
  if (i < 128 * W1K) {                    // W1B[c][k] = w1[k][c], k<128
    int c = i / W1K, k = i - c * W1K;
    W1B[i] = (k < 128) ? f2bf(w1[k * 128 + c]) : (unsigned short)0;
  }
  if (i < 16 * W1K) {                     // W2B[c][k] = w2[k][c], c<3, k<128
    int c = i / W1K, k = i - c * W1K;
    W2B[i] = (k < 128 && c < 3) ? f2bf(w2[k * 3 + c]) : (unsigned short)0;
  }
}

// ============ gather: taps + alpha + 32B tap-digest TD = [k0..k11, gn, 0] bf16 ======
__global__ __launch_bounds__(256) void vox_gather_kernel(
    const float* __restrict__ ray_pts, const float* __restrict__ rays_d,
    const unsigned short* __restrict__ VR,
    const float* __restrict__ s_val, const int* __restrict__ ray_id,
    float* __restrict__ alpha_out, unsigned short* __restrict__ TD, int M) {
  int i = blockIdx.x * 256 + threadIdx.x;
  if (i >= M) return;

  float px = ray_pts[3 * i + 0], py = ray_pts[3 * i + 1], pz = ray_pts[3 * i + 2];
  const float SC = 0.5f * 159.f;
  float ux = fminf(fmaxf((px + 1.f) * SC, 0.f), 159.f);
  float uy = fminf(fmaxf((py + 1.f) * SC, 0.f), 159.f);
  float uz = fminf(fmaxf((pz + 1.f) * SC, 0.f), 159.f);
  int ix = min((int)ux, 158), iy = min((int)uy, 158), iz = min((int)uz, 158);
  float fx = ux - (float)ix, fy = uy - (float)iy, fz = uz - (float)iz;
  float wx0 = 1.f - fx, wy0 = 1.f - fy, wz0 = 1.f - fz;
  float wxy[4];
  wxy[0] = wx0 * wy0; wxy[1] = wx0 * fy; wxy[2] = fx * wy0; wxy[3] = fx * fy;
  const int pairoff[4] = {0, SY, SX, SX + SY};
  int base = (ix * GRIDN + iy) * GRIDN + iz;

  // ---- 4 z-pair taps, 64B contiguous each (2 voxel records) ----
  u32x4 q[4][4];
#pragma unroll
  for (int t = 0; t < 4; t++) {
    const u32x4* p = (const u32x4*)(VR + (size_t)(base + pairoff[t]) * 16);
    q[t][0] = p[0]; q[t][1] = p[1]; q[t][2] = p[2]; q[t][3] = p[3];
  }

  float sdf = 0.f, gx = 0.f, gy = 0.f, gz = 0.f;
  float k[12];
#pragma unroll
  for (int j = 0; j < 12; j++) k[j] = 0.f;
#pragma unroll
  for (int t = 0; t < 4; t++) {
    float w0z = wxy[t] * wz0, w1z = wxy[t] * fz;
    sdf = fmaf(w0z, h_lo(q[t][0].x), sdf);
    gx  = fmaf(w0z, h_hi(q[t][0].x), gx);
    gy  = fmaf(w0z, h_lo(q[t][0].y), gy);
    gz  = fmaf(w0z, h_hi(q[t][0].y), gz);
    k[0]  = fmaf(w0z, bf_lo(q[t][0].z), k[0]);
    k[1]  = fmaf(w0z, bf_hi(q[t][0].z), k[1]);
    k[2]  = fmaf(w0z, bf_lo(q[t][0].w), k[2]);
    k[3]  = fmaf(w0z, bf_hi(q[t][0].w), k[3]);
    k[4]  = fmaf(w0z, bf_lo(q[t][1].x), k[4]);
    k[5]  = fmaf(w0z, bf_hi(q[t][1].x), k[5]);
    k[6]  = fmaf(w0z, bf_lo(q[t][1].y), k[6]);
    k[7]  = fmaf(w0z, bf_hi(q[t][1].y), k[7]);
    k[8]  = fmaf(w0z, bf_lo(q[t][1].z), k[8]);
    k[9]  = fmaf(w0z, bf_hi(q[t][1].z), k[9]);
    k[10] = fmaf(w0z, bf_lo(q[t][1].w), k[10]);
    k[11] = fmaf(w0z, bf_hi(q[t][1].w), k[11]);
    sdf = fmaf(w1z, h_lo(q[t][2].x), sdf);
    gx  = fmaf(w1z, h_hi(q[t][2].x), gx);
    gy  = fmaf(w1z, h_lo(q[t][2].y), gy);
    gz  = fmaf(w1z, h_hi(q[t][2].y), gz);
    k[0]  = fmaf(w1z, bf_lo(q[t][2].z), k[0]);
    k[1]  = fmaf(w1z, bf_hi(q[t][2].z), k[1]);
    k[2]  = fmaf(w1z, bf_lo(q[t][2].w), k[2]);
    k[3]  = fmaf(w1z, bf_hi(q[t][2].w), k[3]);
    k[4]  = fmaf(w1z, bf_lo(q[t][3].x), k[4]);
    k[5]  = fmaf(w1z, bf_hi(q[t][3].x), k[5]);
    k[6]  = fmaf(w1z, bf_lo(q[t][3].y), k[6]);
    k[7]  = fmaf(w1z, bf_hi(q[t][3].y), k[7]);
    k[8]  = fmaf(w1z, bf_lo(q[t][3].z), k[8]);
    k[9]  = fmaf(w1z, bf_hi(q[t][3].z), k[9]);
    k[10] = fmaf(w1z, bf_lo(q[t][3].w), k[10]);
    k[11] = fmaf(w1z, bf_hi(q[t][3].w), k[11]);
  }
  float ginv = 1.f / (sqrtf(gx * gx + gy * gy + gz * gz) + 1e-8f);
  float gnx = gx * ginv, gny = gy * ginv, gnz = gz * ginv;

  int rid = ray_id[i];
  float ddx = rays_d[3 * rid + 0], ddy = rays_d[3 * rid + 1], ddz = rays_d[3 * rid + 2];

  float true_cos = ddx * gnx + ddy * gny + ddz * gnz;
  float iter_cos = fminf(true_cos, 0.f);
  float inv_s = 1.f / s_val[0];
  float e = iter_cos * (DIST_C * 0.5f);
  float prev_cdf = sigm_((sdf - e) * inv_s);
  float next_cdf = sigm_((sdf + e) * inv_s);
  float alpha = (prev_cdf - next_cdf + 1e-5f) / (prev_cdf + 1e-5f);
  alpha_out[i] = fminf(fmaxf(alpha, 0.f), 1.f);

  // ---- tap digest: 12 k0-feats + normalized grad, bf16, 32B coalesced ----
  u32x4* tb = (u32x4*)(TD + (size_t)i * 16);
  tb[0] = (u32x4){pk_bf16(k[0], k[1]), pk_bf16(k[2], k[3]),
                  pk_bf16(k[4], k[5]), pk_bf16(k[6], k[7])};
  tb[1] = (u32x4){pk_bf16(k[8], k[9]), pk_bf16(k[10], k[11]),
                  pk_bf16(gnx, gny), pk_bf16(gnz, 0.f)};
}

// ======== MFMA MLP: embeddings recomputed in-register; B-slices built per g ========
__global__ __launch_bounds__(1024, 1) void vox_mlp_kernel(
    const float* __restrict__ ray_pts, const float* __restrict__ rays_d,
    const int* __restrict__ ray_id, const unsigned short* __restrict__ TD,
    const unsigned short* __restrict__ W0B, const unsigned short* __restrict__ W1B,
    const unsigned short* __restrict__ W2B,
    const float* __restrict__ b0, const float* __restrict__ b1,
    const float* __restrict__ b2, float* __restrict__ rgb, int ngroups) {
  __shared__ __align__(16) unsigned short sW0[128 * W0K];
  __shared__ __align__(16) unsigned short sW1[128 * W1K];
  __shared__ __align__(16) unsigned short sW2[16 * W1K];
  __shared__ __align__(16) unsigned short sH[16 * 16 * W1K];
  __shared__ __align__(16) float sB0[128], sB1[128], sB2[16];

  {
    const uint4* s0 = (const uint4*)W0B; uint4* d0 = (uint4*)sW0;
    for (int i = threadIdx.x; i < 128 * W0K / 8; i += 1024) d0[i] = s0[i];
    const uint4* s1 = (const uint4*)W1B; uint4* d1 = (uint4*)sW1;
    for (int i = threadIdx.x; i < 128 * W1K / 8; i += 1024) d1[i] = s1[i];
    const uint4* s2 = (const uint4*)W2B; uint4* d2 = (uint4*)sW2;
    for (int i = threadIdx.x; i < 16 * W1K / 8; i += 1024) d2[i] = s2[i];
    if (threadIdx.x < 128) { sB0[threadIdx.x] = b0[threadIdx.x]; sB1[threadIdx.x] = b1[threadIdx.x]; }
    if (threadIdx.x < 16) sB2[threadIdx.x] = (threadIdx.x < 3) ? b2[threadIdx.x] : 0.f;
  }
  __syncthreads();

  const int wid = (int)(threadIdx.x >> 6), lane = (int)(threadIdx.x & 63);
  const int l15 = lane & 15, g = lane >> 4;
  unsigned short* myH = sH + wid * (16 * W1K);

#pragma unroll 1
  for (int t = 0; t < TPB; ++t) {
    int grp = blockIdx.x * TPB + t;
    if (grp >= ngroups) break;
    const int pt0 = grp * 256 + wid * 16;
    const int pt = pt0 + l15;

    // ---- per-point state (4x g-redundant, broadcast addresses) ----
    float px = ray_pts[3 * pt + 0], py = ray_pts[3 * pt + 1], pz = ray_pts[3 * pt + 2];
    int rid = ray_id[pt];
    float ddx = rays_d[3 * rid + 0], ddy = rays_d[3 * rid + 1], ddz = rays_d[3 * rid + 2];
    float x01 = (px + 1.f) * 0.5f, y01 = (py + 1.f) * 0.5f, z01 = (pz + 1.f) * 0.5f;
    float snx[5], csx[5], sny[5], csy[5], snz[5], csz[5];
    float sdx[4], cdx[4], sdy[4], cdy[4], sdz[4], cdz[4];
#pragma unroll
    for (int l = 0; l < 5; l++) {
      float f = (float)(1 << l);
      __sincosf(x01 * f, &snx[l], &csx[l]);
      __sincosf(y01 * f, &sny[l], &csy[l]);
      __sincosf(z01 * f, &snz[l], &csz[l]);
    }
#pragma unroll
    for (int l = 0; l < 4; l++) {
      float f = (float)(1 << l);
      __sincosf(ddx * f, &sdx[l], &cdx[l]);
      __sincosf(ddy * f, &sdy[l], &cdy[l]);
      __sincosf(ddz * f, &sdz[l], &cdz[l]);
    }
    const u32x4* tdp = (const u32x4*)(TD + (size_t)pt * 16);
    u32x4 td0 = tdp[0];   // k0..k7
    u32x4 td1 = tdp[1];   // k8..k11, gnx,gny, gnz,0

    // ---- build this lane's three B-slices (feature map per g) ----
    bf16x8 cb0, cb1, cb2;
    const u32x4 zz = (u32x4){0u, 0u, 0u, 0u};
    switch (g) {
      case 0:
        cb0 = __builtin_bit_cast(bf16x8, td0);
        cb1 = __builtin_bit_cast(bf16x8, (u32x4){
            pk_bf16(csx[2], csx[3]), pk_bf16(csx[4], csy[0]),
            pk_bf16(csy[1], csy[2]), pk_bf16(csy[3], csy[4])});
        cb2 = __builtin_bit_cast(bf16x8, (u32x4){
            pk_bf16(cdy[0], cdy[1]), pk_bf16(cdy[2], cdy[3]),
            pk_bf16(cdz[0], cdz[1]), pk_bf16(cdz[2], cdz[3])});
        break;
      case 1:
        cb0 = __builtin_bit_cast(bf16x8, (u32x4){
            td1.x, td1.y, pk_bf16(x01, y01), pk_bf16(z01, snx[0])});
        cb1 = __builtin_bit_cast(bf16x8, (u32x4){
            pk_bf16(csz[0], csz[1]), pk_bf16(csz[2], csz[3]),
            pk_bf16(csz[4], ddx), pk_bf16(ddy, ddz)});
        cb2 = __builtin_bit_cast(bf16x8, (u32x4){td1.z, td1.w, 0u, 0u});
        break;
      case 2:
        cb0 = __builtin_bit_cast(bf16x8, (u32x4){
            pk_bf16(snx[1], snx[2]), pk_bf16(snx[3], snx[4]),
            pk_bf16(sny[0], sny[1]), pk_bf16(sny[2], sny[3])});
        cb1 = __builtin_bit_cast(bf16x8, (u32x4){
            pk_bf16(sdx[0], sdx[1]), pk_bf16(sdx[2], sdx[3]),
            pk_bf16(sdy[0], sdy[1]), pk_bf16(sdy[2], sdy[3])});
        cb2 = __builtin_bit_cast(bf16x8, zz);
        break;
      default:
        cb0 = __builtin_bit_cast(bf16x8, (u32x4){
            pk_bf16(sny[4], snz[0]), pk_bf16(snz[1], snz[2]),
            pk_bf16(snz[3], snz[4]), pk_bf16(csx[0], csx[1])});
        cb1 = __builtin_bit_cast(bf16x8, (u32x4){
            pk_bf16(sdz[0], sdz[1]), pk_bf16(sdz[2], sdz[3]),
            pk_bf16(cdx[0], cdx[1]), pk_bf16(cdx[2], cdx[3])});
        cb2 = __builtin_bit_cast(bf16x8, zz);
        break;
    }

    // ---- GEMM1: D1[hid][pt] = W0^T x feat^T, K=96 ----
    f32x4 acc1[8];
#pragma unroll
    for (int m = 0; m < 8; m++) acc1[m] = (f32x4){0.f, 0.f, 0.f, 0.f};
#pragma unroll
    for (int m = 0; m < 8; m++) {
      bf16x8 a0 = *(const bf16x8*)(sW0 + (m * 16 + l15) * W0K + g * 8);
      acc1[m] = __builtin_amdgcn_mfma_f32_16x16x32_bf16(a0, cb0, acc1[m], 0, 0, 0);
      bf16x8 a1 = *(const bf16x8*)(sW0 + (m * 16 + l15) * W0K + 32 + g * 8);
      acc1[m] = __builtin_amdgcn_mfma_f32_16x16x32_bf16(a1, cb1, acc1[m], 0, 0, 0);
      bf16x8 a2 = *(const bf16x8*)(sW0 + (m * 16 + l15) * W0K + 64 + g * 8);
      acc1[m] = __builtin_amdgcn_mfma_f32_16x16x32_bf16(a2, cb2, acc1[m], 0, 0, 0);
    }
#pragma unroll
    for (int m = 0; m < 8; m++) {
      f32x4 bias = *(const f32x4*)(sB0 + m * 16 + g * 4);
      float h0 = fmaxf(acc1[m][0] + bias[0], 0.f);
      float h1 = fmaxf(acc1[m][1] + bias[1], 0.f);
      float h2 = fmaxf(acc1[m][2] + bias[2], 0.f);
      float h3 = fmaxf(acc1[m][3] + bias[3], 0.f);
      *(uint2*)(myH + l15 * W1K + m * 16 + g * 4) = make_uint2(pk_bf16(h0, h1), pk_bf16(h2, h3));
    }

    // ---- GEMM2: D2[hid2][pt] = W1^T x h1^T, K=128 ----
    f32x4 acc2[8];
#pragma unroll
    for (int m = 0; m < 8; m++) acc2[m] = (f32x4){0.f, 0.f, 0.f, 0.f};
    const unsigned short* hb = myH + l15 * W1K + g * 8;
#pragma unroll
    for (int ks = 0; ks < 4; ks++) {
      bf16x8 bfrag = *(const bf16x8*)(hb + ks * 32);
#pragma unroll
      for (int m = 0; m < 8; m++) {
        bf16x8 afrag = *(const bf16x8*)(sW1 + (m * 16 + l15) * W1K + ks * 32 + g * 8);
        acc2[m] = __builtin_amdgcn_mfma_f32_16x16x32_bf16(afrag, bfrag, acc2[m], 0, 0, 0);
      }
    }
#pragma unroll
    for (int m = 0; m < 8; m++) {
      f32x4 bias = *(const f32x4*)(sB1 + m * 16 + g * 4);
      float h0 = fmaxf(acc2[m][0] + bias[0], 0.f);
      float h1 = fmaxf(acc2[m][1] + bias[1], 0.f);
      float h2 = fmaxf(acc2[m][2] + bias[2], 0.f);
      float h3 = fmaxf(acc2[m][3] + bias[3], 0.f);
      *(uint2*)(myH + l15 * W1K + m * 16 + g * 4) = make_uint2(pk_bf16(h0, h1), pk_bf16(h2, h3));
    }

    // ---- GEMM3: D3[ch][pt] = W2^T x h2^T, K=128, 1 tile ----
    f32x4 acc3 = (f32x4){0.f, 0.f, 0.f, 0.f};
#pragma unroll
    for (int ks = 0; ks < 4; ks++) {
      bf16x8 bfrag = *(const bf16x8*)(hb + ks * 32);
      bf16x8 afrag = *(const bf16x8*)(sW2 + l15 * W1K + ks * 32 + g * 8);
      acc3 = __builtin_amdgcn_mfma_f32_16x16x32_bf16(afrag, bfrag, acc3, 0, 0, 0);
    }
    if (g == 0) {   // rows 0..3 = channels; only 0..2 valid
      rgb[pt * 3 + 0] = sigm_(acc3[0] + sB2[0]);
      rgb[pt * 3 + 1] = sigm_(acc3[1] + sB2[1]);
      rgb[pt * 3 + 2] = sigm_(acc3[2] + sB2[2]);
    }
  }
}

// ============ per-ray scan + composite (1 wave / ray) ============
__global__ __launch_bounds__(256) void vox_scan_kernel(
    const float* __restrict__ alpha, const float* __restrict__ rgb,
    const int* __restrict__ ray_id, float* __restrict__ out, int M, int NR) {
  int wave = (int)((blockIdx.x * blockDim.x + threadIdx.x) >> 6);
  int lane = threadIdx.x & 63;
  if (wave >= NR) return;
  int r = wave;
  int lo = 0, hi = M;
  while (lo < hi) { int mid = (lo + hi) >> 1; if (ray_id[mid] < r) lo = mid + 1; else hi = mid; }
  int start = lo; hi = M;
  while (lo < hi) { int mid = (lo + hi) >> 1; if (ray_id[mid] < r + 1) lo = mid + 1; else hi = mid; }
  int end = lo;

  float carry = 0.f, cr = 0.f, cg = 0.f, cb = 0.f;
  for (int s = start; s < end; s += 64) {
    int idx = s + lane;
    bool valid = idx < end;
    float a = valid ? alpha[idx] : 0.f;
    float l = valid ? log1pf(-fminf(a, 1.f - 1e-7f)) : 0.f;
    float sc = l;
#pragma unroll
    for (int off = 1; off < 64; off <<= 1) {
      float t = __shfl_up(sc, (unsigned)off);
      if (lane >= off) sc += t;
    }
    if (valid) {
      float T = expf(carry + (sc - l));
      float w = a * T;
      cr = fmaf(w, rgb[3 * idx + 0], cr);
      cg = fmaf(w, rgb[3 * idx + 1], cg);
      cb = fmaf(w, rgb[3 * idx + 2], cb);
    }
    carry += __shfl(sc, 63);
  }
#pragma unroll
  for (int off = 32; off > 0; off >>= 1) {
    cr += __shfl_down(cr, (unsigned)off);
    cg += __shfl_down(cg, (unsigned)off);
    cb += __shfl_down(cb, (unsigned)off);
  }
  if (lane == 0) {
    float ail = expf(carry);
    out[3 * r + 0] = cr + ail;
    out[3 * r + 1] = cg + ail;
    out[3 * r + 2] = cb + ail;
  }
}

// ============ fallback (round-1 monolithic path, used if ws too small) ============
__global__ __launch_bounds__(256) void vox_transpose_w0(
    const float* __restrict__ w0, float* __restrict__ w0t) {
  for (int idx = threadIdx.x; idx < 128 * 80; idx += 256) {
    int j = idx / 80, k = idx - j * 80;
    w0t[idx] = (k < 75) ? w0[k * 128 + j] : 0.f;
  }
}

__global__ __launch_bounds__(256) void vox_point_kernel(
    const float* __restrict__ ray_pts, const float* __restrict__ rays_d,
    const float* __restrict__ sdf_vol, const float* __restrict__ k0_vol,
    const float* __restrict__ w0t, const float* __restrict__ b0,
    const float* __restrict__ w1, const float* __restrict__ b1,
    const float* __restrict__ w2, const float* __restrict__ b2,
    const float* __restrict__ s_val, const int* __restrict__ ray_id,
    float* __restrict__ alpha_out, float* __restrict__ rgb_out, int M) {
  int i = blockIdx.x * 256 + threadIdx.x;
  if (i >= M) return;
  float px = ray_pts[3 * i + 0], py = ray_pts[3 * i + 1], pz = ray_pts[3 * i + 2];
  const float SC = 0.5f * 159.f;
  float ux = fminf(fmaxf((px + 1.f) * SC, 0.f), 159.f);
  float uy = fminf(fmaxf((py + 1.f) * SC, 0.f), 159.f);
  float uz = fminf(fmaxf((pz + 1.f) * SC, 0.f), 159.f);
  int ix = min((int)ux, 158), iy = min((int)uy, 158), iz = min((int)uz, 158);
  float fx = ux - (float)ix, fy = uy - (float)iy, fz = uz - (float)iz;
  float wx0 = 1.f - fx, wy0 = 1.f - fy, wz0 = 1.f - fz;
  float w000 = wx0 * wy0 * wz0, w001 = wx0 * wy0 * fz;
  float w010 = wx0 * fy * wz0,  w011 = wx0 * fy * fz;
  float w100 = fx * wy0 * wz0,  w101 = fx * wy0 * fz;
  float w110 = fx * fy * wz0,   w111 = fx * fy * fz;
  int base = (ix * GRIDN + iy) * GRIDN + iz;
  const float* V = sdf_vol;
  float c000 = V[base],          c001 = V[base + 1];
  float c010 = V[base + SY],     c011 = V[base + SY + 1];
  float c100 = V[base + SX],     c101 = V[base + SX + 1];
  float c110 = V[base + SX + SY], c111 = V[base + SX + SY + 1];
  float xm00 = V[base - SX],          xm01 = V[base - SX + 1];
  float xm10 = V[base - SX + SY],     xm11 = V[base - SX + SY + 1];
  float xp00 = V[base + 2 * SX],      xp01 = V[base + 2 * SX + 1];
  float xp10 = V[base + 2 * SX + SY], xp11 = V[base + 2 * SX + SY + 1];
  float ym00 = V[base - SY],          ym01 = V[base - SY + 1];
  float ym10 = V[base + SX - SY],     ym11 = V[base + SX - SY + 1];
  float yp00 = V[base + 2 * SY],      yp01 = V[base + 2 * SY + 1];
  float yp10 = V[base + SX + 2 * SY], yp11 = V[base + SX + 2 * SY + 1];
  float zm00 = V[base - 1],           zm01 = V[base + SY - 1];
  float zm10 = V[base + SX - 1],      zm11 = V[base + SX + SY - 1];
  float zp00 = V[base + 2],           zp01 = V[base + SY + 2];
  float zp10 = V[base + SX + 2],      zp11 = V[base + SX + SY + 2];
  float sdf = w000 * c000 + w001 * c001 + w010 * c010 + w011 * c011 +
              w100 * c100 + w101 * c101 + w110 * c110 + w111 * c111;
  const float INV2H = 159.f / 4.f;
  float gx = (w000 * (c100 - xm00) + w001 * (c101 - xm01) +
              w010 * (c110 - xm10) + w011 * (c111 - xm11) +
              w100 * (xp00 - c000) + w101 * (xp01 - c001) +
              w110 * (xp10 - c010) + w111 * (xp11 - c011)) * INV2H;
  float gy = (w000 * (c010 - ym00) + w001 * (c011 - ym01) +
              w100 * (c110 - ym10) + w101 * (c111 - ym11) +
              w010 * (yp00 - c000) + w011 * (yp01 - c001) +
              w110 * (yp10 - c100) + w111 * (yp11 - c101)) * INV2H;
  float gz = (w000 * (c001 - zm00) + w010 * (c011 - zm01) +
              w100 * (c101 - zm10) + w110 * (c111 - zm11) +
              w001 * (zp00 - c000) + w011 * (zp01 - c010) +
              w101 * (zp10 - c100) + w111 * (zp11 - c110)) * INV2H;
  float ginv = 1.f / (sqrtf(gx * gx + gy * gy + gz * gz) + 1e-8f);
  float gnx = gx * ginv, gny = gy * ginv, gnz = gz * ginv;
  int rid = ray_id[i];
  float ddx = rays_d[3 * rid + 0], ddy = rays_d[3 * rid + 1], ddz = rays_d[3 * rid + 2];
  float true_cos = ddx * gnx + ddy * gny + ddz * gnz;
  float iter_cos = fminf(true_cos, 0.f);
  float inv_s = 1.f / s_val[0];
  float e = iter_cos * (DIST_C * 0.5f);
  float prev_cdf = sigm_((sdf - e) * inv_s);
  float next_cdf = sigm_((sdf + e) * inv_s);
  float alpha = fminf(fmaxf((prev_cdf - next_cdf + 1e-5f) / (prev_cdf + 1e-5f), 0.f), 1.f);
  alpha_out[i] = alpha;
  float feat[75];
  {
    const int offs[8] = {0, 1, SY, SY + 1, SX, SX + 1, SX + SY, SX + SY + 1};
    const float wts[8] = {w000, w001, w010, w011, w100, w101, w110, w111};
#pragma unroll
    for (int c = 0; c < 12; c++) {
      const float* kc = k0_vol + c * N3 + base;
      float acc = 0.f;
#pragma unroll
      for (int t = 0; t < 8; t++) acc = fmaf(wts[t], kc[offs[t]], acc);
      feat[c] = acc;
    }
  }
  float x01 = (px + 1.f) * 0.5f, y01 = (py + 1.f) * 0.5f, z01 = (pz + 1.f) * 0.5f;
  feat[12] = x01; feat[13] = y01; feat[14] = z01;
#pragma unroll
  for (int l = 0; l < 5; l++) {
    float f = (float)(1 << l), s, c;
    sincosf(x01 * f, &s, &c); feat[15 + l] = s; feat[30 + l] = c;
    sincosf(y01 * f, &s, &c); feat[20 + l] = s; feat[35 + l] = c;
    sincosf(z01 * f, &s, &c); feat[25 + l] = s; feat[40 + l] = c;
  }
  feat[45] = ddx; feat[46] = ddy; feat[47] = ddz;
#pragma unroll
  for (int l = 0; l < 4; l++) {
    float f = (float)(1 << l), s, c;
    sincosf(ddx * f, &s, &c); feat[48 + l] = s; feat[60 + l] = c;
    sincosf(ddy * f, &s, &c); feat[52 + l] = s; feat[64 + l] = c;
    sincosf(ddz * f, &s, &c); feat[56 + l] = s; feat[68 + l] = c;
  }
  feat[72] = gnx; feat[73] = gny; feat[74] = gnz;
  float rr = 0.f, rg = 0.f, rb = 0.f;
#pragma unroll 1
  for (int half = 0; half < 2; ++half) {
    float acc[64];
#pragma unroll
    for (int t = 0; t < 64; t++) acc[t] = b1[half * 64 + t];
#pragma unroll 1
    for (int j = 0; j < 128; ++j) {
      float h = b0[j];
      const float* wr = w0t + j * 80;
#pragma unroll
      for (int k = 0; k < 75; k++) h = fmaf(feat[k], wr[k], h);
      h = fmaxf(h, 0.f);
      const float* w1r = w1 + j * 128 + half * 64;
#pragma unroll
      for (int t = 0; t < 64; t++) acc[t] = fmaf(h, w1r[t], acc[t]);
    }
#pragma unroll
    for (int t = 0; t < 64; t++) {
      float h2 = fmaxf(acc[t], 0.f);
      int j2 = half * 64 + t;
      rr = fmaf(h2, w2[3 * j2 + 0], rr);
      rg = fmaf(h2, w2[3 * j2 + 1], rg);
      rb = fmaf(h2, w2[3 * j2 + 2], rb);
    }
  }
  rgb_out[3 * i + 0] = sigm_(rr + b2[0]);
  rgb_out[3 * i + 1] = sigm_(rg + b2[1]);
  rgb_out[3 * i + 2] = sigm_(rb + b2[2]);
}

extern "C" void kernel_launch(void* const* d_in, const int* in_sizes, int n_in,
                              void* d_out, int out_size, void* d_ws, size_t ws_size,
                              hipStream_t stream) {
  const float* ray_pts = (const float*)d_in[0];
  const float* rays_d  = (const float*)d_in[1];
  const float* sdf_vol = (const float*)d_in[2];
  const float* k0_vol  = (const float*)d_in[3];
  const float* w0      = (const float*)d_in[4];
  const float* b0      = (const float*)d_in[5];
  const float* w1      = (const float*)d_in[6];
  const float* b1      = (const float*)d_in[7];
  const float* w2      = (const float*)d_in[8];
  const float* b2      = (const float*)d_in[9];
  const float* s_val   = (const float*)d_in[10];
  const int*   ray_id  = (const int*)d_in[11];
  float* out = (float*)d_out;

  int M  = in_sizes[0] / 3;   // 1048576
  int NR = in_sizes[1] / 3;   // 8192

  char* ws = (char*)d_ws;
  size_t offVR   = 0;                                  // N3*32 combined records
  size_t offTD   = offVR + (size_t)N3 * 32;            // M*32 tap digests
  size_t offA    = offTD + (size_t)M * 32;
  size_t offRgb  = offA + (size_t)M * 4;
  size_t offW0   = offRgb + (size_t)M * 12;
  size_t offW1   = offW0 + (size_t)128 * W0K * 2;
  size_t offW2   = offW1 + (size_t)128 * W1K * 2;
  size_t need    = offW2 + (size_t)16 * W1K * 2;

  if (ws_size >= need && (M % 256) == 0) {
    unsigned short* VR = (unsigned short*)(ws + offVR);
    unsigned short* TD = (unsigned short*)(ws + offTD);
    float* alpha_ws = (float*)(ws + offA);
    float* rgb_ws = (float*)(ws + offRgb);
    unsigned short* W0B = (unsigned short*)(ws + offW0);
    unsigned short* W1B = (unsigned short*)(ws + offW1);
    unsigned short* W2B = (unsigned short*)(ws + offW2);

    int ngroups = M / 256;
    vox_repack_all<<<(N3 + 255) / 256, 256, 0, stream>>>(sdf_vol, k0_vol, VR);
    vox_repack_w<<<(128 * W1K + 255) / 256, 256, 0, stream>>>(w0, w1, w2, W0B, W1B, W2B);
    vox_gather_kernel<<<(M + 255) / 256, 256, 0, stream>>>(
        ray_pts, rays_d, VR, s_val, ray_id, alpha_ws, TD, M);
    vox_mlp_kernel<<<(ngroups + TPB - 1) / TPB, 1024, 0, stream>>>(
        ray_pts, rays_d, ray_id, TD, W0B, W1B, W2B, b0, b1, b2, rgb_ws, ngroups);
    vox_scan_kernel<<<(NR * 64 + 255) / 256, 256, 0, stream>>>(
        alpha_ws, rgb_ws, ray_id, out, M, NR);
  } else {
    float* alpha_ws = (float*)ws;
    float* rgb_ws   = (float*)(ws + (size_t)M * 4);
    float* w0t_ws   = (float*)(ws + (size_t)M * 16);
    vox_transpose_w0<<<1, 256, 0, stream>>>(w0, w0t_ws);
    vox_point_kernel<<<(M + 255) / 256, 256, 0, stream>>>(
        ray_pts, rays_d, sdf_vol, k0_vol, w0t_ws, b0, w1, b1, w2, b2,
        s_val, ray_id, alpha_ws, rgb_ws, M);
    vox_scan_kernel<<<(NR * 64 + 255) / 256, 256, 0, stream>>>(
        alpha_ws, rgb_ws, ray_id, out, M, NR);
  }
}

// Round 17
// 304.946 us; speedup vs baseline: 6.8233x; 1.0383x over previous
//
#include <hip/hip_runtime.h>
#include <math.h>

#define GRIDN 160
#define N3 (160*160*160)
#define SX (160*160)
#define SY 160
#define DIST_C 0.005f
#define W0K 104   // sW0 row stride (ushorts), K=96 used
#define W1K 136   // sW1/sW2/sH row stride (ushorts), K=128 used
#define TPB 16    // groups (of 256 points) per MLP block -> grid = 256 = 1 block/CU

__device__ __forceinline__ float sigm_(float x) { return 1.f / (1.f + expf(-x)); }
__device__ __forceinline__ unsigned short f2bf(float x) {
  unsigned u = __builtin_bit_cast(unsigned, x);
  u = (u + 0x7fffu + ((u >> 16) & 1u)) >> 16;
  return (unsigned short)u;
}
__device__ __forceinline__ unsigned pk_bf16(float a, float b) {
  return (unsigned)f2bf(a) | ((unsigned)f2bf(b) << 16);
}
__device__ __forceinline__ float bf_lo(unsigned u) { return __builtin_bit_cast(float, u << 16); }
__device__ __forceinline__ float bf_hi(unsigned u) { return __builtin_bit_cast(float, u & 0xffff0000u); }
__device__ __forceinline__ unsigned short f2h(float x) {
  _Float16 h = (_Float16)x; return __builtin_bit_cast(unsigned short, h);
}
__device__ __forceinline__ float h_lo(unsigned u) {
  return (float)__builtin_bit_cast(_Float16, (unsigned short)(u & 0xffffu));
}
__device__ __forceinline__ float h_hi(unsigned u) {
  return (float)__builtin_bit_cast(_Float16, (unsigned short)(u >> 16));
}

typedef __attribute__((ext_vector_type(8))) short bf16x8;
typedef __attribute__((ext_vector_type(4))) float f32x4;
typedef __attribute__((ext_vector_type(4))) unsigned u32x4;

// ==== fused repack -> 32B voxel record: [sdf,gx,gy,gz](f16) + k0 ch0..11 (bf16) ====
__global__ __launch_bounds__(256) void vox_repack_all(
    const float* __restrict__ V, const float* __restrict__ k0,
    unsigned short* __restrict__ VR) {
  int idx = blockIdx.x * 256 + threadIdx.x;
  if (idx >= N3) return;
  int z = idx % GRIDN; int t = idx / GRIDN; int y = t % GRIDN; int x = t / GRIDN;
  float v = V[idx];
  float xp = (x < 159) ? V[idx + SX] : v, xm = (x > 0) ? V[idx - SX] : v;
  float yp = (y < 159) ? V[idx + SY] : v, ym = (y > 0) ? V[idx - SY] : v;
  float zp = (z < 159) ? V[idx + 1]  : v, zm = (z > 0) ? V[idx - 1]  : v;
  float cx = (x > 0 && x < 159) ? (159.f / 4.f) : (159.f / 2.f);
  float cy = (y > 0 && y < 159) ? (159.f / 4.f) : (159.f / 2.f);
  float cz = (z > 0 && z < 159) ? (159.f / 4.f) : (159.f / 2.f);
  unsigned f0 = (unsigned)f2h(v) | ((unsigned)f2h((xp - xm) * cx) << 16);
  unsigned f1 = (unsigned)f2h((yp - ym) * cy) | ((unsigned)f2h((zp - zm) * cz) << 16);
  unsigned w[6];
#pragma unroll
  for (int j = 0; j < 6; j++) {
    float a = __builtin_nontemporal_load(k0 + (size_t)(2 * j) * N3 + idx);
    float b = __builtin_nontemporal_load(k0 + (size_t)(2 * j + 1) * N3 + idx);
    w[j] = pk_bf16(a, b);
  }
  u32x4* r = (u32x4*)(VR + (size_t)idx * 16);
  r[0] = (u32x4){f0, f1, w[0], w[1]};
  r[1] = (u32x4){w[2], w[3], w[4], w[5]};
}

// ============ repack weights -> transposed bf16 with padded strides ============
__global__ __launch_bounds__(256) void vox_repack_w(
    const float* __restrict__ w0, const float* __restrict__ w1, const float* __restrict__ w2,
    unsigned short* __restrict__ W0B, unsigned short* __restrict__ W1B,
    unsigned short* __restrict__ W2B) {
  int i = blockIdx.x * 256 + threadIdx.x;
  if (i < 128 * W0K) {                    // W0B[c][k] = w0[k][c], k<75
    int c = i / W0K, k = i - c * W0K;
    W0B[i] = (k < 75) ? f2bf(w0[k * 128 + c]) : (unsigned short)0;
  }
  if (i < 128 * W1K) {                    // W1B[c][k] = w1[k][c], k<128
    int c = i / W1K, k = i - c * W1K;
    W1B[i] = (k < 128) ? f2bf(w1[k * 128 + c]) : (unsigned short)0;
  }
  if (i < 16 * W1K) {                     // W2B[c][k] = w2[k][c], c<3, k<128
    int c = i / W1K, k = i - c * W1K;
    W2B[i] = (k < 128 && c < 3) ? f2bf(w2[k * 3 + c]) : (unsigned short)0;
  }
}

// ============ per-ray view-embedding table: 64B/ray, pre-packed per g-slice ========
// word 0-3 : pk(cdy0,cdy1) pk(cdy2,cdy3) pk(cdz0,cdz1) pk(cdz2,cdz3)   [g0 cb2]
// word 4-7 : pk(sdx0,sdx1) pk(sdx2,sdx3) pk(sdy0,sdy1) pk(sdy2,sdy3)   [g2 cb1]
// word 8-11: pk(sdz0,sdz1) pk(sdz2,sdz3) pk(cdx0,cdx1) pk(cdx2,cdx3)   [g3 cb1]
// word12-14: ddx,ddy,ddz f32 bits; word15: 0                            [g1]
__global__ __launch_bounds__(256) void vox_view_table(
    const float* __restrict__ rays_d, unsigned* __restrict__ VT, int NR) {
  int r = blockIdx.x * 256 + threadIdx.x;
  if (r >= NR) return;
  float dx = rays_d[3 * r + 0], dy = rays_d[3 * r + 1], dz = rays_d[3 * r + 2];
  float sx[4], cx[4], sy[4], cy[4], sz[4], cz[4];
#pragma unroll
  for (int l = 0; l < 4; l++) {
    float f = (float)(1 << l);
    __sincosf(dx * f, &sx[l], &cx[l]);
    __sincosf(dy * f, &sy[l], &cy[l]);
    __sincosf(dz * f, &sz[l], &cz[l]);
  }
  u32x4* v = (u32x4*)(VT + (size_t)r * 16);
  v[0] = (u32x4){pk_bf16(cy[0], cy[1]), pk_bf16(cy[2], cy[3]),
                 pk_bf16(cz[0], cz[1]), pk_bf16(cz[2], cz[3])};
  v[1] = (u32x4){pk_bf16(sx[0], sx[1]), pk_bf16(sx[2], sx[3]),
                 pk_bf16(sy[0], sy[1]), pk_bf16(sy[2], sy[3])};
  v[2] = (u32x4){pk_bf16(sz[0], sz[1]), pk_bf16(sz[2], sz[3]),
                 pk_bf16(cx[0], cx[1]), pk_bf16(cx[2], cx[3])};
  v[3] = (u32x4){__builtin_bit_cast(unsigned, dx), __builtin_bit_cast(unsigned, dy),
                 __builtin_bit_cast(unsigned, dz), 0u};
}

// ============ gather: taps + alpha + 32B tap-digest TD = [k0..k11, gn, 0] bf16 ======
__global__ __launch_bounds__(256) void vox_gather_kernel(
    const float* __restrict__ ray_pts, const float* __restrict__ rays_d,
    const unsigned short* __restrict__ VR,
    const float* __restrict__ s_val, const int* __restrict__ ray_id,
    float* __restrict__ alpha_out, unsigned short* __restrict__ TD, int M) {
  int i = blockIdx.x * 256 + threadIdx.x;
  if (i >= M) return;

  float px = ray_pts[3 * i + 0], py = ray_pts[3 * i + 1], pz = ray_pts[3 * i + 2];
  const float SC = 0.5f * 159.f;
  float ux = fminf(fmaxf((px + 1.f) * SC, 0.f), 159.f);
  float uy = fminf(fmaxf((py + 1.f) * SC, 0.f), 159.f);
  float uz = fminf(fmaxf((pz + 1.f) * SC, 0.f), 159.f);
  int ix = min((int)ux, 158), iy = min((int)uy, 158), iz = min((int)uz, 158);
  float fx = ux - (float)ix, fy = uy - (float)iy, fz = uz - (float)iz;
  float wx0 = 1.f - fx, wy0 = 1.f - fy, wz0 = 1.f - fz;
  float wxy[4];
  wxy[0] = wx0 * wy0; wxy[1] = wx0 * fy; wxy[2] = fx * wy0; wxy[3] = fx * fy;
  const int pairoff[4] = {0, SY, SX, SX + SY};
  int base = (ix * GRIDN + iy) * GRIDN + iz;

  u32x4 q[4][4];
#pragma unroll
  for (int t = 0; t < 4; t++) {
    const u32x4* p = (const u32x4*)(VR + (size_t)(base + pairoff[t]) * 16);
    q[t][0] = p[0]; q[t][1] = p[1]; q[t][2] = p[2]; q[t][3] = p[3];
  }

  float sdf = 0.f, gx = 0.f, gy = 0.f, gz = 0.f;
  float k[12];
#pragma unroll
  for (int j = 0; j < 12; j++) k[j] = 0.f;
#pragma unroll
  for (int t = 0; t < 4; t++) {
    float w0z = wxy[t] * wz0, w1z = wxy[t] * fz;
    sdf = fmaf(w0z, h_lo(q[t][0].x), sdf);
    gx  = fmaf(w0z, h_hi(q[t][0].x), gx);
    gy  = fmaf(w0z, h_lo(q[t][0].y), gy);
    gz  = fmaf(w0z, h_hi(q[t][0].y), gz);
    k[0]  = fmaf(w0z, bf_lo(q[t][0].z), k[0]);
    k[1]  = fmaf(w0z, bf_hi(q[t][0].z), k[1]);
    k[2]  = fmaf(w0z, bf_lo(q[t][0].w), k[2]);
    k[3]  = fmaf(w0z, bf_hi(q[t][0].w), k[3]);
    k[4]  = fmaf(w0z, bf_lo(q[t][1].x), k[4]);
    k[5]  = fmaf(w0z, bf_hi(q[t][1].x), k[5]);
    k[6]  = fmaf(w0z, bf_lo(q[t][1].y), k[6]);
    k[7]  = fmaf(w0z, bf_hi(q[t][1].y), k[7]);
    k[8]  = fmaf(w0z, bf_lo(q[t][1].z), k[8]);
    k[9]  = fmaf(w0z, bf_hi(q[t][1].z), k[9]);
    k[10] = fmaf(w0z, bf_lo(q[t][1].w), k[10]);
    k[11] = fmaf(w0z, bf_hi(q[t][1].w), k[11]);
    sdf = fmaf(w1z, h_lo(q[t][2].x), sdf);
    gx  = fmaf(w1z, h_hi(q[t][2].x), gx);
    gy  = fmaf(w1z, h_lo(q[t][2].y), gy);
    gz  = fmaf(w1z, h_hi(q[t][2].y), gz);
    k[0]  = fmaf(w1z, bf_lo(q[t][2].z), k[0]);
    k[1]  = fmaf(w1z, bf_hi(q[t][2].z), k[1]);
    k[2]  = fmaf(w1z, bf_lo(q[t][2].w), k[2]);
    k[3]  = fmaf(w1z, bf_hi(q[t][2].w), k[3]);
    k[4]  = fmaf(w1z, bf_lo(q[t][3].x), k[4]);
    k[5]  = fmaf(w1z, bf_hi(q[t][3].x), k[5]);
    k[6]  = fmaf(w1z, bf_lo(q[t][3].y), k[6]);
    k[7]  = fmaf(w1z, bf_hi(q[t][3].y), k[7]);
    k[8]  = fmaf(w1z, bf_lo(q[t][3].z), k[8]);
    k[9]  = fmaf(w1z, bf_hi(q[t][3].z), k[9]);
    k[10] = fmaf(w1z, bf_lo(q[t][3].w), k[10]);
    k[11] = fmaf(w1z, bf_hi(q[t][3].w), k[11]);
  }
  float ginv = 1.f / (sqrtf(gx * gx + gy * gy + gz * gz) + 1e-8f);
  float gnx = gx * ginv, gny = gy * ginv, gnz = gz * ginv;

  int rid = ray_id[i];
  float ddx = rays_d[3 * rid + 0], ddy = rays_d[3 * rid + 1], ddz = rays_d[3 * rid + 2];

  float true_cos = ddx * gnx + ddy * gny + ddz * gnz;
  float iter_cos = fminf(true_cos, 0.f);
  float inv_s = 1.f / s_val[0];
  float e = iter_cos * (DIST_C * 0.5f);
  float prev_cdf = sigm_((sdf - e) * inv_s);
  float next_cdf = sigm_((sdf + e) * inv_s);
  float alpha = (prev_cdf - next_cdf + 1e-5f) / (prev_cdf + 1e-5f);
  alpha_out[i] = fminf(fmaxf(alpha, 0.f), 1.f);

  u32x4* tb = (u32x4*)(TD + (size_t)i * 16);
  tb[0] = (u32x4){pk_bf16(k[0], k[1]), pk_bf16(k[2], k[3]),
                  pk_bf16(k[4], k[5]), pk_bf16(k[6], k[7])};
  tb[1] = (u32x4){pk_bf16(k[8], k[9]), pk_bf16(k[10], k[11]),
                  pk_bf16(gnx, gny), pk_bf16(gnz, 0.f)};
}

// ======== MFMA MLP: pos trig via 3 sincos + doubling; view trig from VT table ======
__global__ __launch_bounds__(1024, 1) void vox_mlp_kernel(
    const float* __restrict__ ray_pts, const unsigned* __restrict__ VT,
    const int* __restrict__ ray_id, const unsigned short* __restrict__ TD,
    const unsigned short* __restrict__ W0B, const unsigned short* __restrict__ W1B,
    const unsigned short* __restrict__ W2B,
    const float* __restrict__ b0, const float* __restrict__ b1,
    const float* __restrict__ b2, float* __restrict__ rgb, int ngroups) {
  __shared__ __align__(16) unsigned short sW0[128 * W0K];
  __shared__ __align__(16) unsigned short sW1[128 * W1K];
  __shared__ __align__(16) unsigned short sW2[16 * W1K];
  __shared__ __align__(16) unsigned short sH[16 * 16 * W1K];
  __shared__ __align__(16) float sB0[128], sB1[128], sB2[16];

  {
    const uint4* s0 = (const uint4*)W0B; uint4* d0 = (uint4*)sW0;
    for (int i = threadIdx.x; i < 128 * W0K / 8; i += 1024) d0[i] = s0[i];
    const uint4* s1 = (const uint4*)W1B; uint4* d1 = (uint4*)sW1;
    for (int i = threadIdx.x; i < 128 * W1K / 8; i += 1024) d1[i] = s1[i];
    const uint4* s2 = (const uint4*)W2B; uint4* d2 = (uint4*)sW2;
    for (int i = threadIdx.x; i < 16 * W1K / 8; i += 1024) d2[i] = s2[i];
    if (threadIdx.x < 128) { sB0[threadIdx.x] = b0[threadIdx.x]; sB1[threadIdx.x] = b1[threadIdx.x]; }
    if (threadIdx.x < 16) sB2[threadIdx.x] = (threadIdx.x < 3) ? b2[threadIdx.x] : 0.f;
  }
  __syncthreads();

  const int wid = (int)(threadIdx.x >> 6), lane = (int)(threadIdx.x & 63);
  const int l15 = lane & 15, g = lane >> 4;
  unsigned short* myH = sH + wid * (16 * W1K);

#pragma unroll 1
  for (int t = 0; t < TPB; ++t) {
    int grp = blockIdx.x * TPB + t;
    if (grp >= ngroups) break;
    const int pt0 = grp * 256 + wid * 16;
    const int pt = pt0 + l15;

    float px = ray_pts[3 * pt + 0], py = ray_pts[3 * pt + 1], pz = ray_pts[3 * pt + 2];
    int rid = ray_id[pt];
    float x01 = (px + 1.f) * 0.5f, y01 = (py + 1.f) * 0.5f, z01 = (pz + 1.f) * 0.5f;
    // positional trig: 3 sincos + angle doubling (s2=2sc, c2=1-2s^2)
    float snx[5], csx[5], sny[5], csy[5], snz[5], csz[5];
    __sincosf(x01, &snx[0], &csx[0]);
    __sincosf(y01, &sny[0], &csy[0]);
    __sincosf(z01, &snz[0], &csz[0]);
#pragma unroll
    for (int l = 1; l < 5; l++) {
      snx[l] = 2.f * snx[l-1] * csx[l-1]; csx[l] = 1.f - 2.f * snx[l-1] * snx[l-1];
      sny[l] = 2.f * sny[l-1] * csy[l-1]; csy[l] = 1.f - 2.f * sny[l-1] * sny[l-1];
      snz[l] = 2.f * snz[l-1] * csz[l-1]; csz[l] = 1.f - 2.f * snz[l-1] * snz[l-1];
    }
    const u32x4* vt = (const u32x4*)(VT + (size_t)rid * 16);
    const u32x4* tdp = (const u32x4*)(TD + (size_t)pt * 16);

    // ---- build this lane's three B-slices ----
    bf16x8 cb0, cb1, cb2;
    const u32x4 zz = (u32x4){0u, 0u, 0u, 0u};
    switch (g) {
      case 0: {
        u32x4 td0 = tdp[0];
        cb0 = __builtin_bit_cast(bf16x8, td0);
        cb1 = __builtin_bit_cast(bf16x8, (u32x4){
            pk_bf16(csx[2], csx[3]), pk_bf16(csx[4], csy[0]),
            pk_bf16(csy[1], csy[2]), pk_bf16(csy[3], csy[4])});
        cb2 = __builtin_bit_cast(bf16x8, vt[0]);
        break;
      }
      case 1: {
        u32x4 td1 = tdp[1];
        u32x4 v3 = vt[3];
        float ddx = __builtin_bit_cast(float, v3.x);
        float ddy = __builtin_bit_cast(float, v3.y);
        float ddz = __builtin_bit_cast(float, v3.z);
        cb0 = __builtin_bit_cast(bf16x8, (u32x4){
            td1.x, td1.y, pk_bf16(x01, y01), pk_bf16(z01, snx[0])});
        cb1 = __builtin_bit_cast(bf16x8, (u32x4){
            pk_bf16(csz[0], csz[1]), pk_bf16(csz[2], csz[3]),
            pk_bf16(csz[4], ddx), pk_bf16(ddy, ddz)});
        cb2 = __builtin_bit_cast(bf16x8, (u32x4){td1.z, td1.w, 0u, 0u});
        break;
      }
      case 2:
        cb0 = __builtin_bit_cast(bf16x8, (u32x4){
            pk_bf16(snx[1], snx[2]), pk_bf16(snx[3], snx[4]),
            pk_bf16(sny[0], sny[1]), pk_bf16(sny[2], sny[3])});
        cb1 = __builtin_bit_cast(bf16x8, vt[1]);
        cb2 = __builtin_bit_cast(bf16x8, zz);
        break;
      default:
        cb0 = __builtin_bit_cast(bf16x8, (u32x4){
            pk_bf16(sny[4], snz[0]), pk_bf16(snz[1], snz[2]),
            pk_bf16(snz[3], snz[4]), pk_bf16(csx[0], csx[1])});
        cb1 = __builtin_bit_cast(bf16x8, vt[2]);
        cb2 = __builtin_bit_cast(bf16x8, zz);
        break;
    }

    // ---- GEMM1: D1[hid][pt] = W0^T x feat^T, K=96 ----
    f32x4 acc1[8];
#pragma unroll
    for (int m = 0; m < 8; m++) acc1[m] = (f32x4){0.f, 0.f, 0.f, 0.f};
#pragma unroll
    for (int m = 0; m < 8; m++) {
      bf16x8 a0 = *(const bf16x8*)(sW0 + (m * 16 + l15) * W0K + g * 8);
      acc1[m] = __builtin_amdgcn_mfma_f32_16x16x32_bf16(a0, cb0, acc1[m], 0, 0, 0);
      bf16x8 a1 = *(const bf16x8*)(sW0 + (m * 16 + l15) * W0K + 32 + g * 8);
      acc1[m] = __builtin_amdgcn_mfma_f32_16x16x32_bf16(a1, cb1, acc1[m], 0, 0, 0);
      bf16x8 a2 = *(const bf16x8*)(sW0 + (m * 16 + l15) * W0K + 64 + g * 8);
      acc1[m] = __builtin_amdgcn_mfma_f32_16x16x32_bf16(a2, cb2, acc1[m], 0, 0, 0);
    }
#pragma unroll
    for (int m = 0; m < 8; m++) {
      f32x4 bias = *(const f32x4*)(sB0 + m * 16 + g * 4);
      float h0 = fmaxf(acc1[m][0] + bias[0], 0.f);
      float h1 = fmaxf(acc1[m][1] + bias[1], 0.f);
      float h2 = fmaxf(acc1[m][2] + bias[2], 0.f);
      float h3 = fmaxf(acc1[m][3] + bias[3], 0.f);
      *(uint2*)(myH + l15 * W1K + m * 16 + g * 4) = make_uint2(pk_bf16(h0, h1), pk_bf16(h2, h3));
    }

    // ---- GEMM2: D2[hid2][pt] = W1^T x h1^T, K=128 ----
    f32x4 acc2[8];
#pragma unroll
    for (int m = 0; m < 8; m++) acc2[m] = (f32x4){0.f, 0.f, 0.f, 0.f};
    const unsigned short* hb = myH + l15 * W1K + g * 8;
#pragma unroll
    for (int ks = 0; ks < 4; ks++) {
      bf16x8 bfrag = *(const bf16x8*)(hb + ks * 32);
#pragma unroll
      for (int m = 0; m < 8; m++) {
        bf16x8 afrag = *(const bf16x8*)(sW1 + (m * 16 + l15) * W1K + ks * 32 + g * 8);
        acc2[m] = __builtin_amdgcn_mfma_f32_16x16x32_bf16(afrag, bfrag, acc2[m], 0, 0, 0);
      }
    }
#pragma unroll
    for (int m = 0; m < 8; m++) {
      f32x4 bias = *(const f32x4*)(sB1 + m * 16 + g * 4);
      float h0 = fmaxf(acc2[m][0] + bias[0], 0.f);
      float h1 = fmaxf(acc2[m][1] + bias[1], 0.f);
      float h2 = fmaxf(acc2[m][2] + bias[2], 0.f);
      float h3 = fmaxf(acc2[m][3] + bias[3], 0.f);
      *(uint2*)(myH + l15 * W1K + m * 16 + g * 4) = make_uint2(pk_bf16(h0, h1), pk_bf16(h2, h3));
    }

    // ---- GEMM3: D3[ch][pt] = W2^T x h2^T, K=128, 1 tile ----
    f32x4 acc3 = (f32x4){0.f, 0.f, 0.f, 0.f};
#pragma unroll
    for (int ks = 0; ks < 4; ks++) {
      bf16x8 bfrag = *(const bf16x8*)(hb + ks * 32);
      bf16x8 afrag = *(const bf16x8*)(sW2 + l15 * W1K + ks * 32 + g * 8);
      acc3 = __builtin_amdgcn_mfma_f32_16x16x32_bf16(afrag, bfrag, acc3, 0, 0, 0);
    }
    if (g == 0) {   // rows 0..3 = channels; only 0..2 valid
      rgb[pt * 3 + 0] = sigm_(acc3[0] + sB2[0]);
      rgb[pt * 3 + 1] = sigm_(acc3[1] + sB2[1]);
      rgb[pt * 3 + 2] = sigm_(acc3[2] + sB2[2]);
    }
  }
}

// ============ per-ray scan + composite (1 wave / ray) ============
__global__ __launch_bounds__(256) void vox_scan_kernel(
    const float* __restrict__ alpha, const float* __restrict__ rgb,
    const int* __restrict__ ray_id, float* __restrict__ out, int M, int NR) {
  int wave = (int)((blockIdx.x * blockDim.x + threadIdx.x) >> 6);
  int lane = threadIdx.x & 63;
  if (wave >= NR) return;
  int r = wave;
  int lo = 0, hi = M;
  while (lo < hi) { int mid = (lo + hi) >> 1; if (ray_id[mid] < r) lo = mid + 1; else hi = mid; }
  int start = lo; hi = M;
  while (lo < hi) { int mid = (lo + hi) >> 1; if (ray_id[mid] < r + 1) lo = mid + 1; else hi = mid; }
  int end = lo;

  float carry = 0.f, cr = 0.f, cg = 0.f, cb = 0.f;
  for (int s = start; s < end; s += 64) {
    int idx = s + lane;
    bool valid = idx < end;
    float a = valid ? alpha[idx] : 0.f;
    float l = valid ? log1pf(-fminf(a, 1.f - 1e-7f)) : 0.f;
    float sc = l;
#pragma unroll
    for (int off = 1; off < 64; off <<= 1) {
      float t = __shfl_up(sc, (unsigned)off);
      if (lane >= off) sc += t;
    }
    if (valid) {
      float T = expf(carry + (sc - l));
      float w = a * T;
      cr = fmaf(w, rgb[3 * idx + 0], cr);
      cg = fmaf(w, rgb[3 * idx + 1], cg);
      cb = fmaf(w, rgb[3 * idx + 2], cb);
    }
    carry += __shfl(sc, 63);
  }
#pragma unroll
  for (int off = 32; off > 0; off >>= 1) {
    cr += __shfl_down(cr, (unsigned)off);
    cg += __shfl_down(cg, (unsigned)off);
    cb += __shfl_down(cb, (unsigned)off);
  }
  if (lane == 0) {
    float ail = expf(carry);
    out[3 * r + 0] = cr + ail;
    out[3 * r + 1] = cg + ail;
    out[3 * r + 2] = cb + ail;
  }
}

// ============ fallback (round-1 monolithic path, used if ws too small) ============
__global__ __launch_bounds__(256) void vox_transpose_w0(
    const float* __restrict__ w0, float* __restrict__ w0t) {
  for (int idx = threadIdx.x; idx < 128 * 80; idx += 256) {
    int j = idx / 80, k = idx - j * 80;
    w0t[idx] = (k < 75) ? w0[k * 128 + j] : 0.f;
  }
}

__global__ __launch_bounds__(256) void vox_point_kernel(
    const float* __restrict__ ray_pts, const float* __restrict__ rays_d,
    const float* __restrict__ sdf_vol, const float* __restrict__ k0_vol,
    const float* __restrict__ w0t, const float* __restrict__ b0,
    const float* __restrict__ w1, const float* __restrict__ b1,
    const float* __restrict__ w2, const float* __restrict__ b2,
    const float* __restrict__ s_val, const int* __restrict__ ray_id,
    float* __restrict__ alpha_out, float* __restrict__ rgb_out, int M) {
  int i = blockIdx.x * 256 + threadIdx.x;
  if (i >= M) return;
  float px = ray_pts[3 * i + 0], py = ray_pts[3 * i + 1], pz = ray_pts[3 * i + 2];
  const float SC = 0.5f * 159.f;
  float ux = fminf(fmaxf((px + 1.f) * SC, 0.f), 159.f);
  float uy = fminf(fmaxf((py + 1.f) * SC, 0.f), 159.f);
  float uz = fminf(fmaxf((pz + 1.f) * SC, 0.f), 159.f);
  int ix = min((int)ux, 158), iy = min((int)uy, 158), iz = min((int)uz, 158);
  float fx = ux - (float)ix, fy = uy - (float)iy, fz = uz - (float)iz;
  float wx0 = 1.f - fx, wy0 = 1.f - fy, wz0 = 1.f - fz;
  float w000 = wx0 * wy0 * wz0, w001 = wx0 * wy0 * fz;
  float w010 = wx0 * fy * wz0,  w011 = wx0 * fy * fz;
  float w100 = fx * wy0 * wz0,  w101 = fx * wy0 * fz;
  float w110 = fx * fy * wz0,   w111 = fx * fy * fz;
  int base = (ix * GRIDN + iy) * GRIDN + iz;
  const float* V = sdf_vol;
  float c000 = V[base],          c001 = V[base + 1];
  float c010 = V[base + SY],     c011 = V[base + SY + 1];
  float c100 = V[base + SX],     c101 = V[base + SX + 1];
  float c110 = V[base + SX + SY], c111 = V[base + SX + SY + 1];
  float xm00 = V[base - SX],          xm01 = V[base - SX + 1];
  float xm10 = V[base - SX + SY],     xm11 = V[base - SX + SY + 1];
  float xp00 = V[base + 2 * SX],      xp01 = V[base + 2 * SX + 1];
  float xp10 = V[base + 2 * SX + SY], xp11 = V[base + 2 * SX + SY + 1];
  float ym00 = V[base - SY],          ym01 = V[base - SY + 1];
  float ym10 = V[base + SX - SY],     ym11 = V[base + SX - SY + 1];
  float yp00 = V[base + 2 * SY],      yp01 = V[base + 2 * SY + 1];
  float yp10 = V[base + SX + 2 * SY], yp11 = V[base + SX + 2 * SY + 1];
  float zm00 = V[base - 1],           zm01 = V[base + SY - 1];
  float zm10 = V[base + SX - 1],      zm11 = V[base + SX + SY - 1];
  float zp00 = V[base + 2],           zp01 = V[base + SY + 2];
  float zp10 = V[base + SX + 2],      zp11 = V[base + SX + SY + 2];
  float sdf = w000 * c000 + w001 * c001 + w010 * c010 + w011 * c011 +
              w100 * c100 + w101 * c101 + w110 * c110 + w111 * c111;
  const float INV2H = 159.f / 4.f;
  float gx = (w000 * (c100 - xm00) + w001 * (c101 - xm01) +
              w010 * (c110 - xm10) + w011 * (c111 - xm11) +
              w100 * (xp00 - c000) + w101 * (xp01 - c001) +
              w110 * (xp10 - c010) + w111 * (xp11 - c011)) * INV2H;
  float gy = (w000 * (c010 - ym00) + w001 * (c011 - ym01) +
              w100 * (c110 - ym10) + w101 * (c111 - ym11) +
              w010 * (yp00 - c000) + w011 * (yp01 - c001) +
              w110 * (yp10 - c100) + w111 * (yp11 - c101)) * INV2H;
  float gz = (w000 * (c001 - zm00) + w010 * (c011 - zm01) +
              w100 * (c101 - zm10) + w110 * (c111 - zm11) +
              w001 * (zp00 - c000) + w011 * (zp01 - c010) +
              w101 * (zp10 - c100) + w111 * (zp11 - c110)) * INV2H;
  float ginv = 1.f / (sqrtf(gx * gx + gy * gy + gz * gz) + 1e-8f);
  float gnx = gx * ginv, gny = gy * ginv, gnz = gz * ginv;
  int rid = ray_id[i];
  float ddx = rays_d[3 * rid + 0], ddy = rays_d[3 * rid + 1], ddz = rays_d[3 * rid + 2];
  float true_cos = ddx * gnx + ddy * gny + ddz * gnz;
  float iter_cos = fminf(true_cos, 0.f);
  float inv_s = 1.f / s_val[0];
  float e = iter_cos * (DIST_C * 0.5f);
  float prev_cdf = sigm_((sdf - e) * inv_s);
  float next_cdf = sigm_((sdf + e) * inv_s);
  float alpha = fminf(fmaxf((prev_cdf - next_cdf + 1e-5f) / (prev_cdf + 1e-5f), 0.f), 1.f);
  alpha_out[i] = alpha;
  float feat[75];
  {
    const int offs[8] = {0, 1, SY, SY + 1, SX, SX + 1, SX + SY, SX + SY + 1};
    const float wts[8] = {w000, w001, w010, w011, w100, w101, w110, w111};
#pragma unroll
    for (int c = 0; c < 12; c++) {
      const float* kc = k0_vol + c * N3 + base;
      float acc = 0.f;
#pragma unroll
      for (int t = 0; t < 8; t++) acc = fmaf(wts[t], kc[offs[t]], acc);
      feat[c] = acc;
    }
  }
  float x01 = (px + 1.f) * 0.5f, y01 = (py + 1.f) * 0.5f, z01 = (pz + 1.f) * 0.5f;
  feat[12] = x01; feat[13] = y01; feat[14] = z01;
#pragma unroll
  for (int l = 0; l < 5; l++) {
    float f = (float)(1 << l), s, c;
    sincosf(x01 * f, &s, &c); feat[15 + l] = s; feat[30 + l] = c;
    sincosf(y01 * f, &s, &c); feat[20 + l] = s; feat[35 + l] = c;
    sincosf(z01 * f, &s, &c); feat[25 + l] = s; feat[40 + l] = c;
  }
  feat[45] = ddx; feat[46] = ddy; feat[47] = ddz;
#pragma unroll
  for (int l = 0; l < 4; l++) {
    float f = (float)(1 << l), s, c;
    sincosf(ddx * f, &s, &c); feat[48 + l] = s; feat[60 + l] = c;
    sincosf(ddy * f, &s, &c); feat[52 + l] = s; feat[64 + l] = c;
    sincosf(ddz * f, &s, &c); feat[56 + l] = s; feat[68 + l] = c;
  }
  feat[72] = gnx; feat[73] = gny; feat[74] = gnz;
  float rr = 0.f, rg = 0.f, rb = 0.f;
#pragma unroll 1
  for (int half = 0; half < 2; ++half) {
    float acc[64];
#pragma unroll
    for (int t = 0; t < 64; t++) acc[t] = b1[half * 64 + t];
#pragma unroll 1
    for (int j = 0; j < 128; ++j) {
      float h = b0[j];
      const float* wr = w0t + j * 80;
#pragma unroll
      for (int k = 0; k < 75; k++) h = fmaf(feat[k], wr[k], h);
      h = fmaxf(h, 0.f);
      const float* w1r = w1 + j * 128 + half * 64;
#pragma unroll
      for (int t = 0; t < 64; t++) acc[t] = fmaf(h, w1r[t], acc[t]);
    }
#pragma unroll
    for (int t = 0; t < 64; t++) {
      float h2 = fmaxf(acc[t], 0.f);
      int j2 = half * 64 + t;
      rr = fmaf(h2, w2[3 * j2 + 0], rr);
      rg = fmaf(h2, w2[3 * j2 + 1], rg);
      rb = fmaf(h2, w2[3 * j2 + 2], rb);
    }
  }
  rgb_out[3 * i + 0] = sigm_(rr + b2[0]);
  rgb_out[3 * i + 1] = sigm_(rg + b2[1]);
  rgb_out[3 * i + 2] = sigm_(rb + b2[2]);
}

extern "C" void kernel_launch(void* const* d_in, const int* in_sizes, int n_in,
                              void* d_out, int out_size, void* d_ws, size_t ws_size,
                              hipStream_t stream) {
  const float* ray_pts = (const float*)d_in[0];
  const float* rays_d  = (const float*)d_in[1];
  const float* sdf_vol = (const float*)d_in[2];
  const float* k0_vol  = (const float*)d_in[3];
  const float* w0      = (const float*)d_in[4];
  const float* b0      = (const float*)d_in[5];
  const float* w1      = (const float*)d_in[6];
  const float* b1      = (const float*)d_in[7];
  const float* w2      = (const float*)d_in[8];
  const float* b2      = (const float*)d_in[9];
  const float* s_val   = (const float*)d_in[10];
  const int*   ray_id  = (const int*)d_in[11];
  float* out = (float*)d_out;

  int M  = in_sizes[0] / 3;   // 1048576
  int NR = in_sizes[1] / 3;   // 8192

  char* ws = (char*)d_ws;
  size_t offVR   = 0;                                  // N3*32 combined records
  size_t offTD   = offVR + (size_t)N3 * 32;            // M*32 tap digests
  size_t offA    = offTD + (size_t)M * 32;
  size_t offRgb  = offA + (size_t)M * 4;
  size_t offW0   = offRgb + (size_t)M * 12;
  size_t offW1   = offW0 + (size_t)128 * W0K * 2;
  size_t offW2   = offW1 + (size_t)128 * W1K * 2;
  size_t offVT   = offW2 + (size_t)16 * W1K * 2;
  size_t need    = offVT + (size_t)NR * 64;

  if (ws_size >= need && (M % 256) == 0) {
    unsigned short* VR = (unsigned short*)(ws + offVR);
    unsigned short* TD = (unsigned short*)(ws + offTD);
    float* alpha_ws = (float*)(ws + offA);
    float* rgb_ws = (float*)(ws + offRgb);
    unsigned short* W0B = (unsigned short*)(ws + offW0);
    unsigned short* W1B = (unsigned short*)(ws + offW1);
    unsigned short* W2B = (unsigned short*)(ws + offW2);
    unsigned* VT = (unsigned*)(ws + offVT);

    int ngroups = M / 256;
    vox_repack_all<<<(N3 + 255) / 256, 256, 0, stream>>>(sdf_vol, k0_vol, VR);
    vox_repack_w<<<(128 * W1K + 255) / 256, 256, 0, stream>>>(w0, w1, w2, W0B, W1B, W2B);
    vox_view_table<<<(NR + 255) / 256, 256, 0, stream>>>(rays_d, VT, NR);
    vox_gather_kernel<<<(M + 255) / 256, 256, 0, stream>>>(
        ray_pts, rays_d, VR, s_val, ray_id, alpha_ws, TD, M);
    vox_mlp_kernel<<<(ngroups + TPB - 1) / TPB, 1024, 0, stream>>>(
        ray_pts, VT, ray_id, TD, W0B, W1B, W2B, b0, b1, b2, rgb_ws, ngroups);
    vox_scan_kernel<<<(NR * 64 + 255) / 256, 256, 0, stream>>>(
        alpha_ws, rgb_ws, ray_id, out, M, NR);
  } else {
    float* alpha_ws = (float*)ws;
    float* rgb_ws   = (float*)(ws + (size_t)M * 4);
    float* w0t_ws   = (float*)(ws + (size_t)M * 16);
    vox_transpose_w0<<<1, 256, 0, stream>>>(w0, w0t_ws);
    vox_point_kernel<<<(M + 255) / 256, 256, 0, stream>>>(
        ray_pts, rays_d, sdf_vol, k0_vol, w0t_ws, b0, w1, b1, w2, b2,
        s_val, ray_id, alpha_ws, rgb_ws, M);
    vox_scan_kernel<<<(NR * 64 + 255) / 256, 256, 0, stream>>>(
        alpha_ws, rgb_ws, ray_id, out, M, NR);
  }
}

// Round 18
// 292.873 us; speedup vs baseline: 7.1046x; 1.0412x over previous
//
#include <hip/hip_runtime.h>
#include <math.h>

#define GRIDN 160
#define N3 (160*160*160)
#define SX (160*160)
#define SY 160
#define DIST_C 0.005f
#define W0K 104   // sW0 row stride (ushorts), K=96 used
#define W1K 136   // sW1/sW2/sH row stride (ushorts), K=128 used
#define TPB 16    // groups (of 256 points) per MLP block -> grid = 256 = 1 block/CU

__device__ __forceinline__ float sigm_(float x) { return 1.f / (1.f + expf(-x)); }
__device__ __forceinline__ unsigned short f2bf(float x) {
  unsigned u = __builtin_bit_cast(unsigned, x);
  u = (u + 0x7fffu + ((u >> 16) & 1u)) >> 16;
  return (unsigned short)u;
}
__device__ __forceinline__ unsigned pk_bf16(float a, float b) {
  return (unsigned)f2bf(a) | ((unsigned)f2bf(b) << 16);
}
// single-instruction RNE pack: a -> low bf16, b -> high bf16
__device__ __forceinline__ unsigned cvtpk(float a, float b) {
  unsigned r;
  asm("v_cvt_pk_bf16_f32 %0, %1, %2" : "=v"(r) : "v"(a), "v"(b));
  return r;
}
__device__ __forceinline__ float bf_lo(unsigned u) { return __builtin_bit_cast(float, u << 16); }
__device__ __forceinline__ float bf_hi(unsigned u) { return __builtin_bit_cast(float, u & 0xffff0000u); }
__device__ __forceinline__ unsigned short f2h(float x) {
  _Float16 h = (_Float16)x; return __builtin_bit_cast(unsigned short, h);
}
__device__ __forceinline__ float h_lo(unsigned u) {
  return (float)__builtin_bit_cast(_Float16, (unsigned short)(u & 0xffffu));
}
__device__ __forceinline__ float h_hi(unsigned u) {
  return (float)__builtin_bit_cast(_Float16, (unsigned short)(u >> 16));
}

typedef __attribute__((ext_vector_type(8))) short bf16x8;
typedef __attribute__((ext_vector_type(4))) float f32x4;
typedef __attribute__((ext_vector_type(4))) unsigned u32x4;

// ==== fused repack -> 32B voxel record: [sdf,gx,gy,gz](f16) + k0 ch0..11 (bf16) ====
__global__ __launch_bounds__(256) void vox_repack_all(
    const float* __restrict__ V, const float* __restrict__ k0,
    unsigned short* __restrict__ VR) {
  int idx = blockIdx.x * 256 + threadIdx.x;
  if (idx >= N3) return;
  int z = idx % GRIDN; int t = idx / GRIDN; int y = t % GRIDN; int x = t / GRIDN;
  float v = V[idx];
  float xp = (x < 159) ? V[idx + SX] : v, xm = (x > 0) ? V[idx - SX] : v;
  float yp = (y < 159) ? V[idx + SY] : v, ym = (y > 0) ? V[idx - SY] : v;
  float zp = (z < 159) ? V[idx + 1]  : v, zm = (z > 0) ? V[idx - 1]  : v;
  float cx = (x > 0 && x < 159) ? (159.f / 4.f) : (159.f / 2.f);
  float cy = (y > 0 && y < 159) ? (159.f / 4.f) : (159.f / 2.f);
  float cz = (z > 0 && z < 159) ? (159.f / 4.f) : (159.f / 2.f);
  unsigned f0 = (unsigned)f2h(v) | ((unsigned)f2h((xp - xm) * cx) << 16);
  unsigned f1 = (unsigned)f2h((yp - ym) * cy) | ((unsigned)f2h((zp - zm) * cz) << 16);
  unsigned w[6];
#pragma unroll
  for (int j = 0; j < 6; j++) {
    float a = __builtin_nontemporal_load(k0 + (size_t)(2 * j) * N3 + idx);
    float b = __builtin_nontemporal_load(k0 + (size_t)(2 * j + 1) * N3 + idx);
    w[j] = pk_bf16(a, b);
  }
  u32x4* r = (u32x4*)(VR + (size_t)idx * 16);
  r[0] = (u32x4){f0, f1, w[0], w[1]};
  r[1] = (u32x4){w[2], w[3], w[4], w[5]};
}

// ============ repack weights -> transposed bf16 with padded strides ============
__global__ __launch_bounds__(256) void vox_repack_w(
    const float* __restrict__ w0, const float* __restrict__ w1, const float* __restrict__ w2,
    unsigned short* __restrict__ W0B, unsigned short* __restrict__ W1B,
    unsigned short* __restrict__ W2B) {
  int i = blockIdx.x * 256 + threadIdx.x;
  if (i < 128 * W0K) {                    // W0B[c][k] = w0[k][c], k<75
    int c = i / W0K, k = i - c * W0K;
    W0B[i] = (k < 75) ? f2bf(w0[k * 128 + c]) : (unsigned short)0;
  }
  if (i < 128 * W1K) {                    // W1B[c][k] = w1[k][c], k<128
    int c = i / W1K, k = i - c * W1K;
    W1B[i] = (k < 128) ? f2bf(w1[k * 128 + c]) : (unsigned short)0;
  }
  if (i < 16 * W1K) {                     // W2B[c][k] = w2[k][c], c<3, k<128
    int c = i / W1K, k = i - c * W1K;
    W2B[i] = (k < 128 && c < 3) ? f2bf(w2[k * 3 + c]) : (unsigned short)0;
  }
}

// ============ per-ray view-embedding table: 64B/ray, pre-packed per g-slice ========
__global__ __launch_bounds__(256) void vox_view_table(
    const float* __restrict__ rays_d, unsigned* __restrict__ VT, int NR) {
  int r = blockIdx.x * 256 + threadIdx.x;
  if (r >= NR) return;
  float dx = rays_d[3 * r + 0], dy = rays_d[3 * r + 1], dz = rays_d[3 * r + 2];
  float sx[4], cx[4], sy[4], cy[4], sz[4], cz[4];
#pragma unroll
  for (int l = 0; l < 4; l++) {
    float f = (float)(1 << l);
    __sincosf(dx * f, &sx[l], &cx[l]);
    __sincosf(dy * f, &sy[l], &cy[l]);
    __sincosf(dz * f, &sz[l], &cz[l]);
  }
  u32x4* v = (u32x4*)(VT + (size_t)r * 16);
  v[0] = (u32x4){pk_bf16(cy[0], cy[1]), pk_bf16(cy[2], cy[3]),
                 pk_bf16(cz[0], cz[1]), pk_bf16(cz[2], cz[3])};
  v[1] = (u32x4){pk_bf16(sx[0], sx[1]), pk_bf16(sx[2], sx[3]),
                 pk_bf16(sy[0], sy[1]), pk_bf16(sy[2], sy[3])};
  v[2] = (u32x4){pk_bf16(sz[0], sz[1]), pk_bf16(sz[2], sz[3]),
                 pk_bf16(cx[0], cx[1]), pk_bf16(cx[2], cx[3])};
  v[3] = (u32x4){__builtin_bit_cast(unsigned, dx), __builtin_bit_cast(unsigned, dy),
                 __builtin_bit_cast(unsigned, dz), 0u};
}

// ============ gather: taps + alpha + 32B tap-digest TD = [k0..k11, gn, 0] bf16 ======
__global__ __launch_bounds__(256) void vox_gather_kernel(
    const float* __restrict__ ray_pts, const float* __restrict__ rays_d,
    const unsigned short* __restrict__ VR,
    const float* __restrict__ s_val, const int* __restrict__ ray_id,
    float* __restrict__ alpha_out, unsigned short* __restrict__ TD, int M) {
  int i = blockIdx.x * 256 + threadIdx.x;
  if (i >= M) return;

  float px = ray_pts[3 * i + 0], py = ray_pts[3 * i + 1], pz = ray_pts[3 * i + 2];
  const float SC = 0.5f * 159.f;
  float ux = fminf(fmaxf((px + 1.f) * SC, 0.f), 159.f);
  float uy = fminf(fmaxf((py + 1.f) * SC, 0.f), 159.f);
  float uz = fminf(fmaxf((pz + 1.f) * SC, 0.f), 159.f);
  int ix = min((int)ux, 158), iy = min((int)uy, 158), iz = min((int)uz, 158);
  float fx = ux - (float)ix, fy = uy - (float)iy, fz = uz - (float)iz;
  float wx0 = 1.f - fx, wy0 = 1.f - fy, wz0 = 1.f - fz;
  float wxy[4];
  wxy[0] = wx0 * wy0; wxy[1] = wx0 * fy; wxy[2] = fx * wy0; wxy[3] = fx * fy;
  const int pairoff[4] = {0, SY, SX, SX + SY};
  int base = (ix * GRIDN + iy) * GRIDN + iz;

  u32x4 q[4][4];
#pragma unroll
  for (int t = 0; t < 4; t++) {
    const u32x4* p = (const u32x4*)(VR + (size_t)(base + pairoff[t]) * 16);
    q[t][0] = p[0]; q[t][1] = p[1]; q[t][2] = p[2]; q[t][3] = p[3];
  }

  float sdf = 0.f, gx = 0.f, gy = 0.f, gz = 0.f;
  float k[12];
#pragma unroll
  for (int j = 0; j < 12; j++) k[j] = 0.f;
#pragma unroll
  for (int t = 0; t < 4; t++) {
    float w0z = wxy[t] * wz0, w1z = wxy[t] * fz;
    sdf = fmaf(w0z, h_lo(q[t][0].x), sdf);
    gx  = fmaf(w0z, h_hi(q[t][0].x), gx);
    gy  = fmaf(w0z, h_lo(q[t][0].y), gy);
    gz  = fmaf(w0z, h_hi(q[t][0].y), gz);
    k[0]  = fmaf(w0z, bf_lo(q[t][0].z), k[0]);
    k[1]  = fmaf(w0z, bf_hi(q[t][0].z), k[1]);
    k[2]  = fmaf(w0z, bf_lo(q[t][0].w), k[2]);
    k[3]  = fmaf(w0z, bf_hi(q[t][0].w), k[3]);
    k[4]  = fmaf(w0z, bf_lo(q[t][1].x), k[4]);
    k[5]  = fmaf(w0z, bf_hi(q[t][1].x), k[5]);
    k[6]  = fmaf(w0z, bf_lo(q[t][1].y), k[6]);
    k[7]  = fmaf(w0z, bf_hi(q[t][1].y), k[7]);
    k[8]  = fmaf(w0z, bf_lo(q[t][1].z), k[8]);
    k[9]  = fmaf(w0z, bf_hi(q[t][1].z), k[9]);
    k[10] = fmaf(w0z, bf_lo(q[t][1].w), k[10]);
    k[11] = fmaf(w0z, bf_hi(q[t][1].w), k[11]);
    sdf = fmaf(w1z, h_lo(q[t][2].x), sdf);
    gx  = fmaf(w1z, h_hi(q[t][2].x), gx);
    gy  = fmaf(w1z, h_lo(q[t][2].y), gy);
    gz  = fmaf(w1z, h_hi(q[t][2].y), gz);
    k[0]  = fmaf(w1z, bf_lo(q[t][2].z), k[0]);
    k[1]  = fmaf(w1z, bf_hi(q[t][2].z), k[1]);
    k[2]  = fmaf(w1z, bf_lo(q[t][2].w), k[2]);
    k[3]  = fmaf(w1z, bf_hi(q[t][2].w), k[3]);
    k[4]  = fmaf(w1z, bf_lo(q[t][3].x), k[4]);
    k[5]  = fmaf(w1z, bf_hi(q[t][3].x), k[5]);
    k[6]  = fmaf(w1z, bf_lo(q[t][3].y), k[6]);
    k[7]  = fmaf(w1z, bf_hi(q[t][3].y), k[7]);
    k[8]  = fmaf(w1z, bf_lo(q[t][3].z), k[8]);
    k[9]  = fmaf(w1z, bf_hi(q[t][3].z), k[9]);
    k[10] = fmaf(w1z, bf_lo(q[t][3].w), k[10]);
    k[11] = fmaf(w1z, bf_hi(q[t][3].w), k[11]);
  }
  float ginv = 1.f / (sqrtf(gx * gx + gy * gy + gz * gz) + 1e-8f);
  float gnx = gx * ginv, gny = gy * ginv, gnz = gz * ginv;

  int rid = ray_id[i];
  float ddx = rays_d[3 * rid + 0], ddy = rays_d[3 * rid + 1], ddz = rays_d[3 * rid + 2];

  float true_cos = ddx * gnx + ddy * gny + ddz * gnz;
  float iter_cos = fminf(true_cos, 0.f);
  float inv_s = 1.f / s_val[0];
  float e = iter_cos * (DIST_C * 0.5f);
  float prev_cdf = sigm_((sdf - e) * inv_s);
  float next_cdf = sigm_((sdf + e) * inv_s);
  float alpha = (prev_cdf - next_cdf + 1e-5f) / (prev_cdf + 1e-5f);
  alpha_out[i] = fminf(fmaxf(alpha, 0.f), 1.f);

  u32x4* tb = (u32x4*)(TD + (size_t)i * 16);
  tb[0] = (u32x4){pk_bf16(k[0], k[1]), pk_bf16(k[2], k[3]),
                  pk_bf16(k[4], k[5]), pk_bf16(k[6], k[7])};
  tb[1] = (u32x4){pk_bf16(k[8], k[9]), pk_bf16(k[10], k[11]),
                  pk_bf16(gnx, gny), pk_bf16(gnz, 0.f)};
}

// ======== MFMA MLP: pos trig via 3 sincos + doubling; view trig from VT table ======
__global__ __launch_bounds__(1024, 1) void vox_mlp_kernel(
    const float* __restrict__ ray_pts, const unsigned* __restrict__ VT,
    const int* __restrict__ ray_id, const unsigned short* __restrict__ TD,
    const unsigned short* __restrict__ W0B, const unsigned short* __restrict__ W1B,
    const unsigned short* __restrict__ W2B,
    const float* __restrict__ b0, const float* __restrict__ b1,
    const float* __restrict__ b2, float* __restrict__ rgb, int ngroups) {
  __shared__ __align__(16) unsigned short sW0[128 * W0K];
  __shared__ __align__(16) unsigned short sW1[128 * W1K];
  __shared__ __align__(16) unsigned short sW2[16 * W1K];
  __shared__ __align__(16) unsigned short sH[16 * 16 * W1K];
  __shared__ __align__(16) float sB0[128], sB1[128], sB2[16];

  {
    const uint4* s0 = (const uint4*)W0B; uint4* d0 = (uint4*)sW0;
    for (int i = threadIdx.x; i < 128 * W0K / 8; i += 1024) d0[i] = s0[i];
    const uint4* s1 = (const uint4*)W1B; uint4* d1 = (uint4*)sW1;
    for (int i = threadIdx.x; i < 128 * W1K / 8; i += 1024) d1[i] = s1[i];
    const uint4* s2 = (const uint4*)W2B; uint4* d2 = (uint4*)sW2;
    for (int i = threadIdx.x; i < 16 * W1K / 8; i += 1024) d2[i] = s2[i];
    if (threadIdx.x < 128) { sB0[threadIdx.x] = b0[threadIdx.x]; sB1[threadIdx.x] = b1[threadIdx.x]; }
    if (threadIdx.x < 16) sB2[threadIdx.x] = (threadIdx.x < 3) ? b2[threadIdx.x] : 0.f;
  }
  __syncthreads();

  const int wid = (int)(threadIdx.x >> 6), lane = (int)(threadIdx.x & 63);
  const int l15 = lane & 15, g = lane >> 4;
  unsigned short* myH = sH + wid * (16 * W1K);

#pragma unroll 1
  for (int t = 0; t < TPB; ++t) {
    int grp = blockIdx.x * TPB + t;
    if (grp >= ngroups) break;
    const int pt0 = grp * 256 + wid * 16;
    const int pt = pt0 + l15;

    float px = ray_pts[3 * pt + 0], py = ray_pts[3 * pt + 1], pz = ray_pts[3 * pt + 2];
    int rid = ray_id[pt];
    float x01 = (px + 1.f) * 0.5f, y01 = (py + 1.f) * 0.5f, z01 = (pz + 1.f) * 0.5f;
    // positional trig: 3 sincos + angle doubling (s2=2sc, c2=1-2s^2)
    float snx[5], csx[5], sny[5], csy[5], snz[5], csz[5];
    __sincosf(x01, &snx[0], &csx[0]);
    __sincosf(y01, &sny[0], &csy[0]);
    __sincosf(z01, &snz[0], &csz[0]);
#pragma unroll
    for (int l = 1; l < 5; l++) {
      snx[l] = 2.f * snx[l-1] * csx[l-1]; csx[l] = 1.f - 2.f * snx[l-1] * snx[l-1];
      sny[l] = 2.f * sny[l-1] * csy[l-1]; csy[l] = 1.f - 2.f * sny[l-1] * sny[l-1];
      snz[l] = 2.f * snz[l-1] * csz[l-1]; csz[l] = 1.f - 2.f * snz[l-1] * snz[l-1];
    }
    const u32x4* vt = (const u32x4*)(VT + (size_t)rid * 16);
    const u32x4* tdp = (const u32x4*)(TD + (size_t)pt * 16);

    // ---- build this lane's three B-slices ----
    bf16x8 cb0, cb1, cb2;
    const u32x4 zz = (u32x4){0u, 0u, 0u, 0u};
    switch (g) {
      case 0: {
        u32x4 td0 = tdp[0];
        cb0 = __builtin_bit_cast(bf16x8, td0);
        cb1 = __builtin_bit_cast(bf16x8, (u32x4){
            cvtpk(csx[2], csx[3]), cvtpk(csx[4], csy[0]),
            cvtpk(csy[1], csy[2]), cvtpk(csy[3], csy[4])});
        cb2 = __builtin_bit_cast(bf16x8, vt[0]);
        break;
      }
      case 1: {
        u32x4 td1 = tdp[1];
        u32x4 v3 = vt[3];
        float ddx = __builtin_bit_cast(float, v3.x);
        float ddy = __builtin_bit_cast(float, v3.y);
        float ddz = __builtin_bit_cast(float, v3.z);
        cb0 = __builtin_bit_cast(bf16x8, (u32x4){
            td1.x, td1.y, cvtpk(x01, y01), cvtpk(z01, snx[0])});
        cb1 = __builtin_bit_cast(bf16x8, (u32x4){
            cvtpk(csz[0], csz[1]), cvtpk(csz[2], csz[3]),
            cvtpk(csz[4], ddx), cvtpk(ddy, ddz)});
        cb2 = __builtin_bit_cast(bf16x8, (u32x4){td1.z, td1.w, 0u, 0u});
        break;
      }
      case 2:
        cb0 = __builtin_bit_cast(bf16x8, (u32x4){
            cvtpk(snx[1], snx[2]), cvtpk(snx[3], snx[4]),
            cvtpk(sny[0], sny[1]), cvtpk(sny[2], sny[3])});
        cb1 = __builtin_bit_cast(bf16x8, vt[1]);
        cb2 = __builtin_bit_cast(bf16x8, zz);
        break;
      default:
        cb0 = __builtin_bit_cast(bf16x8, (u32x4){
            cvtpk(sny[4], snz[0]), cvtpk(snz[1], snz[2]),
            cvtpk(snz[3], snz[4]), cvtpk(csx[0], csx[1])});
        cb1 = __builtin_bit_cast(bf16x8, vt[2]);
        cb2 = __builtin_bit_cast(bf16x8, zz);
        break;
    }

    // ---- GEMM1: D1[hid][pt] = W0^T x feat^T, K=96 ----
    f32x4 acc1[8];
#pragma unroll
    for (int m = 0; m < 8; m++) acc1[m] = (f32x4){0.f, 0.f, 0.f, 0.f};
#pragma unroll
    for (int m = 0; m < 8; m++) {
      bf16x8 a0 = *(const bf16x8*)(sW0 + (m * 16 + l15) * W0K + g * 8);
      acc1[m] = __builtin_amdgcn_mfma_f32_16x16x32_bf16(a0, cb0, acc1[m], 0, 0, 0);
      bf16x8 a1 = *(const bf16x8*)(sW0 + (m * 16 + l15) * W0K + 32 + g * 8);
      acc1[m] = __builtin_amdgcn_mfma_f32_16x16x32_bf16(a1, cb1, acc1[m], 0, 0, 0);
      bf16x8 a2 = *(const bf16x8*)(sW0 + (m * 16 + l15) * W0K + 64 + g * 8);
      acc1[m] = __builtin_amdgcn_mfma_f32_16x16x32_bf16(a2, cb2, acc1[m], 0, 0, 0);
    }
#pragma unroll
    for (int m = 0; m < 8; m++) {
      f32x4 bias = *(const f32x4*)(sB0 + m * 16 + g * 4);
      float h0 = fmaxf(acc1[m][0] + bias[0], 0.f);
      float h1 = fmaxf(acc1[m][1] + bias[1], 0.f);
      float h2 = fmaxf(acc1[m][2] + bias[2], 0.f);
      float h3 = fmaxf(acc1[m][3] + bias[3], 0.f);
      *(uint2*)(myH + l15 * W1K + m * 16 + g * 4) = make_uint2(cvtpk(h0, h1), cvtpk(h2, h3));
    }

    // ---- GEMM2: D2[hid2][pt] = W1^T x h1^T, K=128 ----
    f32x4 acc2[8];
#pragma unroll
    for (int m = 0; m < 8; m++) acc2[m] = (f32x4){0.f, 0.f, 0.f, 0.f};
    const unsigned short* hb = myH + l15 * W1K + g * 8;
#pragma unroll
    for (int ks = 0; ks < 4; ks++) {
      bf16x8 bfrag = *(const bf16x8*)(hb + ks * 32);
#pragma unroll
      for (int m = 0; m < 8; m++) {
        bf16x8 afrag = *(const bf16x8*)(sW1 + (m * 16 + l15) * W1K + ks * 32 + g * 8);
        acc2[m] = __builtin_amdgcn_mfma_f32_16x16x32_bf16(afrag, bfrag, acc2[m], 0, 0, 0);
      }
    }
#pragma unroll
    for (int m = 0; m < 8; m++) {
      f32x4 bias = *(const f32x4*)(sB1 + m * 16 + g * 4);
      float h0 = fmaxf(acc2[m][0] + bias[0], 0.f);
      float h1 = fmaxf(acc2[m][1] + bias[1], 0.f);
      float h2 = fmaxf(acc2[m][2] + bias[2], 0.f);
      float h3 = fmaxf(acc2[m][3] + bias[3], 0.f);
      *(uint2*)(myH + l15 * W1K + m * 16 + g * 4) = make_uint2(cvtpk(h0, h1), cvtpk(h2, h3));
    }

    // ---- GEMM3: D3[ch][pt] = W2^T x h2^T, K=128, 1 tile ----
    f32x4 acc3 = (f32x4){0.f, 0.f, 0.f, 0.f};
#pragma unroll
    for (int ks = 0; ks < 4; ks++) {
      bf16x8 bfrag = *(const bf16x8*)(hb + ks * 32);
      bf16x8 afrag = *(const bf16x8*)(sW2 + l15 * W1K + ks * 32 + g * 8);
      acc3 = __builtin_amdgcn_mfma_f32_16x16x32_bf16(afrag, bfrag, acc3, 0, 0, 0);
    }
    if (g == 0) {   // rows 0..3 = channels; only 0..2 valid
      rgb[pt * 3 + 0] = sigm_(acc3[0] + sB2[0]);
      rgb[pt * 3 + 1] = sigm_(acc3[1] + sB2[1]);
      rgb[pt * 3 + 2] = sigm_(acc3[2] + sB2[2]);
    }
  }
}

// ============ per-ray scan + composite (1 wave / ray) ============
__global__ __launch_bounds__(256) void vox_scan_kernel(
    const float* __restrict__ alpha, const float* __restrict__ rgb,
    const int* __restrict__ ray_id, float* __restrict__ out, int M, int NR) {
  int wave = (int)((blockIdx.x * blockDim.x + threadIdx.x) >> 6);
  int lane = threadIdx.x & 63;
  if (wave >= NR) return;
  int r = wave;
  int lo = 0, hi = M;
  while (lo < hi) { int mid = (lo + hi) >> 1; if (ray_id[mid] < r) lo = mid + 1; else hi = mid; }
  int start = lo; hi = M;
  while (lo < hi) { int mid = (lo + hi) >> 1; if (ray_id[mid] < r + 1) lo = mid + 1; else hi = mid; }
  int end = lo;

  float carry = 0.f, cr = 0.f, cg = 0.f, cb = 0.f;
  for (int s = start; s < end; s += 64) {
    int idx = s + lane;
    bool valid = idx < end;
    float a = valid ? alpha[idx] : 0.f;
    float l = valid ? log1pf(-fminf(a, 1.f - 1e-7f)) : 0.f;
    float sc = l;
#pragma unroll
    for (int off = 1; off < 64; off <<= 1) {
      float t = __shfl_up(sc, (unsigned)off);
      if (lane >= off) sc += t;
    }
    if (valid) {
      float T = expf(carry + (sc - l));
      float w = a * T;
      cr = fmaf(w, rgb[3 * idx + 0], cr);
      cg = fmaf(w, rgb[3 * idx + 1], cg);
      cb = fmaf(w, rgb[3 * idx + 2], cb);
    }
    carry += __shfl(sc, 63);
  }
#pragma unroll
  for (int off = 32; off > 0; off >>= 1) {
    cr += __shfl_down(cr, (unsigned)off);
    cg += __shfl_down(cg, (unsigned)off);
    cb += __shfl_down(cb, (unsigned)off);
  }
  if (lane == 0) {
    float ail = expf(carry);
    out[3 * r + 0] = cr + ail;
    out[3 * r + 1] = cg + ail;
    out[3 * r + 2] = cb + ail;
  }
}

// ============ fallback (round-1 monolithic path, used if ws too small) ============
__global__ __launch_bounds__(256) void vox_transpose_w0(
    const float* __restrict__ w0, float* __restrict__ w0t) {
  for (int idx = threadIdx.x; idx < 128 * 80; idx += 256) {
    int j = idx / 80, k = idx - j * 80;
    w0t[idx] = (k < 75) ? w0[k * 128 + j] : 0.f;
  }
}

__global__ __launch_bounds__(256) void vox_point_kernel(
    const float* __restrict__ ray_pts, const float* __restrict__ rays_d,
    const float* __restrict__ sdf_vol, const float* __restrict__ k0_vol,
    const float* __restrict__ w0t, const float* __restrict__ b0,
    const float* __restrict__ w1, const float* __restrict__ b1,
    const float* __restrict__ w2, const float* __restrict__ b2,
    const float* __restrict__ s_val, const int* __restrict__ ray_id,
    float* __restrict__ alpha_out, float* __restrict__ rgb_out, int M) {
  int i = blockIdx.x * 256 + threadIdx.x;
  if (i >= M) return;
  float px = ray_pts[3 * i + 0], py = ray_pts[3 * i + 1], pz = ray_pts[3 * i + 2];
  const float SC = 0.5f * 159.f;
  float ux = fminf(fmaxf((px + 1.f) * SC, 0.f), 159.f);
  float uy = fminf(fmaxf((py + 1.f) * SC, 0.f), 159.f);
  float uz = fminf(fmaxf((pz + 1.f) * SC, 0.f), 159.f);
  int ix = min((int)ux, 158), iy = min((int)uy, 158), iz = min((int)uz, 158);
  float fx = ux - (float)ix, fy = uy - (float)iy, fz = uz - (float)iz;
  float wx0 = 1.f - fx, wy0 = 1.f - fy, wz0 = 1.f - fz;
  float w000 = wx0 * wy0 * wz0, w001 = wx0 * wy0 * fz;
  float w010 = wx0 * fy * wz0,  w011 = wx0 * fy * fz;
  float w100 = fx * wy0 * wz0,  w101 = fx * wy0 * fz;
  float w110 = fx * fy * wz0,   w111 = fx * fy * fz;
  int base = (ix * GRIDN + iy) * GRIDN + iz;
  const float* V = sdf_vol;
  float c000 = V[base],          c001 = V[base + 1];
  float c010 = V[base + SY],     c011 = V[base + SY + 1];
  float c100 = V[base + SX],     c101 = V[base + SX + 1];
  float c110 = V[base + SX + SY], c111 = V[base + SX + SY + 1];
  float xm00 = V[base - SX],          xm01 = V[base - SX + 1];
  float xm10 = V[base - SX + SY],     xm11 = V[base - SX + SY + 1];
  float xp00 = V[base + 2 * SX],      xp01 = V[base + 2 * SX + 1];
  float xp10 = V[base + 2 * SX + SY], xp11 = V[base + 2 * SX + SY + 1];
  float ym00 = V[base - SY],          ym01 = V[base - SY + 1];
  float ym10 = V[base + SX - SY],     ym11 = V[base + SX - SY + 1];
  float yp00 = V[base + 2 * SY],      yp01 = V[base + 2 * SY + 1];
  float yp10 = V[base + SX + 2 * SY], yp11 = V[base + SX + 2 * SY + 1];
  float zm00 = V[base - 1],           zm01 = V[base + SY - 1];
  float zm10 = V[base + SX - 1],      zm11 = V[base + SX + SY - 1];
  float zp00 = V[base + 2],           zp01 = V[base + SY + 2];
  float zp10 = V[base + SX + 2],      zp11 = V[base + SX + SY + 2];
  float sdf = w000 * c000 + w001 * c001 + w010 * c010 + w011 * c011 +
              w100 * c100 + w101 * c101 + w110 * c110 + w111 * c111;
  const float INV2H = 159.f / 4.f;
  float gx = (w000 * (c100 - xm00) + w001 * (c101 - xm01) +
              w010 * (c110 - xm10) + w011 * (c111 - xm11) +
              w100 * (xp00 - c000) + w101 * (xp01 - c001) +
              w110 * (xp10 - c010) + w111 * (xp11 - c011)) * INV2H;
  float gy = (w000 * (c010 - ym00) + w001 * (c011 - ym01) +
              w100 * (c110 - ym10) + w101 * (c111 - ym11) +
              w010 * (yp00 - c000) + w011 * (yp01 - c001) +
              w110 * (yp10 - c100) + w111 * (yp11 - c101)) * INV2H;
  float gz = (w000 * (c001 - zm00) + w010 * (c011 - zm01) +
              w100 * (c101 - zm10) + w110 * (c111 - zm11) +
              w001 * (zp00 - c000) + w011 * (zp01 - c010) +
              w101 * (zp10 - c100) + w111 * (zp11 - c110)) * INV2H;
  float ginv = 1.f / (sqrtf(gx * gx + gy * gy + gz * gz) + 1e-8f);
  float gnx = gx * ginv, gny = gy * ginv, gnz = gz * ginv;
  int rid = ray_id[i];
  float ddx = rays_d[3 * rid + 0], ddy = rays_d[3 * rid + 1], ddz = rays_d[3 * rid + 2];
  float true_cos = ddx * gnx + ddy * gny + ddz * gnz;
  float iter_cos = fminf(true_cos, 0.f);
  float inv_s = 1.f / s_val[0];
  float e = iter_cos * (DIST_C * 0.5f);
  float prev_cdf = sigm_((sdf - e) * inv_s);
  float next_cdf = sigm_((sdf + e) * inv_s);
  float alpha = fminf(fmaxf((prev_cdf - next_cdf + 1e-5f) / (prev_cdf + 1e-5f), 0.f), 1.f);
  alpha_out[i] = alpha;
  float feat[75];
  {
    const int offs[8] = {0, 1, SY, SY + 1, SX, SX + 1, SX + SY, SX + SY + 1};
    const float wts[8] = {w000, w001, w010, w011, w100, w101, w110, w111};
#pragma unroll
    for (int c = 0; c < 12; c++) {
      const float* kc = k0_vol + c * N3 + base;
      float acc = 0.f;
#pragma unroll
      for (int t = 0; t < 8; t++) acc = fmaf(wts[t], kc[offs[t]], acc);
      feat[c] = acc;
    }
  }
  float x01 = (px + 1.f) * 0.5f, y01 = (py + 1.f) * 0.5f, z01 = (pz + 1.f) * 0.5f;
  feat[12] = x01; feat[13] = y01; feat[14] = z01;
#pragma unroll
  for (int l = 0; l < 5; l++) {
    float f = (float)(1 << l), s, c;
    sincosf(x01 * f, &s, &c); feat[15 + l] = s; feat[30 + l] = c;
    sincosf(y01 * f, &s, &c); feat[20 + l] = s; feat[35 + l] = c;
    sincosf(z01 * f, &s, &c); feat[25 + l] = s; feat[40 + l] = c;
  }
  feat[45] = ddx; feat[46] = ddy; feat[47] = ddz;
#pragma unroll
  for (int l = 0; l < 4; l++) {
    float f = (float)(1 << l), s, c;
    sincosf(ddx * f, &s, &c); feat[48 + l] = s; feat[60 + l] = c;
    sincosf(ddy * f, &s, &c); feat[52 + l] = s; feat[64 + l] = c;
    sincosf(ddz * f, &s, &c); feat[56 + l] = s; feat[68 + l] = c;
  }
  feat[72] = gnx; feat[73] = gny; feat[74] = gnz;
  float rr = 0.f, rg = 0.f, rb = 0.f;
#pragma unroll 1
  for (int half = 0; half < 2; ++half) {
    float acc[64];
#pragma unroll
    for (int t = 0; t < 64; t++) acc[t] = b1[half * 64 + t];
#pragma unroll 1
    for (int j = 0; j < 128; ++j) {
      float h = b0[j];
      const float* wr = w0t + j * 80;
#pragma unroll
      for (int k = 0; k < 75; k++) h = fmaf(feat[k], wr[k], h);
      h = fmaxf(h, 0.f);
      const float* w1r = w1 + j * 128 + half * 64;
#pragma unroll
      for (int t = 0; t < 64; t++) acc[t] = fmaf(h, w1r[t], acc[t]);
    }
#pragma unroll
    for (int t = 0; t < 64; t++) {
      float h2 = fmaxf(acc[t], 0.f);
      int j2 = half * 64 + t;
      rr = fmaf(h2, w2[3 * j2 + 0], rr);
      rg = fmaf(h2, w2[3 * j2 + 1], rg);
      rb = fmaf(h2, w2[3 * j2 + 2], rb);
    }
  }
  rgb_out[3 * i + 0] = sigm_(rr + b2[0]);
  rgb_out[3 * i + 1] = sigm_(rg + b2[1]);
  rgb_out[3 * i + 2] = sigm_(rb + b2[2]);
}

extern "C" void kernel_launch(void* const* d_in, const int* in_sizes, int n_in,
                              void* d_out, int out_size, void* d_ws, size_t ws_size,
                              hipStream_t stream) {
  const float* ray_pts = (const float*)d_in[0];
  const float* rays_d  = (const float*)d_in[1];
  const float* sdf_vol = (const float*)d_in[2];
  const float* k0_vol  = (const float*)d_in[3];
  const float* w0      = (const float*)d_in[4];
  const float* b0      = (const float*)d_in[5];
  const float* w1      = (const float*)d_in[6];
  const float* b1      = (const float*)d_in[7];
  const float* w2      = (const float*)d_in[8];
  const float* b2      = (const float*)d_in[9];
  const float* s_val   = (const float*)d_in[10];
  const int*   ray_id  = (const int*)d_in[11];
  float* out = (float*)d_out;

  int M  = in_sizes[0] / 3;   // 1048576
  int NR = in_sizes[1] / 3;   // 8192

  char* ws = (char*)d_ws;
  size_t offVR   = 0;                                  // N3*32 combined records
  size_t offTD   = offVR + (size_t)N3 * 32;            // M*32 tap digests
  size_t offA    = offTD + (size_t)M * 32;
  size_t offRgb  = offA + (size_t)M * 4;
  size_t offW0   = offRgb + (size_t)M * 12;
  size_t offW1   = offW0 + (size_t)128 * W0K * 2;
  size_t offW2   = offW1 + (size_t)128 * W1K * 2;
  size_t offVT   = offW2 + (size_t)16 * W1K * 2;
  size_t need    = offVT + (size_t)NR * 64;

  if (ws_size >= need && (M % 256) == 0) {
    unsigned short* VR = (unsigned short*)(ws + offVR);
    unsigned short* TD = (unsigned short*)(ws + offTD);
    float* alpha_ws = (float*)(ws + offA);
    float* rgb_ws = (float*)(ws + offRgb);
    unsigned short* W0B = (unsigned short*)(ws + offW0);
    unsigned short* W1B = (unsigned short*)(ws + offW1);
    unsigned short* W2B = (unsigned short*)(ws + offW2);
    unsigned* VT = (unsigned*)(ws + offVT);

    int ngroups = M / 256;
    vox_repack_all<<<(N3 + 255) / 256, 256, 0, stream>>>(sdf_vol, k0_vol, VR);
    vox_repack_w<<<(128 * W1K + 255) / 256, 256, 0, stream>>>(w0, w1, w2, W0B, W1B, W2B);
    vox_view_table<<<(NR + 255) / 256, 256, 0, stream>>>(rays_d, VT, NR);
    vox_gather_kernel<<<(M + 255) / 256, 256, 0, stream>>>(
        ray_pts, rays_d, VR, s_val, ray_id, alpha_ws, TD, M);
    vox_mlp_kernel<<<(ngroups + TPB - 1) / TPB, 1024, 0, stream>>>(
        ray_pts, VT, ray_id, TD, W0B, W1B, W2B, b0, b1, b2, rgb_ws, ngroups);
    vox_scan_kernel<<<(NR * 64 + 255) / 256, 256, 0, stream>>>(
        alpha_ws, rgb_ws, ray_id, out, M, NR);
  } else {
    float* alpha_ws = (float*)ws;
    float* rgb_ws   = (float*)(ws + (size_t)M * 4);
    float* w0t_ws   = (float*)(ws + (size_t)M * 16);
    vox_transpose_w0<<<1, 256, 0, stream>>>(w0, w0t_ws);
    vox_point_kernel<<<(M + 255) / 256, 256, 0, stream>>>(
        ray_pts, rays_d, sdf_vol, k0_vol, w0t_ws, b0, w1, b1, w2, b2,
        s_val, ray_id, alpha_ws, rgb_ws, M);
    vox_scan_kernel<<<(NR * 64 + 255) / 256, 256, 0, stream>>>(
        alpha_ws, rgb_ws, ray_id, out, M, NR);
  }
}

// Round 19
// 292.680 us; speedup vs baseline: 7.1093x; 1.0007x over previous
//
#include <hip/hip_runtime.h>
#include <math.h>

#define GRIDN 160
#define N3 (160*160*160)
#define SX (160*160)
#define SY 160
#define DIST_C 0.005f
#define TPB 16    // groups (of 256 points) per MLP block -> grid = 256 = 1 block/CU

__device__ __forceinline__ float sigm_(float x) { return 1.f / (1.f + expf(-x)); }
__device__ __forceinline__ unsigned short f2bf(float x) {
  unsigned u = __builtin_bit_cast(unsigned, x);
  u = (u + 0x7fffu + ((u >> 16) & 1u)) >> 16;
  return (unsigned short)u;
}
__device__ __forceinline__ unsigned pk_bf16(float a, float b) {
  return (unsigned)f2bf(a) | ((unsigned)f2bf(b) << 16);
}
// single-instruction RNE pack: a -> low bf16, b -> high bf16
__device__ __forceinline__ unsigned cvtpk(float a, float b) {
  unsigned r;
  asm("v_cvt_pk_bf16_f32 %0, %1, %2" : "=v"(r) : "v"(a), "v"(b));
  return r;
}
__device__ __forceinline__ float bf_lo(unsigned u) { return __builtin_bit_cast(float, u << 16); }
__device__ __forceinline__ float bf_hi(unsigned u) { return __builtin_bit_cast(float, u & 0xffff0000u); }
__device__ __forceinline__ unsigned short f2h(float x) {
  _Float16 h = (_Float16)x; return __builtin_bit_cast(unsigned short, h);
}
__device__ __forceinline__ float h_lo(unsigned u) {
  return (float)__builtin_bit_cast(_Float16, (unsigned short)(u & 0xffffu));
}
__device__ __forceinline__ float h_hi(unsigned u) {
  return (float)__builtin_bit_cast(_Float16, (unsigned short)(u >> 16));
}

typedef __attribute__((ext_vector_type(8))) short bf16x8;
typedef __attribute__((ext_vector_type(4))) float f32x4;
typedef __attribute__((ext_vector_type(4))) unsigned u32x4;

// ==== fused repack -> 32B voxel record: [sdf,gx,gy,gz](f16) + k0 ch0..11 (bf16) ====
__global__ __launch_bounds__(256) void vox_repack_all(
    const float* __restrict__ V, const float* __restrict__ k0,
    unsigned short* __restrict__ VR) {
  int idx = blockIdx.x * 256 + threadIdx.x;
  if (idx >= N3) return;
  int z = idx % GRIDN; int t = idx / GRIDN; int y = t % GRIDN; int x = t / GRIDN;
  float v = V[idx];
  float xp = (x < 159) ? V[idx + SX] : v, xm = (x > 0) ? V[idx - SX] : v;
  float yp = (y < 159) ? V[idx + SY] : v, ym = (y > 0) ? V[idx - SY] : v;
  float zp = (z < 159) ? V[idx + 1]  : v, zm = (z > 0) ? V[idx - 1]  : v;
  float cx = (x > 0 && x < 159) ? (159.f / 4.f) : (159.f / 2.f);
  float cy = (y > 0 && y < 159) ? (159.f / 4.f) : (159.f / 2.f);
  float cz = (z > 0 && z < 159) ? (159.f / 4.f) : (159.f / 2.f);
  unsigned f0 = (unsigned)f2h(v) | ((unsigned)f2h((xp - xm) * cx) << 16);
  unsigned f1 = (unsigned)f2h((yp - ym) * cy) | ((unsigned)f2h((zp - zm) * cz) << 16);
  unsigned w[6];
#pragma unroll
  for (int j = 0; j < 6; j++) {
    float a = __builtin_nontemporal_load(k0 + (size_t)(2 * j) * N3 + idx);
    float b = __builtin_nontemporal_load(k0 + (size_t)(2 * j + 1) * N3 + idx);
    w[j] = pk_bf16(a, b);
  }
  u32x4* r = (u32x4*)(VR + (size_t)idx * 16);
  r[0] = (u32x4){f0, f1, w[0], w[1]};
  r[1] = (u32x4){w[2], w[3], w[4], w[5]};
}

// ============ repack weights -> transposed bf16, stride 128 (for XOR-swz LDS) ======
__global__ __launch_bounds__(256) void vox_repack_w(
    const float* __restrict__ w0, const float* __restrict__ w1, const float* __restrict__ w2,
    unsigned short* __restrict__ W0B, unsigned short* __restrict__ W1B,
    unsigned short* __restrict__ W2B) {
  int i = blockIdx.x * 256 + threadIdx.x;
  if (i < 128 * 128) {                    // W0B[c][k] = w0[k][c], k<75
    int c = i >> 7, k = i & 127;
    W0B[i] = (k < 75) ? f2bf(w0[k * 128 + c]) : (unsigned short)0;
  }
  if (i < 128 * 128) {                    // W1B[c][k] = w1[k][c], k<128
    int c = i >> 7, k = i & 127;
    W1B[i] = f2bf(w1[k * 128 + c]);
  }
  if (i < 16 * 128) {                     // W2B[c][k] = w2[k][c], c<3, k<128
    int c = i >> 7, k = i & 127;
    W2B[i] = (c < 3) ? f2bf(w2[k * 3 + c]) : (unsigned short)0;
  }
}

// ============ per-ray view-embedding table: 64B/ray, pre-packed per g-slice ========
__global__ __launch_bounds__(256) void vox_view_table(
    const float* __restrict__ rays_d, unsigned* __restrict__ VT, int NR) {
  int r = blockIdx.x * 256 + threadIdx.x;
  if (r >= NR) return;
  float dx = rays_d[3 * r + 0], dy = rays_d[3 * r + 1], dz = rays_d[3 * r + 2];
  float sx[4], cx[4], sy[4], cy[4], sz[4], cz[4];
#pragma unroll
  for (int l = 0; l < 4; l++) {
    float f = (float)(1 << l);
    __sincosf(dx * f, &sx[l], &cx[l]);
    __sincosf(dy * f, &sy[l], &cy[l]);
    __sincosf(dz * f, &sz[l], &cz[l]);
  }
  u32x4* v = (u32x4*)(VT + (size_t)r * 16);
  v[0] = (u32x4){pk_bf16(cy[0], cy[1]), pk_bf16(cy[2], cy[3]),
                 pk_bf16(cz[0], cz[1]), pk_bf16(cz[2], cz[3])};
  v[1] = (u32x4){pk_bf16(sx[0], sx[1]), pk_bf16(sx[2], sx[3]),
                 pk_bf16(sy[0], sy[1]), pk_bf16(sy[2], sy[3])};
  v[2] = (u32x4){pk_bf16(sz[0], sz[1]), pk_bf16(sz[2], sz[3]),
                 pk_bf16(cx[0], cx[1]), pk_bf16(cx[2], cx[3])};
  v[3] = (u32x4){__builtin_bit_cast(unsigned, dx), __builtin_bit_cast(unsigned, dy),
                 __builtin_bit_cast(unsigned, dz), 0u};
}

// ============ gather: taps + alpha + 32B tap-digest TD = [k0..k11, gn, 0] bf16 ======
__global__ __launch_bounds__(256) void vox_gather_kernel(
    const float* __restrict__ ray_pts, const float* __restrict__ rays_d,
    const unsigned short* __restrict__ VR,
    const float* __restrict__ s_val, const int* __restrict__ ray_id,
    float* __restrict__ alpha_out, unsigned short* __restrict__ TD, int M) {
  int i = blockIdx.x * 256 + threadIdx.x;
  if (i >= M) return;

  float px = ray_pts[3 * i + 0], py = ray_pts[3 * i + 1], pz = ray_pts[3 * i + 2];
  const float SC = 0.5f * 159.f;
  float ux = fminf(fmaxf((px + 1.f) * SC, 0.f), 159.f);
  float uy = fminf(fmaxf((py + 1.f) * SC, 0.f), 159.f);
  float uz = fminf(fmaxf((pz + 1.f) * SC, 0.f), 159.f);
  int ix = min((int)ux, 158), iy = min((int)uy, 158), iz = min((int)uz, 158);
  float fx = ux - (float)ix, fy = uy - (float)iy, fz = uz - (float)iz;
  float wx0 = 1.f - fx, wy0 = 1.f - fy, wz0 = 1.f - fz;
  float wxy[4];
  wxy[0] = wx0 * wy0; wxy[1] = wx0 * fy; wxy[2] = fx * wy0; wxy[3] = fx * fy;
  const int pairoff[4] = {0, SY, SX, SX + SY};
  int base = (ix * GRIDN + iy) * GRIDN + iz;

  u32x4 q[4][4];
#pragma unroll
  for (int t = 0; t < 4; t++) {
    const u32x4* p = (const u32x4*)(VR + (size_t)(base + pairoff[t]) * 16);
    q[t][0] = p[0]; q[t][1] = p[1]; q[t][2] = p[2]; q[t][3] = p[3];
  }

  float sdf = 0.f, gx = 0.f, gy = 0.f, gz = 0.f;
  float k[12];
#pragma unroll
  for (int j = 0; j < 12; j++) k[j] = 0.f;
#pragma unroll
  for (int t = 0; t < 4; t++) {
    float w0z = wxy[t] * wz0, w1z = wxy[t] * fz;
    sdf = fmaf(w0z, h_lo(q[t][0].x), sdf);
    gx  = fmaf(w0z, h_hi(q[t][0].x), gx);
    gy  = fmaf(w0z, h_lo(q[t][0].y), gy);
    gz  = fmaf(w0z, h_hi(q[t][0].y), gz);
    k[0]  = fmaf(w0z, bf_lo(q[t][0].z), k[0]);
    k[1]  = fmaf(w0z, bf_hi(q[t][0].z), k[1]);
    k[2]  = fmaf(w0z, bf_lo(q[t][0].w), k[2]);
    k[3]  = fmaf(w0z, bf_hi(q[t][0].w), k[3]);
    k[4]  = fmaf(w0z, bf_lo(q[t][1].x), k[4]);
    k[5]  = fmaf(w0z, bf_hi(q[t][1].x), k[5]);
    k[6]  = fmaf(w0z, bf_lo(q[t][1].y), k[6]);
    k[7]  = fmaf(w0z, bf_hi(q[t][1].y), k[7]);
    k[8]  = fmaf(w0z, bf_lo(q[t][1].z), k[8]);
    k[9]  = fmaf(w0z, bf_hi(q[t][1].z), k[9]);
    k[10] = fmaf(w0z, bf_lo(q[t][1].w), k[10]);
    k[11] = fmaf(w0z, bf_hi(q[t][1].w), k[11]);
    sdf = fmaf(w1z, h_lo(q[t][2].x), sdf);
    gx  = fmaf(w1z, h_hi(q[t][2].x), gx);
    gy  = fmaf(w1z, h_lo(q[t][2].y), gy);
    gz  = fmaf(w1z, h_hi(q[t][2].y), gz);
    k[0]  = fmaf(w1z, bf_lo(q[t][2].z), k[0]);
    k[1]  = fmaf(w1z, bf_hi(q[t][2].z), k[1]);
    k[2]  = fmaf(w1z, bf_lo(q[t][2].w), k[2]);
    k[3]  = fmaf(w1z, bf_hi(q[t][2].w), k[3]);
    k[4]  = fmaf(w1z, bf_lo(q[t][3].x), k[4]);
    k[5]  = fmaf(w1z, bf_hi(q[t][3].x), k[5]);
    k[6]  = fmaf(w1z, bf_lo(q[t][3].y), k[6]);
    k[7]  = fmaf(w1z, bf_hi(q[t][3].y), k[7]);
    k[8]  = fmaf(w1z, bf_lo(q[t][3].z), k[8]);
    k[9]  = fmaf(w1z, bf_hi(q[t][3].z), k[9]);
    k[10] = fmaf(w1z, bf_lo(q[t][3].w), k[10]);
    k[11] = fmaf(w1z, bf_hi(q[t][3].w), k[11]);
  }
  float ginv = 1.f / (sqrtf(gx * gx + gy * gy + gz * gz) + 1e-8f);
  float gnx = gx * ginv, gny = gy * ginv, gnz = gz * ginv;

  int rid = ray_id[i];
  float ddx = rays_d[3 * rid + 0], ddy = rays_d[3 * rid + 1], ddz = rays_d[3 * rid + 2];

  float true_cos = ddx * gnx + ddy * gny + ddz * gnz;
  float iter_cos = fminf(true_cos, 0.f);
  float inv_s = 1.f / s_val[0];
  float e = iter_cos * (DIST_C * 0.5f);
  float prev_cdf = sigm_((sdf - e) * inv_s);
  float next_cdf = sigm_((sdf + e) * inv_s);
  float alpha = (prev_cdf - next_cdf + 1e-5f) / (prev_cdf + 1e-5f);
  alpha_out[i] = fminf(fmaxf(alpha, 0.f), 1.f);

  u32x4* tb = (u32x4*)(TD + (size_t)i * 16);
  tb[0] = (u32x4){pk_bf16(k[0], k[1]), pk_bf16(k[2], k[3]),
                  pk_bf16(k[4], k[5]), pk_bf16(k[6], k[7])};
  tb[1] = (u32x4){pk_bf16(k[8], k[9]), pk_bf16(k[10], k[11]),
                  pk_bf16(gnx, gny), pk_bf16(gnz, 0.f)};
}

// ======== MFMA MLP: stride-128 LDS with XOR swizzle (16B unit ^= row&7) ========
__global__ __launch_bounds__(1024, 1) void vox_mlp_kernel(
    const float* __restrict__ ray_pts, const unsigned* __restrict__ VT,
    const int* __restrict__ ray_id, const unsigned short* __restrict__ TD,
    const unsigned short* __restrict__ W0B, const unsigned short* __restrict__ W1B,
    const unsigned short* __restrict__ W2B,
    const float* __restrict__ b0, const float* __restrict__ b1,
    const float* __restrict__ b2, float* __restrict__ rgb, int ngroups) {
  __shared__ __align__(16) unsigned short sW0[128 * 128];
  __shared__ __align__(16) unsigned short sW1[128 * 128];
  __shared__ __align__(16) unsigned short sW2[16 * 128];
  __shared__ __align__(16) unsigned short sH[16 * 16 * 128];
  __shared__ __align__(16) float sB0[128], sB1[128], sB2[16];

  {
    const uint4* s0 = (const uint4*)W0B; uint4* d0 = (uint4*)sW0;
    for (int i = threadIdx.x; i < 128 * 128 / 8; i += 1024) {
      int dst = (i & ~15) | ((i & 15) ^ ((i >> 4) & 7));
      d0[dst] = s0[i];
    }
    const uint4* s1 = (const uint4*)W1B; uint4* d1 = (uint4*)sW1;
    for (int i = threadIdx.x; i < 128 * 128 / 8; i += 1024) {
      int dst = (i & ~15) | ((i & 15) ^ ((i >> 4) & 7));
      d1[dst] = s1[i];
    }
    const uint4* s2 = (const uint4*)W2B; uint4* d2 = (uint4*)sW2;
    for (int i = threadIdx.x; i < 16 * 128 / 8; i += 1024) {
      int dst = (i & ~15) | ((i & 15) ^ ((i >> 4) & 7));
      d2[dst] = s2[i];
    }
    if (threadIdx.x < 128) { sB0[threadIdx.x] = b0[threadIdx.x]; sB1[threadIdx.x] = b1[threadIdx.x]; }
    if (threadIdx.x < 16) sB2[threadIdx.x] = (threadIdx.x < 3) ? b2[threadIdx.x] : 0.f;
  }
  __syncthreads();

  const int wid = (int)(threadIdx.x >> 6), lane = (int)(threadIdx.x & 63);
  const int l15 = lane & 15, g = lane >> 4;
  const int rsw = l15 & 7;                      // row-XOR for swizzled 16B units
  unsigned short* myH = sH + wid * (16 * 128);

#pragma unroll 1
  for (int t = 0; t < TPB; ++t) {
    int grp = blockIdx.x * TPB + t;
    if (grp >= ngroups) break;
    const int pt0 = grp * 256 + wid * 16;
    const int pt = pt0 + l15;

    float px = ray_pts[3 * pt + 0], py = ray_pts[3 * pt + 1], pz = ray_pts[3 * pt + 2];
    int rid = ray_id[pt];
    float x01 = (px + 1.f) * 0.5f, y01 = (py + 1.f) * 0.5f, z01 = (pz + 1.f) * 0.5f;
    // positional trig: 3 sincos + angle doubling (s2=2sc, c2=1-2s^2)
    float snx[5], csx[5], sny[5], csy[5], snz[5], csz[5];
    __sincosf(x01, &snx[0], &csx[0]);
    __sincosf(y01, &sny[0], &csy[0]);
    __sincosf(z01, &snz[0], &csz[0]);
#pragma unroll
    for (int l = 1; l < 5; l++) {
      snx[l] = 2.f * snx[l-1] * csx[l-1]; csx[l] = 1.f - 2.f * snx[l-1] * snx[l-1];
      sny[l] = 2.f * sny[l-1] * csy[l-1]; csy[l] = 1.f - 2.f * sny[l-1] * sny[l-1];
      snz[l] = 2.f * snz[l-1] * csz[l-1]; csz[l] = 1.f - 2.f * snz[l-1] * snz[l-1];
    }
    const u32x4* vt = (const u32x4*)(VT + (size_t)rid * 16);
    const u32x4* tdp = (const u32x4*)(TD + (size_t)pt * 16);

    // ---- build this lane's three B-slices ----
    bf16x8 cb0, cb1, cb2;
    const u32x4 zz = (u32x4){0u, 0u, 0u, 0u};
    switch (g) {
      case 0: {
        u32x4 td0 = tdp[0];
        cb0 = __builtin_bit_cast(bf16x8, td0);
        cb1 = __builtin_bit_cast(bf16x8, (u32x4){
            cvtpk(csx[2], csx[3]), cvtpk(csx[4], csy[0]),
            cvtpk(csy[1], csy[2]), cvtpk(csy[3], csy[4])});
        cb2 = __builtin_bit_cast(bf16x8, vt[0]);
        break;
      }
      case 1: {
        u32x4 td1 = tdp[1];
        u32x4 v3 = vt[3];
        float ddx = __builtin_bit_cast(float, v3.x);
        float ddy = __builtin_bit_cast(float, v3.y);
        float ddz = __builtin_bit_cast(float, v3.z);
        cb0 = __builtin_bit_cast(bf16x8, (u32x4){
            td1.x, td1.y, cvtpk(x01, y01), cvtpk(z01, snx[0])});
        cb1 = __builtin_bit_cast(bf16x8, (u32x4){
            cvtpk(csz[0], csz[1]), cvtpk(csz[2], csz[3]),
            cvtpk(csz[4], ddx), cvtpk(ddy, ddz)});
        cb2 = __builtin_bit_cast(bf16x8, (u32x4){td1.z, td1.w, 0u, 0u});
        break;
      }
      case 2:
        cb0 = __builtin_bit_cast(bf16x8, (u32x4){
            cvtpk(snx[1], snx[2]), cvtpk(snx[3], snx[4]),
            cvtpk(sny[0], sny[1]), cvtpk(sny[2], sny[3])});
        cb1 = __builtin_bit_cast(bf16x8, vt[1]);
        cb2 = __builtin_bit_cast(bf16x8, zz);
        break;
      default:
        cb0 = __builtin_bit_cast(bf16x8, (u32x4){
            cvtpk(sny[4], snz[0]), cvtpk(snz[1], snz[2]),
            cvtpk(snz[3], snz[4]), cvtpk(csx[0], csx[1])});
        cb1 = __builtin_bit_cast(bf16x8, vt[2]);
        cb2 = __builtin_bit_cast(bf16x8, zz);
        break;
    }

    // ---- GEMM1: D1[hid][pt] = W0^T x feat^T, K=96 ----
    f32x4 acc1[8];
#pragma unroll
    for (int m = 0; m < 8; m++) acc1[m] = (f32x4){0.f, 0.f, 0.f, 0.f};
#pragma unroll
    for (int m = 0; m < 8; m++) {
      const unsigned short* wr = sW0 + (m * 16 + l15) * 128;
      bf16x8 a0 = *(const bf16x8*)(wr + ((0 + g) ^ rsw) * 8);
      acc1[m] = __builtin_amdgcn_mfma_f32_16x16x32_bf16(a0, cb0, acc1[m], 0, 0, 0);
      bf16x8 a1 = *(const bf16x8*)(wr + ((4 + g) ^ rsw) * 8);
      acc1[m] = __builtin_amdgcn_mfma_f32_16x16x32_bf16(a1, cb1, acc1[m], 0, 0, 0);
      bf16x8 a2 = *(const bf16x8*)(wr + ((8 + g) ^ rsw) * 8);
      acc1[m] = __builtin_amdgcn_mfma_f32_16x16x32_bf16(a2, cb2, acc1[m], 0, 0, 0);
    }
#pragma unroll
    for (int m = 0; m < 8; m++) {
      f32x4 bias = *(const f32x4*)(sB0 + m * 16 + g * 4);
      float h0 = fmaxf(acc1[m][0] + bias[0], 0.f);
      float h1 = fmaxf(acc1[m][1] + bias[1], 0.f);
      float h2 = fmaxf(acc1[m][2] + bias[2], 0.f);
      float h3 = fmaxf(acc1[m][3] + bias[3], 0.f);
      int unit = 2 * m + (g >> 1);
      *(uint2*)(myH + l15 * 128 + (unit ^ rsw) * 8 + (g & 1) * 4) =
          make_uint2(cvtpk(h0, h1), cvtpk(h2, h3));
    }

    // ---- GEMM2: D2[hid2][pt] = W1^T x h1^T, K=128 ----
    f32x4 acc2[8];
#pragma unroll
    for (int m = 0; m < 8; m++) acc2[m] = (f32x4){0.f, 0.f, 0.f, 0.f};
#pragma unroll
    for (int ks = 0; ks < 4; ks++) {
      bf16x8 bfrag = *(const bf16x8*)(myH + l15 * 128 + ((4 * ks + g) ^ rsw) * 8);
#pragma unroll
      for (int m = 0; m < 8; m++) {
        bf16x8 afrag = *(const bf16x8*)(sW1 + (m * 16 + l15) * 128 + ((4 * ks + g) ^ rsw) * 8);
        acc2[m] = __builtin_amdgcn_mfma_f32_16x16x32_bf16(afrag, bfrag, acc2[m], 0, 0, 0);
      }
    }
#pragma unroll
    for (int m = 0; m < 8; m++) {
      f32x4 bias = *(const f32x4*)(sB1 + m * 16 + g * 4);
      float h0 = fmaxf(acc2[m][0] + bias[0], 0.f);
      float h1 = fmaxf(acc2[m][1] + bias[1], 0.f);
      float h2 = fmaxf(acc2[m][2] + bias[2], 0.f);
      float h3 = fmaxf(acc2[m][3] + bias[3], 0.f);
      int unit = 2 * m + (g >> 1);
      *(uint2*)(myH + l15 * 128 + (unit ^ rsw) * 8 + (g & 1) * 4) =
          make_uint2(cvtpk(h0, h1), cvtpk(h2, h3));
    }

    // ---- GEMM3: D3[ch][pt] = W2^T x h2^T, K=128, 1 tile ----
    f32x4 acc3 = (f32x4){0.f, 0.f, 0.f, 0.f};
#pragma unroll
    for (int ks = 0; ks < 4; ks++) {
      bf16x8 bfrag = *(const bf16x8*)(myH + l15 * 128 + ((4 * ks + g) ^ rsw) * 8);
      bf16x8 afrag = *(const bf16x8*)(sW2 + l15 * 128 + ((4 * ks + g) ^ rsw) * 8);
      acc3 = __builtin_amdgcn_mfma_f32_16x16x32_bf16(afrag, bfrag, acc3, 0, 0, 0);
    }
    if (g == 0) {   // rows 0..3 = channels; only 0..2 valid
      rgb[pt * 3 + 0] = sigm_(acc3[0] + sB2[0]);
      rgb[pt * 3 + 1] = sigm_(acc3[1] + sB2[1]);
      rgb[pt * 3 + 2] = sigm_(acc3[2] + sB2[2]);
    }
  }
}

// ============ per-ray scan + composite (1 wave / ray) ============
__global__ __launch_bounds__(256) void vox_scan_kernel(
    const float* __restrict__ alpha, const float* __restrict__ rgb,
    const int* __restrict__ ray_id, float* __restrict__ out, int M, int NR) {
  int wave = (int)((blockIdx.x * blockDim.x + threadIdx.x) >> 6);
  int lane = threadIdx.x & 63;
  if (wave >= NR) return;
  int r = wave;
  int lo = 0, hi = M;
  while (lo < hi) { int mid = (lo + hi) >> 1; if (ray_id[mid] < r) lo = mid + 1; else hi = mid; }
  int start = lo; hi = M;
  while (lo < hi) { int mid = (lo + hi) >> 1; if (ray_id[mid] < r + 1) lo = mid + 1; else hi = mid; }
  int end = lo;

  float carry = 0.f, cr = 0.f, cg = 0.f, cb = 0.f;
  for (int s = start; s < end; s += 64) {
    int idx = s + lane;
    bool valid = idx < end;
    float a = valid ? alpha[idx] : 0.f;
    float l = valid ? log1pf(-fminf(a, 1.f - 1e-7f)) : 0.f;
    float sc = l;
#pragma unroll
    for (int off = 1; off < 64; off <<= 1) {
      float t = __shfl_up(sc, (unsigned)off);
      if (lane >= off) sc += t;
    }
    if (valid) {
      float T = expf(carry + (sc - l));
      float w = a * T;
      cr = fmaf(w, rgb[3 * idx + 0], cr);
      cg = fmaf(w, rgb[3 * idx + 1], cg);
      cb = fmaf(w, rgb[3 * idx + 2], cb);
    }
    carry += __shfl(sc, 63);
  }
#pragma unroll
  for (int off = 32; off > 0; off >>= 1) {
    cr += __shfl_down(cr, (unsigned)off);
    cg += __shfl_down(cg, (unsigned)off);
    cb += __shfl_down(cb, (unsigned)off);
  }
  if (lane == 0) {
    float ail = expf(carry);
    out[3 * r + 0] = cr + ail;
    out[3 * r + 1] = cg + ail;
    out[3 * r + 2] = cb + ail;
  }
}

// ============ fallback (round-1 monolithic path, used if ws too small) ============
__global__ __launch_bounds__(256) void vox_transpose_w0(
    const float* __restrict__ w0, float* __restrict__ w0t) {
  for (int idx = threadIdx.x; idx < 128 * 80; idx += 256) {
    int j = idx / 80, k = idx - j * 80;
    w0t[idx] = (k < 75) ? w0[k * 128 + j] : 0.f;
  }
}

__global__ __launch_bounds__(256) void vox_point_kernel(
    const float* __restrict__ ray_pts, const float* __restrict__ rays_d,
    const float* __restrict__ sdf_vol, const float* __restrict__ k0_vol,
    const float* __restrict__ w0t, const float* __restrict__ b0,
    const float* __restrict__ w1, const float* __restrict__ b1,
    const float* __restrict__ w2, const float* __restrict__ b2,
    const float* __restrict__ s_val, const int* __restrict__ ray_id,
    float* __restrict__ alpha_out, float* __restrict__ rgb_out, int M) {
  int i = blockIdx.x * 256 + threadIdx.x;
  if (i >= M) return;
  float px = ray_pts[3 * i + 0], py = ray_pts[3 * i + 1], pz = ray_pts[3 * i + 2];
  const float SC = 0.5f * 159.f;
  float ux = fminf(fmaxf((px + 1.f) * SC, 0.f), 159.f);
  float uy = fminf(fmaxf((py + 1.f) * SC, 0.f), 159.f);
  float uz = fminf(fmaxf((pz + 1.f) * SC, 0.f), 159.f);
  int ix = min((int)ux, 158), iy = min((int)uy, 158), iz = min((int)uz, 158);
  float fx = ux - (float)ix, fy = uy - (float)iy, fz = uz - (float)iz;
  float wx0 = 1.f - fx, wy0 = 1.f - fy, wz0 = 1.f - fz;
  float w000 = wx0 * wy0 * wz0, w001 = wx0 * wy0 * fz;
  float w010 = wx0 * fy * wz0,  w011 = wx0 * fy * fz;
  float w100 = fx * wy0 * wz0,  w101 = fx * wy0 * fz;
  float w110 = fx * fy * wz0,   w111 = fx * fy * fz;
  int base = (ix * GRIDN + iy) * GRIDN + iz;
  const float* V = sdf_vol;
  float c000 = V[base],          c001 = V[base + 1];
  float c010 = V[base + SY],     c011 = V[base + SY + 1];
  float c100 = V[base + SX],     c101 = V[base + SX + 1];
  float c110 = V[base + SX + SY], c111 = V[base + SX + SY + 1];
  float xm00 = V[base - SX],          xm01 = V[base - SX + 1];
  float xm10 = V[base - SX + SY],     xm11 = V[base - SX + SY + 1];
  float xp00 = V[base + 2 * SX],      xp01 = V[base + 2 * SX + 1];
  float xp10 = V[base + 2 * SX + SY], xp11 = V[base + 2 * SX + SY + 1];
  float ym00 = V[base - SY],          ym01 = V[base - SY + 1];
  float ym10 = V[base + SX - SY],     ym11 = V[base + SX - SY + 1];
  float yp00 = V[base + 2 * SY],      yp01 = V[base + 2 * SY + 1];
  float yp10 = V[base + SX + 2 * SY], yp11 = V[base + SX + 2 * SY + 1];
  float zm00 = V[base - 1],           zm01 = V[base + SY - 1];
  float zm10 = V[base + SX - 1],      zm11 = V[base + SX + SY - 1];
  float zp00 = V[base + 2],           zp01 = V[base + SY + 2];
  float zp10 = V[base + SX + 2],      zp11 = V[base + SX + SY + 2];
  float sdf = w000 * c000 + w001 * c001 + w010 * c010 + w011 * c011 +
              w100 * c100 + w101 * c101 + w110 * c110 + w111 * c111;
  const float INV2H = 159.f / 4.f;
  float gx = (w000 * (c100 - xm00) + w001 * (c101 - xm01) +
              w010 * (c110 - xm10) + w011 * (c111 - xm11) +
              w100 * (xp00 - c000) + w101 * (xp01 - c001) +
              w110 * (xp10 - c010) + w111 * (xp11 - c011)) * INV2H;
  float gy = (w000 * (c010 - ym00) + w001 * (c011 - ym01) +
              w100 * (c110 - ym10) + w101 * (c111 - ym11) +
              w010 * (yp00 - c000) + w011 * (yp01 - c001) +
              w110 * (yp10 - c100) + w111 * (yp11 - c101)) * INV2H;
  float gz = (w000 * (c001 - zm00) + w010 * (c011 - zm01) +
              w100 * (c101 - zm10) + w110 * (c111 - zm11) +
              w001 * (zp00 - c000) + w011 * (zp01 - c010) +
              w101 * (zp10 - c100) + w111 * (zp11 - c110)) * INV2H;
  float ginv = 1.f / (sqrtf(gx * gx + gy * gy + gz * gz) + 1e-8f);
  float gnx = gx * ginv, gny = gy * ginv, gnz = gz * ginv;
  int rid = ray_id[i];
  float ddx = rays_d[3 * rid + 0], ddy = rays_d[3 * rid + 1], ddz = rays_d[3 * rid + 2];
  float true_cos = ddx * gnx + ddy * gny + ddz * gnz;
  float iter_cos = fminf(true_cos, 0.f);
  float inv_s = 1.f / s_val[0];
  float e = iter_cos * (DIST_C * 0.5f);
  float prev_cdf = sigm_((sdf - e) * inv_s);
  float next_cdf = sigm_((sdf + e) * inv_s);
  float alpha = fminf(fmaxf((prev_cdf - next_cdf + 1e-5f) / (prev_cdf + 1e-5f), 0.f), 1.f);
  alpha_out[i] = alpha;
  float feat[75];
  {
    const int offs[8] = {0, 1, SY, SY + 1, SX, SX + 1, SX + SY, SX + SY + 1};
    const float wts[8] = {w000, w001, w010, w011, w100, w101, w110, w111};
#pragma unroll
    for (int c = 0; c < 12; c++) {
      const float* kc = k0_vol + c * N3 + base;
      float acc = 0.f;
#pragma unroll
      for (int t = 0; t < 8; t++) acc = fmaf(wts[t], kc[offs[t]], acc);
      feat[c] = acc;
    }
  }
  float x01 = (px + 1.f) * 0.5f, y01 = (py + 1.f) * 0.5f, z01 = (pz + 1.f) * 0.5f;
  feat[12] = x01; feat[13] = y01; feat[14] = z01;
#pragma unroll
  for (int l = 0; l < 5; l++) {
    float f = (float)(1 << l), s, c;
    sincosf(x01 * f, &s, &c); feat[15 + l] = s; feat[30 + l] = c;
    sincosf(y01 * f, &s, &c); feat[20 + l] = s; feat[35 + l] = c;
    sincosf(z01 * f, &s, &c); feat[25 + l] = s; feat[40 + l] = c;
  }
  feat[45] = ddx; feat[46] = ddy; feat[47] = ddz;
#pragma unroll
  for (int l = 0; l < 4; l++) {
    float f = (float)(1 << l), s, c;
    sincosf(ddx * f, &s, &c); feat[48 + l] = s; feat[60 + l] = c;
    sincosf(ddy * f, &s, &c); feat[52 + l] = s; feat[64 + l] = c;
    sincosf(ddz * f, &s, &c); feat[56 + l] = s; feat[68 + l] = c;
  }
  feat[72] = gnx; feat[73] = gny; feat[74] = gnz;
  float rr = 0.f, rg = 0.f, rb = 0.f;
#pragma unroll 1
  for (int half = 0; half < 2; ++half) {
    float acc[64];
#pragma unroll
    for (int t = 0; t < 64; t++) acc[t] = b1[half * 64 + t];
#pragma unroll 1
    for (int j = 0; j < 128; ++j) {
      float h = b0[j];
      const float* wr = w0t + j * 80;
#pragma unroll
      for (int k = 0; k < 75; k++) h = fmaf(feat[k], wr[k], h);
      h = fmaxf(h, 0.f);
      const float* w1r = w1 + j * 128 + half * 64;
#pragma unroll
      for (int t = 0; t < 64; t++) acc[t] = fmaf(h, w1r[t], acc[t]);
    }
#pragma unroll
    for (int t = 0; t < 64; t++) {
      float h2 = fmaxf(acc[t], 0.f);
      int j2 = half * 64 + t;
      rr = fmaf(h2, w2[3 * j2 + 0], rr);
      rg = fmaf(h2, w2[3 * j2 + 1], rg);
      rb = fmaf(h2, w2[3 * j2 + 2], rb);
    }
  }
  rgb_out[3 * i + 0] = sigm_(rr + b2[0]);
  rgb_out[3 * i + 1] = sigm_(rg + b2[1]);
  rgb_out[3 * i + 2] = sigm_(rb + b2[2]);
}

extern "C" void kernel_launch(void* const* d_in, const int* in_sizes, int n_in,
                              void* d_out, int out_size, void* d_ws, size_t ws_size,
                              hipStream_t stream) {
  const float* ray_pts = (const float*)d_in[0];
  const float* rays_d  = (const float*)d_in[1];
  const float* sdf_vol = (const float*)d_in[2];
  const float* k0_vol  = (const float*)d_in[3];
  const float* w0      = (const float*)d_in[4];
  const float* b0      = (const float*)d_in[5];
  const float* w1      = (const float*)d_in[6];
  const float* b1      = (const float*)d_in[7];
  const float* w2      = (const float*)d_in[8];
  const float* b2      = (const float*)d_in[9];
  const float* s_val   = (const float*)d_in[10];
  const int*   ray_id  = (const int*)d_in[11];
  float* out = (float*)d_out;

  int M  = in_sizes[0] / 3;   // 1048576
  int NR = in_sizes[1] / 3;   // 8192

  char* ws = (char*)d_ws;
  size_t offVR   = 0;                                  // N3*32 combined records
  size_t offTD   = offVR + (size_t)N3 * 32;            // M*32 tap digests
  size_t offA    = offTD + (size_t)M * 32;
  size_t offRgb  = offA + (size_t)M * 4;
  size_t offW0   = offRgb + (size_t)M * 12;
  size_t offW1   = offW0 + (size_t)128 * 128 * 2;
  size_t offW2   = offW1 + (size_t)128 * 128 * 2;
  size_t offVT   = offW2 + (size_t)16 * 128 * 2;
  size_t need    = offVT + (size_t)NR * 64;

  if (ws_size >= need && (M % 256) == 0) {
    unsigned short* VR = (unsigned short*)(ws + offVR);
    unsigned short* TD = (unsigned short*)(ws + offTD);
    float* alpha_ws = (float*)(ws + offA);
    float* rgb_ws = (float*)(ws + offRgb);
    unsigned short* W0B = (unsigned short*)(ws + offW0);
    unsigned short* W1B = (unsigned short*)(ws + offW1);
    unsigned short* W2B = (unsigned short*)(ws + offW2);
    unsigned* VT = (unsigned*)(ws + offVT);

    int ngroups = M / 256;
    vox_repack_all<<<(N3 + 255) / 256, 256, 0, stream>>>(sdf_vol, k0_vol, VR);
    vox_repack_w<<<(128 * 128 + 255) / 256, 256, 0, stream>>>(w0, w1, w2, W0B, W1B, W2B);
    vox_view_table<<<(NR + 255) / 256, 256, 0, stream>>>(rays_d, VT, NR);
    vox_gather_kernel<<<(M + 255) / 256, 256, 0, stream>>>(
        ray_pts, rays_d, VR, s_val, ray_id, alpha_ws, TD, M);
    vox_mlp_kernel<<<(ngroups + TPB - 1) / TPB, 1024, 0, stream>>>(
        ray_pts, VT, ray_id, TD, W0B, W1B, W2B, b0, b1, b2, rgb_ws, ngroups);
    vox_scan_kernel<<<(NR * 64 + 255) / 256, 256, 0, stream>>>(
        alpha_ws, rgb_ws, ray_id, out, M, NR);
  } else {
    float* alpha_ws = (float*)ws;
    float* rgb_ws   = (float*)(ws + (size_t)M * 4);
    float* w0t_ws   = (float*)(ws + (size_t)M * 16);
    vox_transpose_w0<<<1, 256, 0, stream>>>(w0, w0t_ws);
    vox_point_kernel<<<(M + 255) / 256, 256, 0, stream>>>(
        ray_pts, rays_d, sdf_vol, k0_vol, w0t_ws, b0, w1, b1, w2, b2,
        s_val, ray_id, alpha_ws, rgb_ws, M);
    vox_scan_kernel<<<(NR * 64 + 255) / 256, 256, 0, stream>>>(
        alpha_ws, rgb_ws, ray_id, out, M, NR);
  }
}

// Round 20
// 291.040 us; speedup vs baseline: 7.1494x; 1.0056x over previous
//
#include <hip/hip_runtime.h>
#include <math.h>

#define GRIDN 160
#define N3 (160*160*160)
#define SX (160*160)
#define SY 160
#define DIST_C 0.005f
#define TPB 16    // groups (of 256 points) per MLP block -> grid = 256 = 1 block/CU

__device__ __forceinline__ float sigm_(float x) { return 1.f / (1.f + expf(-x)); }
__device__ __forceinline__ unsigned short f2bf(float x) {
  unsigned u = __builtin_bit_cast(unsigned, x);
  u = (u + 0x7fffu + ((u >> 16) & 1u)) >> 16;
  return (unsigned short)u;
}
__device__ __forceinline__ unsigned pk_bf16(float a, float b) {
  return (unsigned)f2bf(a) | ((unsigned)f2bf(b) << 16);
}
// single-instruction RNE pack: a -> low bf16, b -> high bf16
__device__ __forceinline__ unsigned cvtpk(float a, float b) {
  unsigned r;
  asm("v_cvt_pk_bf16_f32 %0, %1, %2" : "=v"(r) : "v"(a), "v"(b));
  return r;
}
__device__ __forceinline__ float bf_lo(unsigned u) { return __builtin_bit_cast(float, u << 16); }
__device__ __forceinline__ float bf_hi(unsigned u) { return __builtin_bit_cast(float, u & 0xffff0000u); }
__device__ __forceinline__ unsigned short f2h(float x) {
  _Float16 h = (_Float16)x; return __builtin_bit_cast(unsigned short, h);
}
__device__ __forceinline__ float h_lo(unsigned u) {
  return (float)__builtin_bit_cast(_Float16, (unsigned short)(u & 0xffffu));
}
__device__ __forceinline__ float h_hi(unsigned u) {
  return (float)__builtin_bit_cast(_Float16, (unsigned short)(u >> 16));
}

typedef __attribute__((ext_vector_type(8))) short bf16x8;
typedef __attribute__((ext_vector_type(4))) float f32x4;
typedef __attribute__((ext_vector_type(4))) unsigned u32x4;

// ==== fused repack -> 32B voxel record: [sdf,gx,gy,gz](f16) + k0 ch0..11 (bf16) ====
__global__ __launch_bounds__(256) void vox_repack_all(
    const float* __restrict__ V, const float* __restrict__ k0,
    unsigned short* __restrict__ VR) {
  int idx = blockIdx.x * 256 + threadIdx.x;
  if (idx >= N3) return;
  int z = idx % GRIDN; int t = idx / GRIDN; int y = t % GRIDN; int x = t / GRIDN;
  float v = V[idx];
  float xp = (x < 159) ? V[idx + SX] : v, xm = (x > 0) ? V[idx - SX] : v;
  float yp = (y < 159) ? V[idx + SY] : v, ym = (y > 0) ? V[idx - SY] : v;
  float zp = (z < 159) ? V[idx + 1]  : v, zm = (z > 0) ? V[idx - 1]  : v;
  float cx = (x > 0 && x < 159) ? (159.f / 4.f) : (159.f / 2.f);
  float cy = (y > 0 && y < 159) ? (159.f / 4.f) : (159.f / 2.f);
  float cz = (z > 0 && z < 159) ? (159.f / 4.f) : (159.f / 2.f);
  unsigned f0 = (unsigned)f2h(v) | ((unsigned)f2h((xp - xm) * cx) << 16);
  unsigned f1 = (unsigned)f2h((yp - ym) * cy) | ((unsigned)f2h((zp - zm) * cz) << 16);
  unsigned w[6];
#pragma unroll
  for (int j = 0; j < 6; j++) {
    float a = __builtin_nontemporal_load(k0 + (size_t)(2 * j) * N3 + idx);
    float b = __builtin_nontemporal_load(k0 + (size_t)(2 * j + 1) * N3 + idx);
    w[j] = pk_bf16(a, b);
  }
  u32x4* r = (u32x4*)(VR + (size_t)idx * 16);
  r[0] = (u32x4){f0, f1, w[0], w[1]};
  r[1] = (u32x4){w[2], w[3], w[4], w[5]};
}

// ============ repack weights -> transposed bf16, stride 128 (for XOR-swz LDS) ======
__global__ __launch_bounds__(256) void vox_repack_w(
    const float* __restrict__ w0, const float* __restrict__ w1, const float* __restrict__ w2,
    unsigned short* __restrict__ W0B, unsigned short* __restrict__ W1B,
    unsigned short* __restrict__ W2B) {
  int i = blockIdx.x * 256 + threadIdx.x;
  if (i < 128 * 128) {                    // W0B[c][k] = w0[k][c], k<75
    int c = i >> 7, k = i & 127;
    W0B[i] = (k < 75) ? f2bf(w0[k * 128 + c]) : (unsigned short)0;
  }
  if (i < 128 * 128) {                    // W1B[c][k] = w1[k][c], k<128
    int c = i >> 7, k = i & 127;
    W1B[i] = f2bf(w1[k * 128 + c]);
  }
  if (i < 16 * 128) {                     // W2B[c][k] = w2[k][c], c<3, k<128
    int c = i >> 7, k = i & 127;
    W2B[i] = (c < 3) ? f2bf(w2[k * 3 + c]) : (unsigned short)0;
  }
}

// ============ per-ray view-embedding table: 64B/ray, pre-packed per g-slice ========
__global__ __launch_bounds__(256) void vox_view_table(
    const float* __restrict__ rays_d, unsigned* __restrict__ VT, int NR) {
  int r = blockIdx.x * 256 + threadIdx.x;
  if (r >= NR) return;
  float dx = rays_d[3 * r + 0], dy = rays_d[3 * r + 1], dz = rays_d[3 * r + 2];
  float sx[4], cx[4], sy[4], cy[4], sz[4], cz[4];
#pragma unroll
  for (int l = 0; l < 4; l++) {
    float f = (float)(1 << l);
    __sincosf(dx * f, &sx[l], &cx[l]);
    __sincosf(dy * f, &sy[l], &cy[l]);
    __sincosf(dz * f, &sz[l], &cz[l]);
  }
  u32x4* v = (u32x4*)(VT + (size_t)r * 16);
  v[0] = (u32x4){pk_bf16(cy[0], cy[1]), pk_bf16(cy[2], cy[3]),
                 pk_bf16(cz[0], cz[1]), pk_bf16(cz[2], cz[3])};
  v[1] = (u32x4){pk_bf16(sx[0], sx[1]), pk_bf16(sx[2], sx[3]),
                 pk_bf16(sy[0], sy[1]), pk_bf16(sy[2], sy[3])};
  v[2] = (u32x4){pk_bf16(sz[0], sz[1]), pk_bf16(sz[2], sz[3]),
                 pk_bf16(cx[0], cx[1]), pk_bf16(cx[2], cx[3])};
  v[3] = (u32x4){__builtin_bit_cast(unsigned, dx), __builtin_bit_cast(unsigned, dy),
                 __builtin_bit_cast(unsigned, dz), 0u};
}

// ============ gather: taps + alpha + 32B tap-digest TD = [k0..k11, gn, 0] bf16 ======
__global__ __launch_bounds__(256) void vox_gather_kernel(
    const float* __restrict__ ray_pts, const float* __restrict__ rays_d,
    const unsigned short* __restrict__ VR,
    const float* __restrict__ s_val, const int* __restrict__ ray_id,
    float* __restrict__ alpha_out, unsigned short* __restrict__ TD, int M) {
  int i = blockIdx.x * 256 + threadIdx.x;
  if (i >= M) return;

  float px = ray_pts[3 * i + 0], py = ray_pts[3 * i + 1], pz = ray_pts[3 * i + 2];
  const float SC = 0.5f * 159.f;
  float ux = fminf(fmaxf((px + 1.f) * SC, 0.f), 159.f);
  float uy = fminf(fmaxf((py + 1.f) * SC, 0.f), 159.f);
  float uz = fminf(fmaxf((pz + 1.f) * SC, 0.f), 159.f);
  int ix = min((int)ux, 158), iy = min((int)uy, 158), iz = min((int)uz, 158);
  float fx = ux - (float)ix, fy = uy - (float)iy, fz = uz - (float)iz;
  float wx0 = 1.f - fx, wy0 = 1.f - fy, wz0 = 1.f - fz;
  float wxy[4];
  wxy[0] = wx0 * wy0; wxy[1] = wx0 * fy; wxy[2] = fx * wy0; wxy[3] = fx * fy;
  const int pairoff[4] = {0, SY, SX, SX + SY};
  int base = (ix * GRIDN + iy) * GRIDN + iz;

  u32x4 q[4][4];
#pragma unroll
  for (int t = 0; t < 4; t++) {
    const u32x4* p = (const u32x4*)(VR + (size_t)(base + pairoff[t]) * 16);
    q[t][0] = p[0]; q[t][1] = p[1]; q[t][2] = p[2]; q[t][3] = p[3];
  }

  float sdf = 0.f, gx = 0.f, gy = 0.f, gz = 0.f;
  float k[12];
#pragma unroll
  for (int j = 0; j < 12; j++) k[j] = 0.f;
#pragma unroll
  for (int t = 0; t < 4; t++) {
    float w0z = wxy[t] * wz0, w1z = wxy[t] * fz;
    sdf = fmaf(w0z, h_lo(q[t][0].x), sdf);
    gx  = fmaf(w0z, h_hi(q[t][0].x), gx);
    gy  = fmaf(w0z, h_lo(q[t][0].y), gy);
    gz  = fmaf(w0z, h_hi(q[t][0].y), gz);
    k[0]  = fmaf(w0z, bf_lo(q[t][0].z), k[0]);
    k[1]  = fmaf(w0z, bf_hi(q[t][0].z), k[1]);
    k[2]  = fmaf(w0z, bf_lo(q[t][0].w), k[2]);
    k[3]  = fmaf(w0z, bf_hi(q[t][0].w), k[3]);
    k[4]  = fmaf(w0z, bf_lo(q[t][1].x), k[4]);
    k[5]  = fmaf(w0z, bf_hi(q[t][1].x), k[5]);
    k[6]  = fmaf(w0z, bf_lo(q[t][1].y), k[6]);
    k[7]  = fmaf(w0z, bf_hi(q[t][1].y), k[7]);
    k[8]  = fmaf(w0z, bf_lo(q[t][1].z), k[8]);
    k[9]  = fmaf(w0z, bf_hi(q[t][1].z), k[9]);
    k[10] = fmaf(w0z, bf_lo(q[t][1].w), k[10]);
    k[11] = fmaf(w0z, bf_hi(q[t][1].w), k[11]);
    sdf = fmaf(w1z, h_lo(q[t][2].x), sdf);
    gx  = fmaf(w1z, h_hi(q[t][2].x), gx);
    gy  = fmaf(w1z, h_lo(q[t][2].y), gy);
    gz  = fmaf(w1z, h_hi(q[t][2].y), gz);
    k[0]  = fmaf(w1z, bf_lo(q[t][2].z), k[0]);
    k[1]  = fmaf(w1z, bf_hi(q[t][2].z), k[1]);
    k[2]  = fmaf(w1z, bf_lo(q[t][2].w), k[2]);
    k[3]  = fmaf(w1z, bf_hi(q[t][2].w), k[3]);
    k[4]  = fmaf(w1z, bf_lo(q[t][3].x), k[4]);
    k[5]  = fmaf(w1z, bf_hi(q[t][3].x), k[5]);
    k[6]  = fmaf(w1z, bf_lo(q[t][3].y), k[6]);
    k[7]  = fmaf(w1z, bf_hi(q[t][3].y), k[7]);
    k[8]  = fmaf(w1z, bf_lo(q[t][3].z), k[8]);
    k[9]  = fmaf(w1z, bf_hi(q[t][3].z), k[9]);
    k[10] = fmaf(w1z, bf_lo(q[t][3].w), k[10]);
    k[11] = fmaf(w1z, bf_hi(q[t][3].w), k[11]);
  }
  float ginv = 1.f / (sqrtf(gx * gx + gy * gy + gz * gz) + 1e-8f);
  float gnx = gx * ginv, gny = gy * ginv, gnz = gz * ginv;

  int rid = ray_id[i];
  float ddx = rays_d[3 * rid + 0], ddy = rays_d[3 * rid + 1], ddz = rays_d[3 * rid + 2];

  float true_cos = ddx * gnx + ddy * gny + ddz * gnz;
  float iter_cos = fminf(true_cos, 0.f);
  float inv_s = 1.f / s_val[0];
  float e = iter_cos * (DIST_C * 0.5f);
  float prev_cdf = sigm_((sdf - e) * inv_s);
  float next_cdf = sigm_((sdf + e) * inv_s);
  float alpha = (prev_cdf - next_cdf + 1e-5f) / (prev_cdf + 1e-5f);
  alpha_out[i] = fminf(fmaxf(alpha, 0.f), 1.f);

  u32x4* tb = (u32x4*)(TD + (size_t)i * 16);
  tb[0] = (u32x4){pk_bf16(k[0], k[1]), pk_bf16(k[2], k[3]),
                  pk_bf16(k[4], k[5]), pk_bf16(k[6], k[7])};
  tb[1] = (u32x4){pk_bf16(k[8], k[9]), pk_bf16(k[10], k[11]),
                  pk_bf16(gnx, gny), pk_bf16(gnz, 0.f)};
}

// ======== MFMA MLP: stride-128 LDS with XOR swizzle + T5 setprio on MFMA clusters ==
__global__ __launch_bounds__(1024, 1) void vox_mlp_kernel(
    const float* __restrict__ ray_pts, const unsigned* __restrict__ VT,
    const int* __restrict__ ray_id, const unsigned short* __restrict__ TD,
    const unsigned short* __restrict__ W0B, const unsigned short* __restrict__ W1B,
    const unsigned short* __restrict__ W2B,
    const float* __restrict__ b0, const float* __restrict__ b1,
    const float* __restrict__ b2, float* __restrict__ rgb, int ngroups) {
  __shared__ __align__(16) unsigned short sW0[128 * 128];
  __shared__ __align__(16) unsigned short sW1[128 * 128];
  __shared__ __align__(16) unsigned short sW2[16 * 128];
  __shared__ __align__(16) unsigned short sH[16 * 16 * 128];
  __shared__ __align__(16) float sB0[128], sB1[128], sB2[16];

  {
    const uint4* s0 = (const uint4*)W0B; uint4* d0 = (uint4*)sW0;
    for (int i = threadIdx.x; i < 128 * 128 / 8; i += 1024) {
      int dst = (i & ~15) | ((i & 15) ^ ((i >> 4) & 7));
      d0[dst] = s0[i];
    }
    const uint4* s1 = (const uint4*)W1B; uint4* d1 = (uint4*)sW1;
    for (int i = threadIdx.x; i < 128 * 128 / 8; i += 1024) {
      int dst = (i & ~15) | ((i & 15) ^ ((i >> 4) & 7));
      d1[dst] = s1[i];
    }
    const uint4* s2 = (const uint4*)W2B; uint4* d2 = (uint4*)sW2;
    for (int i = threadIdx.x; i < 16 * 128 / 8; i += 1024) {
      int dst = (i & ~15) | ((i & 15) ^ ((i >> 4) & 7));
      d2[dst] = s2[i];
    }
    if (threadIdx.x < 128) { sB0[threadIdx.x] = b0[threadIdx.x]; sB1[threadIdx.x] = b1[threadIdx.x]; }
    if (threadIdx.x < 16) sB2[threadIdx.x] = (threadIdx.x < 3) ? b2[threadIdx.x] : 0.f;
  }
  __syncthreads();

  const int wid = (int)(threadIdx.x >> 6), lane = (int)(threadIdx.x & 63);
  const int l15 = lane & 15, g = lane >> 4;
  const int rsw = l15 & 7;                      // row-XOR for swizzled 16B units
  unsigned short* myH = sH + wid * (16 * 128);

#pragma unroll 1
  for (int t = 0; t < TPB; ++t) {
    int grp = blockIdx.x * TPB + t;
    if (grp >= ngroups) break;
    const int pt0 = grp * 256 + wid * 16;
    const int pt = pt0 + l15;

    float px = ray_pts[3 * pt + 0], py = ray_pts[3 * pt + 1], pz = ray_pts[3 * pt + 2];
    int rid = ray_id[pt];
    float x01 = (px + 1.f) * 0.5f, y01 = (py + 1.f) * 0.5f, z01 = (pz + 1.f) * 0.5f;
    // positional trig: 3 sincos + angle doubling (s2=2sc, c2=1-2s^2)
    float snx[5], csx[5], sny[5], csy[5], snz[5], csz[5];
    __sincosf(x01, &snx[0], &csx[0]);
    __sincosf(y01, &sny[0], &csy[0]);
    __sincosf(z01, &snz[0], &csz[0]);
#pragma unroll
    for (int l = 1; l < 5; l++) {
      snx[l] = 2.f * snx[l-1] * csx[l-1]; csx[l] = 1.f - 2.f * snx[l-1] * snx[l-1];
      sny[l] = 2.f * sny[l-1] * csy[l-1]; csy[l] = 1.f - 2.f * sny[l-1] * sny[l-1];
      snz[l] = 2.f * snz[l-1] * csz[l-1]; csz[l] = 1.f - 2.f * snz[l-1] * snz[l-1];
    }
    const u32x4* vt = (const u32x4*)(VT + (size_t)rid * 16);
    const u32x4* tdp = (const u32x4*)(TD + (size_t)pt * 16);

    // ---- build this lane's three B-slices ----
    bf16x8 cb0, cb1, cb2;
    const u32x4 zz = (u32x4){0u, 0u, 0u, 0u};
    switch (g) {
      case 0: {
        u32x4 td0 = tdp[0];
        cb0 = __builtin_bit_cast(bf16x8, td0);
        cb1 = __builtin_bit_cast(bf16x8, (u32x4){
            cvtpk(csx[2], csx[3]), cvtpk(csx[4], csy[0]),
            cvtpk(csy[1], csy[2]), cvtpk(csy[3], csy[4])});
        cb2 = __builtin_bit_cast(bf16x8, vt[0]);
        break;
      }
      case 1: {
        u32x4 td1 = tdp[1];
        u32x4 v3 = vt[3];
        float ddx = __builtin_bit_cast(float, v3.x);
        float ddy = __builtin_bit_cast(float, v3.y);
        float ddz = __builtin_bit_cast(float, v3.z);
        cb0 = __builtin_bit_cast(bf16x8, (u32x4){
            td1.x, td1.y, cvtpk(x01, y01), cvtpk(z01, snx[0])});
        cb1 = __builtin_bit_cast(bf16x8, (u32x4){
            cvtpk(csz[0], csz[1]), cvtpk(csz[2], csz[3]),
            cvtpk(csz[4], ddx), cvtpk(ddy, ddz)});
        cb2 = __builtin_bit_cast(bf16x8, (u32x4){td1.z, td1.w, 0u, 0u});
        break;
      }
      case 2:
        cb0 = __builtin_bit_cast(bf16x8, (u32x4){
            cvtpk(snx[1], snx[2]), cvtpk(snx[3], snx[4]),
            cvtpk(sny[0], sny[1]), cvtpk(sny[2], sny[3])});
        cb1 = __builtin_bit_cast(bf16x8, vt[1]);
        cb2 = __builtin_bit_cast(bf16x8, zz);
        break;
      default:
        cb0 = __builtin_bit_cast(bf16x8, (u32x4){
            cvtpk(sny[4], snz[0]), cvtpk(snz[1], snz[2]),
            cvtpk(snz[3], snz[4]), cvtpk(csx[0], csx[1])});
        cb1 = __builtin_bit_cast(bf16x8, vt[2]);
        cb2 = __builtin_bit_cast(bf16x8, zz);
        break;
    }

    // ---- GEMM1: D1[hid][pt] = W0^T x feat^T, K=96 ----
    f32x4 acc1[8];
#pragma unroll
    for (int m = 0; m < 8; m++) acc1[m] = (f32x4){0.f, 0.f, 0.f, 0.f};
    __builtin_amdgcn_s_setprio(1);
#pragma unroll
    for (int m = 0; m < 8; m++) {
      const unsigned short* wr = sW0 + (m * 16 + l15) * 128;
      bf16x8 a0 = *(const bf16x8*)(wr + ((0 + g) ^ rsw) * 8);
      acc1[m] = __builtin_amdgcn_mfma_f32_16x16x32_bf16(a0, cb0, acc1[m], 0, 0, 0);
      bf16x8 a1 = *(const bf16x8*)(wr + ((4 + g) ^ rsw) * 8);
      acc1[m] = __builtin_amdgcn_mfma_f32_16x16x32_bf16(a1, cb1, acc1[m], 0, 0, 0);
      bf16x8 a2 = *(const bf16x8*)(wr + ((8 + g) ^ rsw) * 8);
      acc1[m] = __builtin_amdgcn_mfma_f32_16x16x32_bf16(a2, cb2, acc1[m], 0, 0, 0);
    }
    __builtin_amdgcn_s_setprio(0);
#pragma unroll
    for (int m = 0; m < 8; m++) {
      f32x4 bias = *(const f32x4*)(sB0 + m * 16 + g * 4);
      float h0 = fmaxf(acc1[m][0] + bias[0], 0.f);
      float h1 = fmaxf(acc1[m][1] + bias[1], 0.f);
      float h2 = fmaxf(acc1[m][2] + bias[2], 0.f);
      float h3 = fmaxf(acc1[m][3] + bias[3], 0.f);
      int unit = 2 * m + (g >> 1);
      *(uint2*)(myH + l15 * 128 + (unit ^ rsw) * 8 + (g & 1) * 4) =
          make_uint2(cvtpk(h0, h1), cvtpk(h2, h3));
    }

    // ---- GEMM2: D2[hid2][pt] = W1^T x h1^T, K=128 ----
    f32x4 acc2[8];
#pragma unroll
    for (int m = 0; m < 8; m++) acc2[m] = (f32x4){0.f, 0.f, 0.f, 0.f};
    __builtin_amdgcn_s_setprio(1);
#pragma unroll
    for (int ks = 0; ks < 4; ks++) {
      bf16x8 bfrag = *(const bf16x8*)(myH + l15 * 128 + ((4 * ks + g) ^ rsw) * 8);
#pragma unroll
      for (int m = 0; m < 8; m++) {
        bf16x8 afrag = *(const bf16x8*)(sW1 + (m * 16 + l15) * 128 + ((4 * ks + g) ^ rsw) * 8);
        acc2[m] = __builtin_amdgcn_mfma_f32_16x16x32_bf16(afrag, bfrag, acc2[m], 0, 0, 0);
      }
    }
    __builtin_amdgcn_s_setprio(0);
#pragma unroll
    for (int m = 0; m < 8; m++) {
      f32x4 bias = *(const f32x4*)(sB1 + m * 16 + g * 4);
      float h0 = fmaxf(acc2[m][0] + bias[0], 0.f);
      float h1 = fmaxf(acc2[m][1] + bias[1], 0.f);
      float h2 = fmaxf(acc2[m][2] + bias[2], 0.f);
      float h3 = fmaxf(acc2[m][3] + bias[3], 0.f);
      int unit = 2 * m + (g >> 1);
      *(uint2*)(myH + l15 * 128 + (unit ^ rsw) * 8 + (g & 1) * 4) =
          make_uint2(cvtpk(h0, h1), cvtpk(h2, h3));
    }

    // ---- GEMM3: D3[ch][pt] = W2^T x h2^T, K=128, 1 tile ----
    f32x4 acc3 = (f32x4){0.f, 0.f, 0.f, 0.f};
    __builtin_amdgcn_s_setprio(1);
#pragma unroll
    for (int ks = 0; ks < 4; ks++) {
      bf16x8 bfrag = *(const bf16x8*)(myH + l15 * 128 + ((4 * ks + g) ^ rsw) * 8);
      bf16x8 afrag = *(const bf16x8*)(sW2 + l15 * 128 + ((4 * ks + g) ^ rsw) * 8);
      acc3 = __builtin_amdgcn_mfma_f32_16x16x32_bf16(afrag, bfrag, acc3, 0, 0, 0);
    }
    __builtin_amdgcn_s_setprio(0);
    if (g == 0) {   // rows 0..3 = channels; only 0..2 valid
      rgb[pt * 3 + 0] = sigm_(acc3[0] + sB2[0]);
      rgb[pt * 3 + 1] = sigm_(acc3[1] + sB2[1]);
      rgb[pt * 3 + 2] = sigm_(acc3[2] + sB2[2]);
    }
  }
}

// ============ per-ray scan + composite (1 wave / ray) ============
__global__ __launch_bounds__(256) void vox_scan_kernel(
    const float* __restrict__ alpha, const float* __restrict__ rgb,
    const int* __restrict__ ray_id, float* __restrict__ out, int M, int NR) {
  int wave = (int)((blockIdx.x * blockDim.x + threadIdx.x) >> 6);
  int lane = threadIdx.x & 63;
  if (wave >= NR) return;
  int r = wave;
  int lo = 0, hi = M;
  while (lo < hi) { int mid = (lo + hi) >> 1; if (ray_id[mid] < r) lo = mid + 1; else hi = mid; }
  int start = lo; hi = M;
  while (lo < hi) { int mid = (lo + hi) >> 1; if (ray_id[mid] < r + 1) lo = mid + 1; else hi = mid; }
  int end = lo;

  float carry = 0.f, cr = 0.f, cg = 0.f, cb = 0.f;
  for (int s = start; s < end; s += 64) {
    int idx = s + lane;
    bool valid = idx < end;
    float a = valid ? alpha[idx] : 0.f;
    float l = valid ? log1pf(-fminf(a, 1.f - 1e-7f)) : 0.f;
    float sc = l;
#pragma unroll
    for (int off = 1; off < 64; off <<= 1) {
      float t = __shfl_up(sc, (unsigned)off);
      if (lane >= off) sc += t;
    }
    if (valid) {
      float T = expf(carry + (sc - l));
      float w = a * T;
      cr = fmaf(w, rgb[3 * idx + 0], cr);
      cg = fmaf(w, rgb[3 * idx + 1], cg);
      cb = fmaf(w, rgb[3 * idx + 2], cb);
    }
    carry += __shfl(sc, 63);
  }
#pragma unroll
  for (int off = 32; off > 0; off >>= 1) {
    cr += __shfl_down(cr, (unsigned)off);
    cg += __shfl_down(cg, (unsigned)off);
    cb += __shfl_down(cb, (unsigned)off);
  }
  if (lane == 0) {
    float ail = expf(carry);
    out[3 * r + 0] = cr + ail;
    out[3 * r + 1] = cg + ail;
    out[3 * r + 2] = cb + ail;
  }
}

// ============ fallback (round-1 monolithic path, used if ws too small) ============
__global__ __launch_bounds__(256) void vox_transpose_w0(
    const float* __restrict__ w0, float* __restrict__ w0t) {
  for (int idx = threadIdx.x; idx < 128 * 80; idx += 256) {
    int j = idx / 80, k = idx - j * 80;
    w0t[idx] = (k < 75) ? w0[k * 128 + j] : 0.f;
  }
}

__global__ __launch_bounds__(256) void vox_point_kernel(
    const float* __restrict__ ray_pts, const float* __restrict__ rays_d,
    const float* __restrict__ sdf_vol, const float* __restrict__ k0_vol,
    const float* __restrict__ w0t, const float* __restrict__ b0,
    const float* __restrict__ w1, const float* __restrict__ b1,
    const float* __restrict__ w2, const float* __restrict__ b2,
    const float* __restrict__ s_val, const int* __restrict__ ray_id,
    float* __restrict__ alpha_out, float* __restrict__ rgb_out, int M) {
  int i = blockIdx.x * 256 + threadIdx.x;
  if (i >= M) return;
  float px = ray_pts[3 * i + 0], py = ray_pts[3 * i + 1], pz = ray_pts[3 * i + 2];
  const float SC = 0.5f * 159.f;
  float ux = fminf(fmaxf((px + 1.f) * SC, 0.f), 159.f);
  float uy = fminf(fmaxf((py + 1.f) * SC, 0.f), 159.f);
  float uz = fminf(fmaxf((pz + 1.f) * SC, 0.f), 159.f);
  int ix = min((int)ux, 158), iy = min((int)uy, 158), iz = min((int)uz, 158);
  float fx = ux - (float)ix, fy = uy - (float)iy, fz = uz - (float)iz;
  float wx0 = 1.f - fx, wy0 = 1.f - fy, wz0 = 1.f - fz;
  float w000 = wx0 * wy0 * wz0, w001 = wx0 * wy0 * fz;
  float w010 = wx0 * fy * wz0,  w011 = wx0 * fy * fz;
  float w100 = fx * wy0 * wz0,  w101 = fx * wy0 * fz;
  float w110 = fx * fy * wz0,   w111 = fx * fy * fz;
  int base = (ix * GRIDN + iy) * GRIDN + iz;
  const float* V = sdf_vol;
  float c000 = V[base],          c001 = V[base + 1];
  float c010 = V[base + SY],     c011 = V[base + SY + 1];
  float c100 = V[base + SX],     c101 = V[base + SX + 1];
  float c110 = V[base + SX + SY], c111 = V[base + SX + SY + 1];
  float xm00 = V[base - SX],          xm01 = V[base - SX + 1];
  float xm10 = V[base - SX + SY],     xm11 = V[base - SX + SY + 1];
  float xp00 = V[base + 2 * SX],      xp01 = V[base + 2 * SX + 1];
  float xp10 = V[base + 2 * SX + SY], xp11 = V[base + 2 * SX + SY + 1];
  float ym00 = V[base - SY],          ym01 = V[base - SY + 1];
  float ym10 = V[base + SX - SY],     ym11 = V[base + SX - SY + 1];
  float yp00 = V[base + 2 * SY],      yp01 = V[base + 2 * SY + 1];
  float yp10 = V[base + SX + 2 * SY], yp11 = V[base + SX + 2 * SY + 1];
  float zm00 = V[base - 1],           zm01 = V[base + SY - 1];
  float zm10 = V[base + SX - 1],      zm11 = V[base + SX + SY - 1];
  float zp00 = V[base + 2],           zp01 = V[base + SY + 2];
  float zp10 = V[base + SX + 2],      zp11 = V[base + SX + SY + 2];
  float sdf = w000 * c000 + w001 * c001 + w010 * c010 + w011 * c011 +
              w100 * c100 + w101 * c101 + w110 * c110 + w111 * c111;
  const float INV2H = 159.f / 4.f;
  float gx = (w000 * (c100 - xm00) + w001 * (c101 - xm01) +
              w010 * (c110 - xm10) + w011 * (c111 - xm11) +
              w100 * (xp00 - c000) + w101 * (xp01 - c001) +
              w110 * (xp10 - c010) + w111 * (xp11 - c011)) * INV2H;
  float gy = (w000 * (c010 - ym00) + w001 * (c011 - ym01) +
              w100 * (c110 - ym10) + w101 * (c111 - ym11) +
              w010 * (yp00 - c000) + w011 * (yp01 - c001) +
              w110 * (yp10 - c100) + w111 * (yp11 - c101)) * INV2H;
  float gz = (w000 * (c001 - zm00) + w010 * (c011 - zm01) +
              w100 * (c101 - zm10) + w110 * (c111 - zm11) +
              w001 * (zp00 - c000) + w011 * (zp01 - c010) +
              w101 * (zp10 - c100) + w111 * (zp11 - c110)) * INV2H;
  float ginv = 1.f / (sqrtf(gx * gx + gy * gy + gz * gz) + 1e-8f);
  float gnx = gx * ginv, gny = gy * ginv, gnz = gz * ginv;
  int rid = ray_id[i];
  float ddx = rays_d[3 * rid + 0], ddy = rays_d[3 * rid + 1], ddz = rays_d[3 * rid + 2];
  float true_cos = ddx * gnx + ddy * gny + ddz * gnz;
  float iter_cos = fminf(true_cos, 0.f);
  float inv_s = 1.f / s_val[0];
  float e = iter_cos * (DIST_C * 0.5f);
  float prev_cdf = sigm_((sdf - e) * inv_s);
  float next_cdf = sigm_((sdf + e) * inv_s);
  float alpha = fminf(fmaxf((prev_cdf - next_cdf + 1e-5f) / (prev_cdf + 1e-5f), 0.f), 1.f);
  alpha_out[i] = alpha;
  float feat[75];
  {
    const int offs[8] = {0, 1, SY, SY + 1, SX, SX + 1, SX + SY, SX + SY + 1};
    const float wts[8] = {w000, w001, w010, w011, w100, w101, w110, w111};
#pragma unroll
    for (int c = 0; c < 12; c++) {
      const float* kc = k0_vol + c * N3 + base;
      float acc = 0.f;
#pragma unroll
      for (int t = 0; t < 8; t++) acc = fmaf(wts[t], kc[offs[t]], acc);
      feat[c] = acc;
    }
  }
  float x01 = (px + 1.f) * 0.5f, y01 = (py + 1.f) * 0.5f, z01 = (pz + 1.f) * 0.5f;
  feat[12] = x01; feat[13] = y01; feat[14] = z01;
#pragma unroll
  for (int l = 0; l < 5; l++) {
    float f = (float)(1 << l), s, c;
    sincosf(x01 * f, &s, &c); feat[15 + l] = s; feat[30 + l] = c;
    sincosf(y01 * f, &s, &c); feat[20 + l] = s; feat[35 + l] = c;
    sincosf(z01 * f, &s, &c); feat[25 + l] = s; feat[40 + l] = c;
  }
  feat[45] = ddx; feat[46] = ddy; feat[47] = ddz;
#pragma unroll
  for (int l = 0; l < 4; l++) {
    float f = (float)(1 << l), s, c;
    sincosf(ddx * f, &s, &c); feat[48 + l] = s; feat[60 + l] = c;
    sincosf(ddy * f, &s, &c); feat[52 + l] = s; feat[64 + l] = c;
    sincosf(ddz * f, &s, &c); feat[56 + l] = s; feat[68 + l] = c;
  }
  feat[72] = gnx; feat[73] = gny; feat[74] = gnz;
  float rr = 0.f, rg = 0.f, rb = 0.f;
#pragma unroll 1
  for (int half = 0; half < 2; ++half) {
    float acc[64];
#pragma unroll
    for (int t = 0; t < 64; t++) acc[t] = b1[half * 64 + t];
#pragma unroll 1
    for (int j = 0; j < 128; ++j) {
      float h = b0[j];
      const float* wr = w0t + j * 80;
#pragma unroll
      for (int k = 0; k < 75; k++) h = fmaf(feat[k], wr[k], h);
      h = fmaxf(h, 0.f);
      const float* w1r = w1 + j * 128 + half * 64;
#pragma unroll
      for (int t = 0; t < 64; t++) acc[t] = fmaf(h, w1r[t], acc[t]);
    }
#pragma unroll
    for (int t = 0; t < 64; t++) {
      float h2 = fmaxf(acc[t], 0.f);
      int j2 = half * 64 + t;
      rr = fmaf(h2, w2[3 * j2 + 0], rr);
      rg = fmaf(h2, w2[3 * j2 + 1], rg);
      rb = fmaf(h2, w2[3 * j2 + 2], rb);
    }
  }
  rgb_out[3 * i + 0] = sigm_(rr + b2[0]);
  rgb_out[3 * i + 1] = sigm_(rg + b2[1]);
  rgb_out[3 * i + 2] = sigm_(rb + b2[2]);
}

extern "C" void kernel_launch(void* const* d_in, const int* in_sizes, int n_in,
                              void* d_out, int out_size, void* d_ws, size_t ws_size,
                              hipStream_t stream) {
  const float* ray_pts = (const float*)d_in[0];
  const float* rays_d  = (const float*)d_in[1];
  const float* sdf_vol = (const float*)d_in[2];
  const float* k0_vol  = (const float*)d_in[3];
  const float* w0      = (const float*)d_in[4];
  const float* b0      = (const float*)d_in[5];
  const float* w1      = (const float*)d_in[6];
  const float* b1      = (const float*)d_in[7];
  const float* w2      = (const float*)d_in[8];
  const float* b2      = (const float*)d_in[9];
  const float* s_val   = (const float*)d_in[10];
  const int*   ray_id  = (const int*)d_in[11];
  float* out = (float*)d_out;

  int M  = in_sizes[0] / 3;   // 1048576
  int NR = in_sizes[1] / 3;   // 8192

  char* ws = (char*)d_ws;
  size_t offVR   = 0;                                  // N3*32 combined records
  size_t offTD   = offVR + (size_t)N3 * 32;            // M*32 tap digests
  size_t offA    = offTD + (size_t)M * 32;
  size_t offRgb  = offA + (size_t)M * 4;
  size_t offW0   = offRgb + (size_t)M * 12;
  size_t offW1   = offW0 + (size_t)128 * 128 * 2;
  size_t offW2   = offW1 + (size_t)128 * 128 * 2;
  size_t offVT   = offW2 + (size_t)16 * 128 * 2;
  size_t need    = offVT + (size_t)NR * 64;

  if (ws_size >= need && (M % 256) == 0) {
    unsigned short* VR = (unsigned short*)(ws + offVR);
    unsigned short* TD = (unsigned short*)(ws + offTD);
    float* alpha_ws = (float*)(ws + offA);
    float* rgb_ws = (float*)(ws + offRgb);
    unsigned short* W0B = (unsigned short*)(ws + offW0);
    unsigned short* W1B = (unsigned short*)(ws + offW1);
    unsigned short* W2B = (unsigned short*)(ws + offW2);
    unsigned* VT = (unsigned*)(ws + offVT);

    int ngroups = M / 256;
    vox_repack_all<<<(N3 + 255) / 256, 256, 0, stream>>>(sdf_vol, k0_vol, VR);
    vox_repack_w<<<(128 * 128 + 255) / 256, 256, 0, stream>>>(w0, w1, w2, W0B, W1B, W2B);
    vox_view_table<<<(NR + 255) / 256, 256, 0, stream>>>(rays_d, VT, NR);
    vox_gather_kernel<<<(M + 255) / 256, 256, 0, stream>>>(
        ray_pts, rays_d, VR, s_val, ray_id, alpha_ws, TD, M);
    vox_mlp_kernel<<<(ngroups + TPB - 1) / TPB, 1024, 0, stream>>>(
        ray_pts, VT, ray_id, TD, W0B, W1B, W2B, b0, b1, b2, rgb_ws, ngroups);
    vox_scan_kernel<<<(NR * 64 + 255) / 256, 256, 0, stream>>>(
        alpha_ws, rgb_ws, ray_id, out, M, NR);
  } else {
    float* alpha_ws = (float*)ws;
    float* rgb_ws   = (float*)(ws + (size_t)M * 4);
    float* w0t_ws   = (float*)(ws + (size_t)M * 16);
    vox_transpose_w0<<<1, 256, 0, stream>>>(w0, w0t_ws);
    vox_point_kernel<<<(M + 255) / 256, 256, 0, stream>>>(
        ray_pts, rays_d, sdf_vol, k0_vol, w0t_ws, b0, w1, b1, w2, b2,
        s_val, ray_id, alpha_ws, rgb_ws, M);
    vox_scan_kernel<<<(NR * 64 + 255) / 256, 256, 0, stream>>>(
        alpha_ws, rgb_ws, ray_id, out, M, NR);
  }
}